// Round 1
// 279.559 us; speedup vs baseline: 1.0616x; 1.0616x over previous
//
#include <hip/hip_runtime.h>
#include <math.h>

typedef _Float16 h16;

#define DEV static __device__ __forceinline__

constexpr int B_ = 8, C_ = 128, L_ = 4096, OUT_ = 128;
constexpr int NCH = 4, DM = 32, DS = 16, DI = 64;
constexpr int NI = 32;            // B_*NCH instances
constexpr int NSEG = 64;          // scan segments
constexpr int SL = L_ / NSEG;     // 64 steps per segment

DEV float sigmoidf_(float x) { return 1.f / (1.f + __expf(-x)); }
DEV float siluf_(float x) { return x * sigmoidf_(x); }
DEV float softplusf_(float x) { return (x > 20.f) ? x : __logf(1.f + __expf(x)); }

template <int CTRL>
DEV float dpp_add_(float x) {
  int v = __builtin_amdgcn_update_dpp(0, __float_as_int(x), CTRL, 0xf, 0xf, false);
  return x + __int_as_float(v);
}

typedef __attribute__((ext_vector_type(8))) _Float16 f16x8;
typedef __attribute__((ext_vector_type(4))) float f32x4;

// ---------------- K1: LayerNorm1 (B,C,L)->(B,L,C) + token sums ----------------
__global__ __launch_bounds__(256) void k1_ln(const float* __restrict__ x,
                                             const float* __restrict__ gn,
                                             const float* __restrict__ bn,
                                             float* __restrict__ XN,
                                             float* __restrict__ SUMXN) {
  int bid = blockIdx.x;
  int b = bid >> 6, tile = bid & 63;
  int t0 = tile * 64;
  int tid = threadIdx.x;
  __shared__ float xT[128][65];
  __shared__ float gnS[128], bnS[128];
  __shared__ float red[256];
  if (tid < 128) { gnS[tid] = gn[tid]; bnS[tid] = bn[tid]; }
  for (int k = tid; k < 8192; k += 256) {
    int c = k >> 6, tt = k & 63;
    xT[c][tt] = x[((size_t)(b * C_ + c)) * L_ + t0 + tt];
  }
  __syncthreads();
  {
    int tok = tid >> 2, q = tid & 3;
    float s = 0.f, qq = 0.f;
#pragma unroll
    for (int j = 0; j < 32; ++j) {
      float v = xT[q + 4 * j][tok];
      s += v; qq += v * v;
    }
    s = dpp_add_<0xB1>(s); qq = dpp_add_<0xB1>(qq);
    s = dpp_add_<0x4E>(s); qq = dpp_add_<0x4E>(qq);
    float m = s * (1.f / 128.f);
    float var = qq * (1.f / 128.f) - m * m;
    float rs = rsqrtf(var + 1e-5f);
#pragma unroll
    for (int j = 0; j < 32; ++j) {
      int c = q + 4 * j;
      float v = xT[c][tok];
      xT[c][tok] = (v - m) * rs * gnS[c] + bnS[c];
    }
  }
  __syncthreads();
  float acc = 0.f;
  int cfix = tid & 127;
  for (int k = tid; k < 8192; k += 256) {
    int tt = k >> 7, c = k & 127;
    float v = xT[c][tt];
    XN[((size_t)(b * L_ + t0 + tt)) * C_ + c] = v;
    acc += v;
  }
  red[tid] = acc;
  __syncthreads();
  if (tid < 128) atomicAdd(&SUMXN[b * C_ + cfix], red[tid] + red[tid + 128]);
}

// ---------------- K2: in-proj + conv + silu + x-proj + dt via f16 MFMA --------
// in-proj: 80x32 @ 32x64 as 5x4 tiles of mfma_f32_16x16x32_f16 (K=32 in one op)
// x-proj:  64x64 @ 64x48(pad) as 4x3 tiles x 2 K-chunks
// Fragment layout (verified m89/m92): A row=lane&15, k=(lane>>4)*8+i (contig);
// B col=lane&15, same k; D col=lane&15, row=(lane>>4)*4+reg.
__global__ __launch_bounds__(256) void k2_prep(
    const float* __restrict__ in_W, const float* __restrict__ conv_W,
    const float* __restrict__ conv_b, const float* __restrict__ xproj_W,
    const float* __restrict__ dt_W, const float* __restrict__ dt_b,
    const float* __restrict__ XN, h16* __restrict__ SX2, h16* __restrict__ SDT2,
    h16* __restrict__ SB2, h16* __restrict__ SC2) {
  int bid = blockIdx.x;
  int i = bid >> 6, tile = bid & 63;
  int b = i >> 2, ch = i & 3;
  int t0 = tile * 64;
  int tid = threadIdx.x;
  int w = __builtin_amdgcn_readfirstlane(tid >> 6);
  int lane = tid & 63;

  // xd overlays u/in_W staging (dead after the in-proj barrier).
  __shared__ __attribute__((aligned(16))) union {
    struct {
      _Float16 uH[80][40];   // rows 0..66 = tokens t0-3..t0+63; 67..79 zero
      _Float16 w1H[64][40];  // in_W x-half, row=d, col=c (16B-aligned stride)
    } s;
    float xdS[64][36];       // x-proj output, row=token, col=o (34 used)
  } U;
  __shared__ __attribute__((aligned(16))) _Float16 preH[80][66];  // in-proj out
  __shared__ __attribute__((aligned(16))) _Float16 xH[64][72];    // conv+silu out
  __shared__ __attribute__((aligned(16))) _Float16 w2H[48][72];   // xproj_W, pad rows 34..47 = 0
  __shared__ float convWS[64][4];
  __shared__ float dtWS[64][2];
  __shared__ float dtbS[64], cbS[64];

  convWS[tid >> 2][tid & 3] = conv_W[tid];
  if (tid < 128) dtWS[tid >> 1][tid & 1] = dt_W[tid];
  if (tid < 64) { dtbS[tid] = dt_b[tid]; cbS[tid] = conv_b[tid]; }
  const float* xn = XN + (size_t)b * L_ * C_ + ch * DM;
  for (int k = tid; k < 80 * 32; k += 256) {
    int r = k >> 5, c = k & 31;
    int tg = t0 - 3 + r;
    float v = (r < 67 && tg >= 0) ? xn[(size_t)tg * C_ + c] : 0.f;
    U.s.uH[r][c] = (_Float16)v;
  }
  for (int k = tid; k < 2048; k += 256) U.s.w1H[k >> 5][k & 31] = (_Float16)in_W[k];
  for (int k = tid; k < 48 * 64; k += 256) {
    int r = k >> 6, c = k & 63;
    w2H[r][c] = (r < 34) ? (_Float16)xproj_W[r * 64 + c] : (_Float16)0.f;
  }
  __syncthreads();

  // in-proj MFMA: wave w owns N-tile nt=w (B-frag loaded once), loops 5 M-tiles
  {
    int rsel = lane & 15, ksel = (lane >> 4) * 8;
    int nt = w;
    f16x8 bf = *(const f16x8*)&U.s.w1H[nt * 16 + rsel][ksel];
    int row0q = (lane >> 4) << 2;
    int col = nt * 16 + rsel;
#pragma unroll
    for (int mt = 0; mt < 5; ++mt) {
      f16x8 af = *(const f16x8*)&U.s.uH[mt * 16 + rsel][ksel];
      f32x4 acc = {0.f, 0.f, 0.f, 0.f};
      acc = __builtin_amdgcn_mfma_f32_16x16x32_f16(af, bf, acc, 0, 0, 0);
      int row0 = mt * 16 + row0q;
#pragma unroll
      for (int r = 0; r < 4; ++r) preH[row0 + r][col] = (_Float16)acc[r];
    }
  }
  __syncthreads();

  // causal depthwise conv + silu; write xH (x-proj A operand) + SX2 inline
  h16* SXp = SX2 + ((size_t)i * L_ + t0) * DI;
  for (int k = tid; k < 4096; k += 256) {
    int r = k >> 6, d = k & 63;
    float v = cbS[d];
#pragma unroll
    for (int j = 0; j < 4; ++j) v = fmaf(convWS[d][j], (float)preH[r + j][d], v);
    v = siluf_(v);
    xH[r][d] = (_Float16)v;
    SXp[(size_t)r * DI + d] = (h16)v;
  }
  __syncthreads();

  // x-proj MFMA: wave w owns M-tile mt=w; K=64 as 2 chunks; N padded to 48
  {
    int rsel = lane & 15, ksel = (lane >> 4) * 8;
    int mt = w;
    f16x8 a0 = *(const f16x8*)&xH[mt * 16 + rsel][ksel];
    f16x8 a1 = *(const f16x8*)&xH[mt * 16 + rsel][32 + ksel];
    int row0 = mt * 16 + ((lane >> 4) << 2);
#pragma unroll
    for (int nt = 0; nt < 3; ++nt) {
      f16x8 b0 = *(const f16x8*)&w2H[nt * 16 + rsel][ksel];
      f16x8 b1 = *(const f16x8*)&w2H[nt * 16 + rsel][32 + ksel];
      f32x4 acc = {0.f, 0.f, 0.f, 0.f};
      acc = __builtin_amdgcn_mfma_f32_16x16x32_f16(a0, b0, acc, 0, 0, 0);
      acc = __builtin_amdgcn_mfma_f32_16x16x32_f16(a1, b1, acc, 0, 0, 0);
      int col = nt * 16 + rsel;
      if (col < 34) {
#pragma unroll
        for (int r = 0; r < 4; ++r) U.xdS[row0 + r][col] = acc[r];
      }
    }
  }
  __syncthreads();

  h16* SDTp = SDT2 + ((size_t)i * L_ + t0) * DI;
  for (int k = tid; k < 4096; k += 256) {
    int d = k & 63, r = k >> 6;
    float raw = fmaf(U.xdS[r][0], dtWS[d][0], fmaf(U.xdS[r][1], dtWS[d][1], dtbS[d]));
    SDTp[(size_t)r * DI + d] = (h16)softplusf_(raw);
  }
  h16* SBp = SB2 + ((size_t)i * L_ + t0) * DS;
  h16* SCp = SC2 + ((size_t)i * L_ + t0) * DS;
  for (int k = tid; k < 1024; k += 256) {
    int s = k & 15, r = k >> 4;
    SBp[(size_t)r * DS + s] = (h16)U.xdS[r][2 + s];
    SCp[(size_t)r * DS + s] = (h16)U.xdS[r][18 + s];
  }
}

// ---------------- K3a: per-segment local scan (d-per-thread) -> (P, Q) ----------------
__global__ __launch_bounds__(256) void k3a_seg(
    const float* __restrict__ A_log, const h16* __restrict__ SDT2,
    const h16* __restrict__ SX2, const h16* __restrict__ SB2,
    float* __restrict__ Pp, float* __restrict__ Qp) {
  int bid = blockIdx.x;             // i*16 + sg4
  int i = bid >> 4, sg4 = bid & 15;
  int tid = threadIdx.x;
  int w = tid >> 6, lane = tid & 63;
  int seg = sg4 * 4 + w;
  int t0 = seg * SL;
  __shared__ float bS[4][64][20];
  {
    const h16* pb = SB2 + ((size_t)i * L_ + t0 + lane) * DS;
    float4 r0 = *(const float4*)pb;
    float4 r1 = *(const float4*)(pb + 8);
    const h16* h0p = (const h16*)&r0;
    const h16* h1p = (const h16*)&r1;
#pragma unroll
    for (int s = 0; s < 8; ++s) bS[w][lane][s] = (float)h0p[s];
#pragma unroll
    for (int s = 0; s < 8; ++s) bS[w][lane][8 + s] = (float)h1p[s];
  }
  __syncthreads();
  float Av[16];
#pragma unroll
  for (int s = 0; s < 16; ++s) Av[s] = -__expf(A_log[lane * 16 + s]);
  float A0 = Av[0];
  bool okf = true;
#pragma unroll
  for (int s = 0; s < 16; ++s) okf &= fabsf(Av[s] - (float)(s + 1) * A0) <= 1e-4f * fabsf(Av[s]);
  int fastp = __all(okf ? 1 : 0);
  float h[16];
#pragma unroll
  for (int s = 0; s < 16; ++s) h[s] = 0.f;
  float sdt = 0.f;
  const h16* pdt = SDT2 + ((size_t)i * L_ + t0) * DI + lane;
  const h16* pxx = SX2 + ((size_t)i * L_ + t0) * DI + lane;
  float dtc = (float)pdt[0], xvc = (float)pxx[0];
  for (int t = 0; t < SL; ++t) {
    float dt = dtc, xv = xvc;
    if (t < SL - 1) { dtc = (float)pdt[(t + 1) * DI]; xvc = (float)pxx[(t + 1) * DI]; }
    float Bv[16];
    const float* row = &bS[w][t][0];
#pragma unroll
    for (int j = 0; j < 4; ++j) *(float4*)&Bv[4 * j] = *(const float4*)(row + 4 * j);
    float dtx = dt * xv;
    float dA[16];
    if (fastp) {
      float E = __expf(A0 * dt);
      dA[0] = E;
#pragma unroll
      for (int s = 1; s < 16; ++s) dA[s] = dA[s - 1] * E;
    } else {
#pragma unroll
      for (int s = 0; s < 16; ++s) dA[s] = __expf(Av[s] * dt);
    }
#pragma unroll
    for (int s = 0; s < 16; ++s) h[s] = fmaf(dA[s], h[s], dtx * Bv[s]);
    sdt += dt;
  }
  float P[16];
  if (fastp) {
    float E = __expf(A0 * sdt);
    P[0] = E;
#pragma unroll
    for (int s = 1; s < 16; ++s) P[s] = P[s - 1] * E;
  } else {
#pragma unroll
    for (int s = 0; s < 16; ++s) P[s] = __expf(Av[s] * sdt);
  }
  size_t base = (((size_t)i * DI + lane) * NSEG + seg) * DS;
#pragma unroll
  for (int j = 0; j < 4; ++j) {
    *(float4*)(Pp + base + 4 * j) = *(float4*)&P[4 * j];
    *(float4*)(Qp + base + 4 * j) = *(float4*)&h[4 * j];
  }
}

// ---------------- K3b: inter-segment scan -> h0 per segment (overlays P) ----------------
__global__ __launch_bounds__(256) void k3b_comb(float* __restrict__ Pp,
                                                const float* __restrict__ Qp) {
  int g = blockIdx.x * 256 + threadIdx.x;  // 32768 = NI*DI*DS
  int s = g & 15;
  int r = g >> 4;          // over NI*DI
  size_t base = (size_t)r * NSEG * DS + s;
  float H = 0.f;
  for (int seg = 0; seg < NSEG; ++seg) {
    size_t a = base + (size_t)seg * DS;
    float P = Pp[a], Q = Qp[a];
    Pp[a] = H;
    H = fmaf(P, H, Q);
  }
}

// ---------------- K3c: final scan, fused with z-gate/D-term/token-sums ----------------
__global__ __launch_bounds__(256) void k3c_scan(
    const float* __restrict__ A_log, const h16* __restrict__ SDT2,
    const h16* __restrict__ SX2, const h16* __restrict__ SB2,
    const h16* __restrict__ SC2, const float* __restrict__ XN,
    const float* __restrict__ in_W, const float* __restrict__ D_p,
    const float* __restrict__ H0p, h16* __restrict__ YS2,
    float* __restrict__ SUMYF) {
  int bid = blockIdx.x;             // i*16 + sg4
  int i = bid >> 4, sg4 = bid & 15;
  int b = i >> 2, ch = i & 3;
  int tid = threadIdx.x;
  int w = tid >> 6, lane = tid & 63;
  int seg = sg4 * 4 + w;
  int t0 = seg * SL;
  __shared__ float rowS[4][64][68];   // [w][t][ B16 | C16 | u32 ] + pad
  {
    const h16* pb = SB2 + ((size_t)i * L_ + t0 + lane) * DS;
    const h16* pc = SC2 + ((size_t)i * L_ + t0 + lane) * DS;
    float4 r0 = *(const float4*)pb;
    float4 r1 = *(const float4*)(pb + 8);
    float4 r2 = *(const float4*)pc;
    float4 r3 = *(const float4*)(pc + 8);
    const h16* hp0 = (const h16*)&r0;
    const h16* hp1 = (const h16*)&r1;
    const h16* hp2 = (const h16*)&r2;
    const h16* hp3 = (const h16*)&r3;
#pragma unroll
    for (int s = 0; s < 8; ++s) {
      rowS[w][lane][s] = (float)hp0[s];
      rowS[w][lane][8 + s] = (float)hp1[s];
      rowS[w][lane][16 + s] = (float)hp2[s];
      rowS[w][lane][24 + s] = (float)hp3[s];
    }
    const float* pu = XN + ((size_t)(b * L_ + t0 + lane)) * C_ + ch * DM;
#pragma unroll
    for (int j = 0; j < 8; ++j)
      *(float4*)&rowS[w][lane][32 + 4 * j] = *(const float4*)(pu + 4 * j);
  }
  __syncthreads();
  float Av[16];
#pragma unroll
  for (int s = 0; s < 16; ++s) Av[s] = -__expf(A_log[lane * 16 + s]);
  float A0 = Av[0];
  bool okf = true;
#pragma unroll
  for (int s = 0; s < 16; ++s) okf &= fabsf(Av[s] - (float)(s + 1) * A0) <= 1e-4f * fabsf(Av[s]);
  int fastp = __all(okf ? 1 : 0);
  float4 wz[8];
#pragma unroll
  for (int j = 0; j < 8; ++j) wz[j] = *(const float4*)(in_W + 2048 + lane * 32 + 4 * j);
  float Dp = D_p[lane];
  float h[16];
  {
    size_t base = (((size_t)i * DI + lane) * NSEG + seg) * DS;
#pragma unroll
    for (int j = 0; j < 4; ++j) *(float4*)&h[4 * j] = *(const float4*)(H0p + base + 4 * j);
  }
  const h16* pdt = SDT2 + ((size_t)i * L_ + t0) * DI + lane;
  const h16* pxx = SX2 + ((size_t)i * L_ + t0) * DI + lane;
  h16* pys = YS2 + ((size_t)i * L_ + t0) * DI + lane;
  float dtc = (float)pdt[0], xvc = (float)pxx[0];
  float sum = 0.f;
  for (int t = 0; t < SL; ++t) {
    float dt = dtc, xv = xvc;
    if (t < SL - 1) { dtc = (float)pdt[(t + 1) * DI]; xvc = (float)pxx[(t + 1) * DI]; }
    const float* row = &rowS[w][t][0];
    float Bv[16], Cv[16];
#pragma unroll
    for (int j = 0; j < 4; ++j) {
      *(float4*)&Bv[4 * j] = *(const float4*)(row + 4 * j);
      *(float4*)&Cv[4 * j] = *(const float4*)(row + 16 + 4 * j);
    }
    float dtx = dt * xv;
    float dA[16];
    if (fastp) {
      float E = __expf(A0 * dt);
      dA[0] = E;
#pragma unroll
      for (int s = 1; s < 16; ++s) dA[s] = dA[s - 1] * E;
    } else {
#pragma unroll
      for (int s = 0; s < 16; ++s) dA[s] = __expf(Av[s] * dt);
    }
    float y = 0.f;
#pragma unroll
    for (int s = 0; s < 16; ++s) {
      h[s] = fmaf(dA[s], h[s], dtx * Bv[s]);
      y = fmaf(h[s], Cv[s], y);
    }
    float z = 0.f;
#pragma unroll
    for (int j = 0; j < 8; ++j) {
      float4 u4 = *(const float4*)(row + 32 + 4 * j);
      z = fmaf(u4.x, wz[j].x, z);
      z = fmaf(u4.y, wz[j].y, z);
      z = fmaf(u4.z, wz[j].z, z);
      z = fmaf(u4.w, wz[j].w, z);
    }
    float yf = (y + xv * Dp) * siluf_(z);
    pys[(size_t)t * DI] = (h16)yf;
    sum += yf;
  }
  atomicAdd(&SUMYF[i * DI + lane], sum);
}

// ---------------- K4: SE gates ----------------
__global__ __launch_bounds__(64) void k4_gates(
    const float* __restrict__ out_W, const float* __restrict__ se_W1,
    const float* __restrict__ se_W2, const float* __restrict__ skip_p,
    const float* __restrict__ SUMYF, const float* __restrict__ SUMXN,
    float* __restrict__ GATES) {
  int i = blockIdx.x;
  int b = i >> 2, ch = i & 3;
  int tid = threadIdx.x;
  __shared__ float syS[64], catS[64], seS[2];
  syS[tid] = SUMYF[i * DI + tid];
  __syncthreads();
  float invL = 1.f / (float)L_;
  if (tid < 32) {
    float acc = 0.f;
#pragma unroll
    for (int dd = 0; dd < 64; ++dd) acc = fmaf(syS[dd], out_W[tid * 64 + dd], acc);
    catS[tid] = acc * invL;
  } else {
    int c = tid - 32;
    catS[tid] = skip_p[0] * SUMXN[b * C_ + ch * DM + c] * invL;
  }
  __syncthreads();
  if (tid < 2) {
    float acc = 0.f;
#pragma unroll
    for (int k = 0; k < 64; ++k) acc = fmaf(catS[k], se_W1[tid * 64 + k], acc);
    seS[tid] = fmaxf(acc, 0.f);
  }
  __syncthreads();
  float gg = fmaf(seS[0], se_W2[tid * 2 + 0], seS[1] * se_W2[tid * 2 + 1]);
  GATES[i * DI + tid] = sigmoidf_(gg);
}

// ---------------- K5b: M1 = yfull @ outW.T, gated combine (in place over xn) ----------------
__global__ __launch_bounds__(256) void k5b_combine(
    const float* __restrict__ out_W, const float* __restrict__ skip_p,
    const float* __restrict__ GATES, const h16* __restrict__ YS2,
    float* __restrict__ XN) {
  int bid = blockIdx.x;
  int i = bid >> 6, tile = bid & 63;
  int b = i >> 2, ch = i & 3;
  int t0 = tile * 64;
  int tid = threadIdx.x;
  int w = tid >> 6, lane = tid & 63;
  __shared__ float outWS[32][68];
  __shared__ float yfT[64][65];
  __shared__ float xnS[64][37];
  __shared__ float gS[64];
  for (int k = tid; k < 2048; k += 256) outWS[k >> 6][k & 63] = out_W[k];
  if (tid < 64) gS[tid] = GATES[i * DI + tid];
  const h16* py = YS2 + ((size_t)i * L_ + t0) * DI;
  for (int k = tid; k < 4096; k += 256) {
    int dd = k & 63, tt = k >> 6;
    yfT[tt][dd] = (float)py[(size_t)tt * DI + dd];
  }
  float* xn = XN + (size_t)b * L_ * C_ + ch * DM;
  for (int k = tid; k < 2048; k += 256) {
    int tt = k >> 5, o = k & 31;
    xnS[tt][o] = xn[(size_t)(t0 + tt) * C_ + o];
  }
  __syncthreads();
  float yr[64];
#pragma unroll
  for (int dd = 0; dd < 64; ++dd) yr[dd] = yfT[lane][dd];
  float skip = skip_p[0];
#pragma unroll
  for (int q = 0; q < 8; ++q) {
    int o = w * 8 + q;
    float a = 0.f;
#pragma unroll
    for (int d4 = 0; d4 < 64; d4 += 4) {
      float4 wv = *(const float4*)&outWS[o][d4];
      a = fmaf(yr[d4], wv.x, a);
      a = fmaf(yr[d4 + 1], wv.y, a);
      a = fmaf(yr[d4 + 2], wv.z, a);
      a = fmaf(yr[d4 + 3], wv.w, a);
    }
    xnS[lane][o] = gS[o] * a + gS[32 + o] * skip * xnS[lane][o];
  }
  __syncthreads();
  for (int k = tid; k < 2048; k += 256) {
    int tt = k >> 5, o = k & 31;
    xn[(size_t)(t0 + tt) * C_ + o] = xnS[tt][o];
  }
}

// ---------------- K6: LN2 + proj + transpose to (B,OUT,H,W) ----------------
__global__ __launch_bounds__(256) void k6_ln_proj(
    const float* __restrict__ gn, const float* __restrict__ bn,
    const float* __restrict__ proj_W, const float* __restrict__ proj_b,
    const float* __restrict__ XN, float* __restrict__ out) {
  int bid = blockIdx.x;
  int b = bid >> 6, tile = bid & 63;
  int t0 = tile * 64;
  int tid = threadIdx.x;
  int w = tid >> 6, lane = tid & 63;
  __shared__ float xmS[64][132];
  __shared__ float projS[64][132];
  __shared__ float gnS[128], bnS[128];
  if (tid < 128) { gnS[tid] = gn[tid]; bnS[tid] = bn[tid]; }
  const float* xm = XN + (size_t)b * L_ * C_;
  for (int k = tid; k < 8192; k += 256) {
    int tt = k >> 7, c = k & 127;
    xmS[tt][c] = xm[(size_t)(t0 + tt) * C_ + c];
  }
  for (int k = tid; k < 8192; k += 256) {
    int o = k >> 7, c = k & 127;
    projS[o][c] = proj_W[k];
  }
  __syncthreads();
  {
    int tok = tid >> 2, q = tid & 3;
    float s = 0.f, qq = 0.f;
#pragma unroll
    for (int j = 0; j < 32; ++j) {
      float v = xmS[tok][4 * j + q];
      s += v; qq += v * v;
    }
    s = dpp_add_<0xB1>(s); qq = dpp_add_<0xB1>(qq);
    s = dpp_add_<0x4E>(s); qq = dpp_add_<0x4E>(qq);
    float m = s * (1.f / 128.f);
    float var = qq * (1.f / 128.f) - m * m;
    float rs = rsqrtf(var + 1e-5f);
#pragma unroll
    for (int j = 0; j < 32; ++j) {
      int c = 4 * j + q;
      float v = xmS[tok][c];
      xmS[tok][c] = (v - m) * rs * gnS[c] + bnS[c];
    }
  }
  __syncthreads();
  int lt = lane >> 2, lo = lane & 3;
  for (int phase = 0; phase < 2; ++phase) {
    if (phase == 1) {
      __syncthreads();
      for (int k = tid; k < 8192; k += 256) {
        int o = k >> 7, c = k & 127;
        projS[o][c] = proj_W[8192 + k];
      }
      __syncthreads();
    }
    int obase = phase * 64 + w * 16 + lo * 4;
    float acc[16];
#pragma unroll
    for (int j = 0; j < 4; ++j)
#pragma unroll
      for (int oi = 0; oi < 4; ++oi) acc[j * 4 + oi] = proj_b[obase + oi];
#pragma unroll 4
    for (int c0 = 0; c0 < 128; c0 += 4) {
      float4 xr[4], pr[4];
#pragma unroll
      for (int j = 0; j < 4; ++j) xr[j] = *(const float4*)&xmS[lt * 4 + j][c0];
#pragma unroll
      for (int oi = 0; oi < 4; ++oi) pr[oi] = *(const float4*)&projS[w * 16 + lo * 4 + oi][c0];
#pragma unroll
      for (int j = 0; j < 4; ++j)
#pragma unroll
        for (int oi = 0; oi < 4; ++oi) {
          float a = acc[j * 4 + oi];
          a = fmaf(xr[j].x, pr[oi].x, a);
          a = fmaf(xr[j].y, pr[oi].y, a);
          a = fmaf(xr[j].z, pr[oi].z, a);
          a = fmaf(xr[j].w, pr[oi].w, a);
          acc[j * 4 + oi] = a;
        }
    }
#pragma unroll
    for (int oi = 0; oi < 4; ++oi) {
      int o = obase + oi;
      float4 v = make_float4(acc[0 * 4 + oi], acc[1 * 4 + oi],
                             acc[2 * 4 + oi], acc[3 * 4 + oi]);
      *(float4*)&out[((size_t)(b * OUT_ + o)) * L_ + t0 + lt * 4] = v;
    }
  }
}

extern "C" void kernel_launch(void* const* d_in, const int* in_sizes, int n_in,
                              void* d_out, int out_size, void* d_ws, size_t ws_size,
                              hipStream_t stream) {
  const float* x = (const float*)d_in[0];
  const float* norm_g = (const float*)d_in[1];
  const float* norm_b = (const float*)d_in[2];
  const float* proj_W = (const float*)d_in[3];
  const float* proj_b = (const float*)d_in[4];
  const float* skip = (const float*)d_in[5];
  const float* se_W1 = (const float*)d_in[6];
  const float* se_W2 = (const float*)d_in[7];
  const float* in_W = (const float*)d_in[8];
  const float* conv_W = (const float*)d_in[9];
  const float* conv_b = (const float*)d_in[10];
  const float* xproj_W = (const float*)d_in[11];
  const float* dt_W = (const float*)d_in[12];
  const float* dt_b = (const float*)d_in[13];
  const float* A_log = (const float*)d_in[14];
  const float* D_p = (const float*)d_in[15];
  const float* out_W = (const float*)d_in[16];
  float* out = (float*)d_out;

  // workspace (~92 MiB)
  float* XN = (float*)d_ws;                         // B*L*C f32
  float* SUMYF = XN + (size_t)B_ * L_ * C_;         // NI*DI
  float* SUMXN = SUMYF + NI * DI;                   // B*C
  float* GATES = SUMXN + B_ * C_;                   // NI*DI
  float* Pp = GATES + NI * DI;                      // NI*DI*NSEG*DS f32
  float* Qp = Pp + (size_t)NI * DI * NSEG * DS;
  h16* YS2 = (h16*)(Qp + (size_t)NI * DI * NSEG * DS);  // NI*L*DI h16
  h16* SX2 = YS2 + (size_t)NI * L_ * DI;
  h16* SDT2 = SX2 + (size_t)NI * L_ * DI;
  h16* SB2 = SDT2 + (size_t)NI * L_ * DI;           // NI*L*DS h16
  h16* SC2 = SB2 + (size_t)NI * L_ * DS;

  hipMemsetAsync(SUMYF, 0, (size_t)(NI * DI + B_ * C_) * sizeof(float), stream);
  k1_ln<<<B_ * 64, 256, 0, stream>>>(x, norm_g, norm_b, XN, SUMXN);
  k2_prep<<<NI * 64, 256, 0, stream>>>(in_W, conv_W, conv_b, xproj_W, dt_W, dt_b,
                                       XN, SX2, SDT2, SB2, SC2);
  k3a_seg<<<NI * 16, 256, 0, stream>>>(A_log, SDT2, SX2, SB2, Pp, Qp);
  k3b_comb<<<128, 256, 0, stream>>>(Pp, Qp);
  k3c_scan<<<NI * 16, 256, 0, stream>>>(A_log, SDT2, SX2, SB2, SC2, XN, in_W, D_p,
                                        Pp, YS2, SUMYF);
  k4_gates<<<NI, 64, 0, stream>>>(out_W, se_W1, se_W2, skip, SUMYF, SUMXN, GATES);
  k5b_combine<<<NI * 64, 256, 0, stream>>>(out_W, skip, GATES, YS2, XN);
  k6_ln_proj<<<B_ * 64, 256, 0, stream>>>(norm_g, norm_b, proj_W, proj_b, XN, out);
}

// Round 2
// 272.459 us; speedup vs baseline: 1.0892x; 1.0261x over previous
//
#include <hip/hip_runtime.h>
#include <math.h>

typedef _Float16 h16;

#define DEV static __device__ __forceinline__

constexpr int B_ = 8, C_ = 128, L_ = 4096, OUT_ = 128;
constexpr int NCH = 4, DM = 32, DS = 16, DI = 64;
constexpr int NI = 32;            // B_*NCH instances
constexpr int NSEG = 128;         // scan segments (was 64): 2x occupancy for k3a/k3c
constexpr int SL = L_ / NSEG;     // 32 steps per segment

DEV float sigmoidf_(float x) { return 1.f / (1.f + __expf(-x)); }
DEV float siluf_(float x) { return x * sigmoidf_(x); }
DEV float softplusf_(float x) { return (x > 20.f) ? x : __logf(1.f + __expf(x)); }

template <int CTRL>
DEV float dpp_add_(float x) {
  int v = __builtin_amdgcn_update_dpp(0, __float_as_int(x), CTRL, 0xf, 0xf, false);
  return x + __int_as_float(v);
}

typedef __attribute__((ext_vector_type(8))) _Float16 f16x8;
typedef __attribute__((ext_vector_type(4))) _Float16 f16x4;
typedef __attribute__((ext_vector_type(4))) float f32x4;

// log-depth powers: out[s] = E^(s+1), dep depth ~5 instead of 15
DEV void powladder_(float E, float* out) {
  float E2 = E * E;
  float E4 = E2 * E2;
  float E8 = E4 * E4;
  float E3 = E2 * E;
  out[0] = E;       out[1] = E2;      out[2] = E3;      out[3] = E4;
  out[4] = E4 * E;  out[5] = E4 * E2; out[6] = E4 * E3; out[7] = E8;
  out[8] = E8 * E;  out[9] = E8 * E2; out[10] = E8 * E3; out[11] = E8 * E4;
  out[12] = E8 * out[4]; out[13] = E8 * out[5]; out[14] = E8 * out[6];
  out[15] = E8 * E8;
}

// ---------------- K1: LayerNorm1 (B,C,L)->(B,L,C) + token sums ----------------
__global__ __launch_bounds__(256) void k1_ln(const float* __restrict__ x,
                                             const float* __restrict__ gn,
                                             const float* __restrict__ bn,
                                             float* __restrict__ XN,
                                             float* __restrict__ SUMXN) {
  int bid = blockIdx.x;
  int b = bid >> 6, tile = bid & 63;
  int t0 = tile * 64;
  int tid = threadIdx.x;
  __shared__ float xT[128][65];
  __shared__ float gnS[128], bnS[128];
  __shared__ float red[256];
  if (tid < 128) { gnS[tid] = gn[tid]; bnS[tid] = bn[tid]; }
  for (int k = tid; k < 8192; k += 256) {
    int c = k >> 6, tt = k & 63;
    xT[c][tt] = x[((size_t)(b * C_ + c)) * L_ + t0 + tt];
  }
  __syncthreads();
  {
    int tok = tid >> 2, q = tid & 3;
    float s = 0.f, qq = 0.f;
#pragma unroll
    for (int j = 0; j < 32; ++j) {
      float v = xT[q + 4 * j][tok];
      s += v; qq += v * v;
    }
    s = dpp_add_<0xB1>(s); qq = dpp_add_<0xB1>(qq);
    s = dpp_add_<0x4E>(s); qq = dpp_add_<0x4E>(qq);
    float m = s * (1.f / 128.f);
    float var = qq * (1.f / 128.f) - m * m;
    float rs = rsqrtf(var + 1e-5f);
#pragma unroll
    for (int j = 0; j < 32; ++j) {
      int c = q + 4 * j;
      float v = xT[c][tok];
      xT[c][tok] = (v - m) * rs * gnS[c] + bnS[c];
    }
  }
  __syncthreads();
  float acc = 0.f;
  int cfix = tid & 127;
  for (int k = tid; k < 8192; k += 256) {
    int tt = k >> 7, c = k & 127;
    float v = xT[c][tt];
    XN[((size_t)(b * L_ + t0 + tt)) * C_ + c] = v;
    acc += v;
  }
  red[tid] = acc;
  __syncthreads();
  if (tid < 128) atomicAdd(&SUMXN[b * C_ + cfix], red[tid] + red[tid + 128]);
}

// ---------------- K2: in-proj + conv + silu + x-proj + dt + z-gate (MFMA) -----
// in-proj x-half: 80x32 @ 32x64 as 5x4 tiles of mfma_f32_16x16x32_f16
// z-gate (NEW): z^T = Wz(64x32) @ u^T(32x64) as 4x4 tiles; silu'd, stored SZ2
// x-proj:  64x64 @ 64x48(pad) as 4x3 tiles x 2 K-chunks
// Fragment layout (verified m89/m92): A row=lane&15, k=(lane>>4)*8+i (contig);
// B col=lane&15, same k; D col=lane&15, row=(lane>>4)*4+reg.
__global__ __launch_bounds__(256) void k2_prep(
    const float* __restrict__ in_W, const float* __restrict__ conv_W,
    const float* __restrict__ conv_b, const float* __restrict__ xproj_W,
    const float* __restrict__ dt_W, const float* __restrict__ dt_b,
    const float* __restrict__ XN, h16* __restrict__ SX2, h16* __restrict__ SDT2,
    h16* __restrict__ SB2, h16* __restrict__ SC2, h16* __restrict__ SZ2) {
  int bid = blockIdx.x;
  int i = bid >> 6, tile = bid & 63;
  int b = i >> 2, ch = i & 3;
  int t0 = tile * 64;
  int tid = threadIdx.x;
  int w = __builtin_amdgcn_readfirstlane(tid >> 6);
  int lane = tid & 63;

  // union: staging (u + x-half of in_W) | x-proj output | z transpose bounce
  __shared__ __attribute__((aligned(16))) union {
    struct {
      _Float16 uH[80][40];   // rows 0..66 = tokens t0-3..t0+63; 67..79 zero
      _Float16 w1H[64][40];  // in_W x-half, row=d, col=c
    } s;
    float xdS[64][36];       // x-proj output, row=token, col=o (34 used)
    _Float16 zL[64][80];     // silu(z) bounce, row=token, col=zd
  } U;
  __shared__ __attribute__((aligned(16))) _Float16 preH[80][66];  // in-proj out
  __shared__ __attribute__((aligned(16))) _Float16 xH[64][72];    // conv+silu out
  __shared__ __attribute__((aligned(16))) _Float16 w2H[48][72];   // xproj_W, pad rows 34..47 = 0
  __shared__ float convWS[64][4];
  __shared__ float dtWS[64][2];
  __shared__ float dtbS[64], cbS[64];

  convWS[tid >> 2][tid & 3] = conv_W[tid];
  if (tid < 128) dtWS[tid >> 1][tid & 1] = dt_W[tid];
  if (tid < 64) { dtbS[tid] = dt_b[tid]; cbS[tid] = conv_b[tid]; }
  const float* xn = XN + (size_t)b * L_ * C_ + ch * DM;
  for (int k = tid; k < 80 * 32; k += 256) {
    int r = k >> 5, c = k & 31;
    int tg = t0 - 3 + r;
    float v = (r < 67 && tg >= 0) ? xn[(size_t)tg * C_ + c] : 0.f;
    U.s.uH[r][c] = (_Float16)v;
  }
  for (int k = tid; k < 2048; k += 256) U.s.w1H[k >> 5][k & 31] = (_Float16)in_W[k];
  for (int k = tid; k < 48 * 64; k += 256) {
    int r = k >> 6, c = k & 63;
    w2H[r][c] = (r < 34) ? (_Float16)xproj_W[r * 64 + c] : (_Float16)0.f;
  }
  __syncthreads();

  int rsel = lane & 15, ksel = (lane >> 4) * 8;
  // in-proj MFMA: wave w owns N-tile nt=w (B-frag loaded once), loops 5 M-tiles
  {
    int nt = w;
    f16x8 bf = *(const f16x8*)&U.s.w1H[nt * 16 + rsel][ksel];
    int row0q = (lane >> 4) << 2;
    int col = nt * 16 + rsel;
#pragma unroll
    for (int mt = 0; mt < 5; ++mt) {
      f16x8 af = *(const f16x8*)&U.s.uH[mt * 16 + rsel][ksel];
      f32x4 acc = {0.f, 0.f, 0.f, 0.f};
      acc = __builtin_amdgcn_mfma_f32_16x16x32_f16(af, bf, acc, 0, 0, 0);
      int row0 = mt * 16 + row0q;
#pragma unroll
      for (int r = 0; r < 4; ++r) preH[row0 + r][col] = (_Float16)acc[r];
    }
  }
  // z-gate MFMA (transposed): D[zd][token]; wave w owns token-tile w.
  // A = Wz rows (global, L2-hot, cvt to h16), B = u tokens from uH.
  // Result kept in regs across the x-proj phase (xdS overlays uH).
  f32x4 zacc[4];
  {
    f16x8 bf = *(const f16x8*)&U.s.uH[3 + w * 16 + rsel][ksel];
#pragma unroll
    for (int mt = 0; mt < 4; ++mt) {
      const float* wp = in_W + (64 + mt * 16 + rsel) * 32 + ksel;
      float4 w0 = *(const float4*)wp;
      float4 w1 = *(const float4*)(wp + 4);
      f16x8 af;
      af[0] = (_Float16)w0.x; af[1] = (_Float16)w0.y;
      af[2] = (_Float16)w0.z; af[3] = (_Float16)w0.w;
      af[4] = (_Float16)w1.x; af[5] = (_Float16)w1.y;
      af[6] = (_Float16)w1.z; af[7] = (_Float16)w1.w;
      f32x4 acc = {0.f, 0.f, 0.f, 0.f};
      zacc[mt] = __builtin_amdgcn_mfma_f32_16x16x32_f16(af, bf, acc, 0, 0, 0);
    }
  }
  __syncthreads();

  // causal depthwise conv + silu; write xH (x-proj A operand) + SX2 inline
  h16* SXp = SX2 + ((size_t)i * L_ + t0) * DI;
  for (int k = tid; k < 4096; k += 256) {
    int r = k >> 6, d = k & 63;
    float v = cbS[d];
#pragma unroll
    for (int j = 0; j < 4; ++j) v = fmaf(convWS[d][j], (float)preH[r + j][d], v);
    v = siluf_(v);
    xH[r][d] = (_Float16)v;
    SXp[(size_t)r * DI + d] = (h16)v;
  }
  __syncthreads();

  // x-proj MFMA: wave w owns M-tile mt=w; K=64 as 2 chunks; N padded to 48
  {
    int mt = w;
    f16x8 a0 = *(const f16x8*)&xH[mt * 16 + rsel][ksel];
    f16x8 a1 = *(const f16x8*)&xH[mt * 16 + rsel][32 + ksel];
    int row0 = mt * 16 + ((lane >> 4) << 2);
#pragma unroll
    for (int nt = 0; nt < 3; ++nt) {
      f16x8 b0 = *(const f16x8*)&w2H[nt * 16 + rsel][ksel];
      f16x8 b1 = *(const f16x8*)&w2H[nt * 16 + rsel][32 + ksel];
      f32x4 acc = {0.f, 0.f, 0.f, 0.f};
      acc = __builtin_amdgcn_mfma_f32_16x16x32_f16(a0, b0, acc, 0, 0, 0);
      acc = __builtin_amdgcn_mfma_f32_16x16x32_f16(a1, b1, acc, 0, 0, 0);
      int col = nt * 16 + rsel;
      if (col < 34) {
#pragma unroll
        for (int r = 0; r < 4; ++r) U.xdS[row0 + r][col] = acc[r];
      }
    }
  }
  __syncthreads();

  h16* SDTp = SDT2 + ((size_t)i * L_ + t0) * DI;
  for (int k = tid; k < 4096; k += 256) {
    int d = k & 63, r = k >> 6;
    float raw = fmaf(U.xdS[r][0], dtWS[d][0], fmaf(U.xdS[r][1], dtWS[d][1], dtbS[d]));
    SDTp[(size_t)r * DI + d] = (h16)softplusf_(raw);
  }
  h16* SBp = SB2 + ((size_t)i * L_ + t0) * DS;
  h16* SCp = SC2 + ((size_t)i * L_ + t0) * DS;
  for (int k = tid; k < 1024; k += 256) {
    int s = k & 15, r = k >> 4;
    SBp[(size_t)r * DS + s] = (h16)U.xdS[r][2 + s];
    SCp[(size_t)r * DS + s] = (h16)U.xdS[r][18 + s];
  }
  __syncthreads();   // xdS fully consumed; reuse union as zL

  // z writeout: pack 4 consecutive zd per lane into LDS, then coalesced global
  {
    int tok = w * 16 + rsel;
    int zq = (lane >> 4) << 2;
#pragma unroll
    for (int mt = 0; mt < 4; ++mt) {
      f16x4 pk;
#pragma unroll
      for (int r = 0; r < 4; ++r) pk[r] = (_Float16)siluf_(zacc[mt][r]);
      *(f16x4*)&U.zL[tok][mt * 16 + zq] = pk;
    }
  }
  __syncthreads();
  h16* SZp = SZ2 + ((size_t)i * L_ + t0) * DI;
  for (int k = tid; k < 512; k += 256) {
    int r = k >> 3, dblk = (k & 7) * 8;
    f16x8 v = *(const f16x8*)&U.zL[r][dblk];
    *(f16x8*)&SZp[(size_t)r * DI + dblk] = v;
  }
}

// ---------------- K3a: per-segment local scan (d-per-thread) -> (P, Q) ----------------
__global__ __launch_bounds__(256) void k3a_seg(
    const float* __restrict__ A_log, const h16* __restrict__ SDT2,
    const h16* __restrict__ SX2, const h16* __restrict__ SB2,
    float* __restrict__ Pp, float* __restrict__ Qp) {
  int bid = blockIdx.x;             // i*32 + sg
  int i = bid >> 5, sg = bid & 31;
  int tid = threadIdx.x;
  int w = tid >> 6, lane = tid & 63;
  int seg = sg * 4 + w;
  int t0 = seg * SL;
  __shared__ float bS[4][SL][20];
  {
    int tk = lane & 31, hf = lane >> 5;
    const h16* pb = SB2 + ((size_t)i * L_ + t0 + tk) * DS + hf * 8;
    float4 r0 = *(const float4*)pb;
    const h16* h0p = (const h16*)&r0;
#pragma unroll
    for (int s = 0; s < 8; ++s) bS[w][tk][hf * 8 + s] = (float)h0p[s];
  }
  __syncthreads();
  float Av[16];
#pragma unroll
  for (int s = 0; s < 16; ++s) Av[s] = -__expf(A_log[lane * 16 + s]);
  float A0 = Av[0];
  bool okf = true;
#pragma unroll
  for (int s = 0; s < 16; ++s) okf &= fabsf(Av[s] - (float)(s + 1) * A0) <= 1e-4f * fabsf(Av[s]);
  int fastp = __all(okf ? 1 : 0);
  float h[16];
#pragma unroll
  for (int s = 0; s < 16; ++s) h[s] = 0.f;
  float sdt = 0.f;
  const h16* pdt = SDT2 + ((size_t)i * L_ + t0) * DI + lane;
  const h16* pxx = SX2 + ((size_t)i * L_ + t0) * DI + lane;
  float dtc = (float)pdt[0], xvc = (float)pxx[0];
  for (int t = 0; t < SL; ++t) {
    float dt = dtc, xv = xvc;
    if (t < SL - 1) { dtc = (float)pdt[(t + 1) * DI]; xvc = (float)pxx[(t + 1) * DI]; }
    float Bv[16];
    const float* row = &bS[w][t][0];
#pragma unroll
    for (int j = 0; j < 4; ++j) *(float4*)&Bv[4 * j] = *(const float4*)(row + 4 * j);
    float dtx = dt * xv;
    float dA[16];
    if (fastp) {
      powladder_(__expf(A0 * dt), dA);
    } else {
#pragma unroll
      for (int s = 0; s < 16; ++s) dA[s] = __expf(Av[s] * dt);
    }
#pragma unroll
    for (int s = 0; s < 16; ++s) h[s] = fmaf(dA[s], h[s], dtx * Bv[s]);
    sdt += dt;
  }
  float P[16];
  if (fastp) {
    powladder_(__expf(A0 * sdt), P);
  } else {
#pragma unroll
    for (int s = 0; s < 16; ++s) P[s] = __expf(Av[s] * sdt);
  }
  size_t base = (((size_t)i * DI + lane) * NSEG + seg) * DS;
#pragma unroll
  for (int j = 0; j < 4; ++j) {
    *(float4*)(Pp + base + 4 * j) = *(float4*)&P[4 * j];
    *(float4*)(Qp + base + 4 * j) = *(float4*)&h[4 * j];
  }
}

// ---------------- K3b: inter-segment scan -> h0 per segment (overlays P) ----------------
__global__ __launch_bounds__(256) void k3b_comb(float* __restrict__ Pp,
                                                const float* __restrict__ Qp) {
  int g = blockIdx.x * 256 + threadIdx.x;  // 32768 = NI*DI*DS
  int s = g & 15;
  int r = g >> 4;          // over NI*DI
  size_t base = (size_t)r * NSEG * DS + s;
  float H = 0.f;
  for (int seg = 0; seg < NSEG; ++seg) {
    size_t a = base + (size_t)seg * DS;
    float P = Pp[a], Q = Qp[a];
    Pp[a] = H;
    H = fmaf(P, H, Q);
  }
}

// ---------------- K3c: final scan, fused with D-term/z-gate-mult/token-sums ----
// z-gate precomputed (SZ2 = silu(z)); no u staging, no in_W; LDS 18.4 KB.
__global__ __launch_bounds__(256) void k3c_scan(
    const float* __restrict__ A_log, const h16* __restrict__ SDT2,
    const h16* __restrict__ SX2, const h16* __restrict__ SB2,
    const h16* __restrict__ SC2, const h16* __restrict__ SZ2,
    const float* __restrict__ D_p, const float* __restrict__ H0p,
    h16* __restrict__ YS2, float* __restrict__ SUMYF) {
  int bid = blockIdx.x;             // i*32 + sg
  int i = bid >> 5, sg = bid & 31;
  int tid = threadIdx.x;
  int w = tid >> 6, lane = tid & 63;
  int seg = sg * 4 + w;
  int t0 = seg * SL;
  __shared__ float rowS[4][SL][36];   // [w][t][ B16 | C16 ] + pad
  {
    int tk = lane & 31, hf = lane >> 5;
    const h16* p = (hf ? SC2 : SB2) + ((size_t)i * L_ + t0 + tk) * DS;
    float4 r0 = *(const float4*)p;
    float4 r1 = *(const float4*)(p + 8);
    const h16* hp0 = (const h16*)&r0;
    const h16* hp1 = (const h16*)&r1;
#pragma unroll
    for (int s = 0; s < 8; ++s) {
      rowS[w][tk][hf * 16 + s] = (float)hp0[s];
      rowS[w][tk][hf * 16 + 8 + s] = (float)hp1[s];
    }
  }
  __syncthreads();
  float Av[16];
#pragma unroll
  for (int s = 0; s < 16; ++s) Av[s] = -__expf(A_log[lane * 16 + s]);
  float A0 = Av[0];
  bool okf = true;
#pragma unroll
  for (int s = 0; s < 16; ++s) okf &= fabsf(Av[s] - (float)(s + 1) * A0) <= 1e-4f * fabsf(Av[s]);
  int fastp = __all(okf ? 1 : 0);
  float Dp = D_p[lane];
  float h[16];
  {
    size_t base = (((size_t)i * DI + lane) * NSEG + seg) * DS;
#pragma unroll
    for (int j = 0; j < 4; ++j) *(float4*)&h[4 * j] = *(const float4*)(H0p + base + 4 * j);
  }
  const h16* pdt = SDT2 + ((size_t)i * L_ + t0) * DI + lane;
  const h16* pxx = SX2 + ((size_t)i * L_ + t0) * DI + lane;
  const h16* pzz = SZ2 + ((size_t)i * L_ + t0) * DI + lane;
  h16* pys = YS2 + ((size_t)i * L_ + t0) * DI + lane;
  float dtc = (float)pdt[0], xvc = (float)pxx[0], zvc = (float)pzz[0];
  float sum = 0.f;
  for (int t = 0; t < SL; ++t) {
    float dt = dtc, xv = xvc, zv = zvc;
    if (t < SL - 1) {
      dtc = (float)pdt[(t + 1) * DI];
      xvc = (float)pxx[(t + 1) * DI];
      zvc = (float)pzz[(t + 1) * DI];
    }
    const float* row = &rowS[w][t][0];
    float Bv[16], Cv[16];
#pragma unroll
    for (int j = 0; j < 4; ++j) {
      *(float4*)&Bv[4 * j] = *(const float4*)(row + 4 * j);
      *(float4*)&Cv[4 * j] = *(const float4*)(row + 16 + 4 * j);
    }
    float dtx = dt * xv;
    float dA[16];
    if (fastp) {
      powladder_(__expf(A0 * dt), dA);
    } else {
#pragma unroll
      for (int s = 0; s < 16; ++s) dA[s] = __expf(Av[s] * dt);
    }
    float y0 = 0.f, y1 = 0.f, y2 = 0.f, y3 = 0.f;
#pragma unroll
    for (int s = 0; s < 16; s += 4) {
      h[s] = fmaf(dA[s], h[s], dtx * Bv[s]);       y0 = fmaf(h[s], Cv[s], y0);
      h[s + 1] = fmaf(dA[s + 1], h[s + 1], dtx * Bv[s + 1]); y1 = fmaf(h[s + 1], Cv[s + 1], y1);
      h[s + 2] = fmaf(dA[s + 2], h[s + 2], dtx * Bv[s + 2]); y2 = fmaf(h[s + 2], Cv[s + 2], y2);
      h[s + 3] = fmaf(dA[s + 3], h[s + 3], dtx * Bv[s + 3]); y3 = fmaf(h[s + 3], Cv[s + 3], y3);
    }
    float y = (y0 + y1) + (y2 + y3);
    float yf = fmaf(xv, Dp, y) * zv;
    pys[(size_t)t * DI] = (h16)yf;
    sum += yf;
  }
  atomicAdd(&SUMYF[i * DI + lane], sum);
}

// ---------------- K4: SE gates ----------------
__global__ __launch_bounds__(64) void k4_gates(
    const float* __restrict__ out_W, const float* __restrict__ se_W1,
    const float* __restrict__ se_W2, const float* __restrict__ skip_p,
    const float* __restrict__ SUMYF, const float* __restrict__ SUMXN,
    float* __restrict__ GATES) {
  int i = blockIdx.x;
  int b = i >> 2, ch = i & 3;
  int tid = threadIdx.x;
  __shared__ float syS[64], catS[64], seS[2];
  syS[tid] = SUMYF[i * DI + tid];
  __syncthreads();
  float invL = 1.f / (float)L_;
  if (tid < 32) {
    float acc = 0.f;
#pragma unroll
    for (int dd = 0; dd < 64; ++dd) acc = fmaf(syS[dd], out_W[tid * 64 + dd], acc);
    catS[tid] = acc * invL;
  } else {
    int c = tid - 32;
    catS[tid] = skip_p[0] * SUMXN[b * C_ + ch * DM + c] * invL;
  }
  __syncthreads();
  if (tid < 2) {
    float acc = 0.f;
#pragma unroll
    for (int k = 0; k < 64; ++k) acc = fmaf(catS[k], se_W1[tid * 64 + k], acc);
    seS[tid] = fmaxf(acc, 0.f);
  }
  __syncthreads();
  float gg = fmaf(seS[0], se_W2[tid * 2 + 0], seS[1] * se_W2[tid * 2 + 1]);
  GATES[i * DI + tid] = sigmoidf_(gg);
}

// ---------------- K5b: M1 = yfull @ outW.T, gated combine (in place over xn) ----------------
__global__ __launch_bounds__(256) void k5b_combine(
    const float* __restrict__ out_W, const float* __restrict__ skip_p,
    const float* __restrict__ GATES, const h16* __restrict__ YS2,
    float* __restrict__ XN) {
  int bid = blockIdx.x;
  int i = bid >> 6, tile = bid & 63;
  int b = i >> 2, ch = i & 3;
  int t0 = tile * 64;
  int tid = threadIdx.x;
  int w = tid >> 6, lane = tid & 63;
  __shared__ float outWS[32][68];
  __shared__ float yfT[64][65];
  __shared__ float xnS[64][37];
  __shared__ float gS[64];
  for (int k = tid; k < 2048; k += 256) outWS[k >> 6][k & 63] = out_W[k];
  if (tid < 64) gS[tid] = GATES[i * DI + tid];
  const h16* py = YS2 + ((size_t)i * L_ + t0) * DI;
  for (int k = tid; k < 4096; k += 256) {
    int dd = k & 63, tt = k >> 6;
    yfT[tt][dd] = (float)py[(size_t)tt * DI + dd];
  }
  float* xn = XN + (size_t)b * L_ * C_ + ch * DM;
  for (int k = tid; k < 2048; k += 256) {
    int tt = k >> 5, o = k & 31;
    xnS[tt][o] = xn[(size_t)(t0 + tt) * C_ + o];
  }
  __syncthreads();
  float yr[64];
#pragma unroll
  for (int dd = 0; dd < 64; ++dd) yr[dd] = yfT[lane][dd];
  float skip = skip_p[0];
#pragma unroll
  for (int q = 0; q < 8; ++q) {
    int o = w * 8 + q;
    float a = 0.f;
#pragma unroll
    for (int d4 = 0; d4 < 64; d4 += 4) {
      float4 wv = *(const float4*)&outWS[o][d4];
      a = fmaf(yr[d4], wv.x, a);
      a = fmaf(yr[d4 + 1], wv.y, a);
      a = fmaf(yr[d4 + 2], wv.z, a);
      a = fmaf(yr[d4 + 3], wv.w, a);
    }
    xnS[lane][o] = gS[o] * a + gS[32 + o] * skip * xnS[lane][o];
  }
  __syncthreads();
  for (int k = tid; k < 2048; k += 256) {
    int tt = k >> 5, o = k & 31;
    xn[(size_t)(t0 + tt) * C_ + o] = xnS[tt][o];
  }
}

// ---------------- K6: LN2 + proj + transpose to (B,OUT,H,W) ----------------
__global__ __launch_bounds__(256) void k6_ln_proj(
    const float* __restrict__ gn, const float* __restrict__ bn,
    const float* __restrict__ proj_W, const float* __restrict__ proj_b,
    const float* __restrict__ XN, float* __restrict__ out) {
  int bid = blockIdx.x;
  int b = bid >> 6, tile = bid & 63;
  int t0 = tile * 64;
  int tid = threadIdx.x;
  int w = tid >> 6, lane = tid & 63;
  __shared__ float xmS[64][132];
  __shared__ float projS[64][132];
  __shared__ float gnS[128], bnS[128];
  if (tid < 128) { gnS[tid] = gn[tid]; bnS[tid] = bn[tid]; }
  const float* xm = XN + (size_t)b * L_ * C_;
  for (int k = tid; k < 8192; k += 256) {
    int tt = k >> 7, c = k & 127;
    xmS[tt][c] = xm[(size_t)(t0 + tt) * C_ + c];
  }
  for (int k = tid; k < 8192; k += 256) {
    int o = k >> 7, c = k & 127;
    projS[o][c] = proj_W[k];
  }
  __syncthreads();
  {
    int tok = tid >> 2, q = tid & 3;
    float s = 0.f, qq = 0.f;
#pragma unroll
    for (int j = 0; j < 32; ++j) {
      float v = xmS[tok][4 * j + q];
      s += v; qq += v * v;
    }
    s = dpp_add_<0xB1>(s); qq = dpp_add_<0xB1>(qq);
    s = dpp_add_<0x4E>(s); qq = dpp_add_<0x4E>(qq);
    float m = s * (1.f / 128.f);
    float var = qq * (1.f / 128.f) - m * m;
    float rs = rsqrtf(var + 1e-5f);
#pragma unroll
    for (int j = 0; j < 32; ++j) {
      int c = 4 * j + q;
      float v = xmS[tok][c];
      xmS[tok][c] = (v - m) * rs * gnS[c] + bnS[c];
    }
  }
  __syncthreads();
  int lt = lane >> 2, lo = lane & 3;
  for (int phase = 0; phase < 2; ++phase) {
    if (phase == 1) {
      __syncthreads();
      for (int k = tid; k < 8192; k += 256) {
        int o = k >> 7, c = k & 127;
        projS[o][c] = proj_W[8192 + k];
      }
      __syncthreads();
    }
    int obase = phase * 64 + w * 16 + lo * 4;
    float acc[16];
#pragma unroll
    for (int j = 0; j < 4; ++j)
#pragma unroll
      for (int oi = 0; oi < 4; ++oi) acc[j * 4 + oi] = proj_b[obase + oi];
#pragma unroll 4
    for (int c0 = 0; c0 < 128; c0 += 4) {
      float4 xr[4], pr[4];
#pragma unroll
      for (int j = 0; j < 4; ++j) xr[j] = *(const float4*)&xmS[lt * 4 + j][c0];
#pragma unroll
      for (int oi = 0; oi < 4; ++oi) pr[oi] = *(const float4*)&projS[w * 16 + lo * 4 + oi][c0];
#pragma unroll
      for (int j = 0; j < 4; ++j)
#pragma unroll
        for (int oi = 0; oi < 4; ++oi) {
          float a = acc[j * 4 + oi];
          a = fmaf(xr[j].x, pr[oi].x, a);
          a = fmaf(xr[j].y, pr[oi].y, a);
          a = fmaf(xr[j].z, pr[oi].z, a);
          a = fmaf(xr[j].w, pr[oi].w, a);
          acc[j * 4 + oi] = a;
        }
    }
#pragma unroll
    for (int oi = 0; oi < 4; ++oi) {
      int o = obase + oi;
      float4 v = make_float4(acc[0 * 4 + oi], acc[1 * 4 + oi],
                             acc[2 * 4 + oi], acc[3 * 4 + oi]);
      *(float4*)&out[((size_t)(b * OUT_ + o)) * L_ + t0 + lt * 4] = v;
    }
  }
}

extern "C" void kernel_launch(void* const* d_in, const int* in_sizes, int n_in,
                              void* d_out, int out_size, void* d_ws, size_t ws_size,
                              hipStream_t stream) {
  const float* x = (const float*)d_in[0];
  const float* norm_g = (const float*)d_in[1];
  const float* norm_b = (const float*)d_in[2];
  const float* proj_W = (const float*)d_in[3];
  const float* proj_b = (const float*)d_in[4];
  const float* skip = (const float*)d_in[5];
  const float* se_W1 = (const float*)d_in[6];
  const float* se_W2 = (const float*)d_in[7];
  const float* in_W = (const float*)d_in[8];
  const float* conv_W = (const float*)d_in[9];
  const float* conv_b = (const float*)d_in[10];
  const float* xproj_W = (const float*)d_in[11];
  const float* dt_W = (const float*)d_in[12];
  const float* dt_b = (const float*)d_in[13];
  const float* A_log = (const float*)d_in[14];
  const float* D_p = (const float*)d_in[15];
  const float* out_W = (const float*)d_in[16];
  float* out = (float*)d_out;

  // workspace (~126 MiB)
  float* XN = (float*)d_ws;                         // B*L*C f32
  float* SUMYF = XN + (size_t)B_ * L_ * C_;         // NI*DI
  float* SUMXN = SUMYF + NI * DI;                   // B*C
  float* GATES = SUMXN + B_ * C_;                   // NI*DI
  float* Pp = GATES + NI * DI;                      // NI*DI*NSEG*DS f32
  float* Qp = Pp + (size_t)NI * DI * NSEG * DS;
  h16* YS2 = (h16*)(Qp + (size_t)NI * DI * NSEG * DS);  // NI*L*DI h16
  h16* SX2 = YS2 + (size_t)NI * L_ * DI;
  h16* SDT2 = SX2 + (size_t)NI * L_ * DI;
  h16* SB2 = SDT2 + (size_t)NI * L_ * DI;           // NI*L*DS h16
  h16* SC2 = SB2 + (size_t)NI * L_ * DS;
  h16* SZ2 = SC2 + (size_t)NI * L_ * DS;            // NI*L*DI h16 (silu(z))

  hipMemsetAsync(SUMYF, 0, (size_t)(NI * DI + B_ * C_) * sizeof(float), stream);
  k1_ln<<<B_ * 64, 256, 0, stream>>>(x, norm_g, norm_b, XN, SUMXN);
  k2_prep<<<NI * 64, 256, 0, stream>>>(in_W, conv_W, conv_b, xproj_W, dt_W, dt_b,
                                       XN, SX2, SDT2, SB2, SC2, SZ2);
  k3a_seg<<<NI * 32, 256, 0, stream>>>(A_log, SDT2, SX2, SB2, Pp, Qp);
  k3b_comb<<<128, 256, 0, stream>>>(Pp, Qp);
  k3c_scan<<<NI * 32, 256, 0, stream>>>(A_log, SDT2, SX2, SB2, SC2, SZ2, D_p,
                                        Pp, YS2, SUMYF);
  k4_gates<<<NI, 64, 0, stream>>>(out_W, se_W1, se_W2, skip, SUMYF, SUMXN, GATES);
  k5b_combine<<<NI * 64, 256, 0, stream>>>(out_W, skip, GATES, YS2, XN);
  k6_ln_proj<<<B_ * 64, 256, 0, stream>>>(norm_g, norm_b, proj_W, proj_b, XN, out);
}

// Round 3
// 242.176 us; speedup vs baseline: 1.2254x; 1.1250x over previous
//
#include <hip/hip_runtime.h>
#include <math.h>

typedef _Float16 h16;

#define DEV static __device__ __forceinline__

constexpr int B_ = 8, C_ = 128, L_ = 4096, OUT_ = 128;
constexpr int NCH = 4, DM = 32, DS = 16, DI = 64;
constexpr int NI = 32;            // B_*NCH instances
constexpr int NSEG = 128;         // scan segments
constexpr int SL = L_ / NSEG;     // 32 steps per segment

DEV float sigmoidf_(float x) { return 1.f / (1.f + __expf(-x)); }
DEV float siluf_(float x) { return x * sigmoidf_(x); }
DEV float softplusf_(float x) { return (x > 20.f) ? x : __logf(1.f + __expf(x)); }

template <int CTRL>
DEV float dpp_add_(float x) {
  int v = __builtin_amdgcn_update_dpp(0, __float_as_int(x), CTRL, 0xf, 0xf, false);
  return x + __int_as_float(v);
}

typedef __attribute__((ext_vector_type(8))) _Float16 f16x8;
typedef __attribute__((ext_vector_type(4))) _Float16 f16x4;
typedef __attribute__((ext_vector_type(4))) float f32x4;

// log-depth powers: out[s] = E^(s+1), dep depth ~5 instead of 15
DEV void powladder_(float E, float* out) {
  float E2 = E * E;
  float E4 = E2 * E2;
  float E8 = E4 * E4;
  float E3 = E2 * E;
  out[0] = E;       out[1] = E2;      out[2] = E3;      out[3] = E4;
  out[4] = E4 * E;  out[5] = E4 * E2; out[6] = E4 * E3; out[7] = E8;
  out[8] = E8 * E;  out[9] = E8 * E2; out[10] = E8 * E3; out[11] = E8 * E4;
  out[12] = E8 * out[4]; out[13] = E8 * out[5]; out[14] = E8 * out[6];
  out[15] = E8 * E8;
}

// ---------------- K1: LayerNorm1 (B,C,L)->(B,L,C) + token sums ----------------
__global__ __launch_bounds__(256) void k1_ln(const float* __restrict__ x,
                                             const float* __restrict__ gn,
                                             const float* __restrict__ bn,
                                             float* __restrict__ XN,
                                             float* __restrict__ SUMXN) {
  int bid = blockIdx.x;
  int b = bid >> 6, tile = bid & 63;
  int t0 = tile * 64;
  int tid = threadIdx.x;
  __shared__ float xT[128][65];
  __shared__ float gnS[128], bnS[128];
  __shared__ float red[256];
  if (tid < 128) { gnS[tid] = gn[tid]; bnS[tid] = bn[tid]; }
  for (int k = tid; k < 8192; k += 256) {
    int c = k >> 6, tt = k & 63;
    xT[c][tt] = x[((size_t)(b * C_ + c)) * L_ + t0 + tt];
  }
  __syncthreads();
  {
    int tok = tid >> 2, q = tid & 3;
    float s = 0.f, qq = 0.f;
#pragma unroll
    for (int j = 0; j < 32; ++j) {
      float v = xT[q + 4 * j][tok];
      s += v; qq += v * v;
    }
    s = dpp_add_<0xB1>(s); qq = dpp_add_<0xB1>(qq);
    s = dpp_add_<0x4E>(s); qq = dpp_add_<0x4E>(qq);
    float m = s * (1.f / 128.f);
    float var = qq * (1.f / 128.f) - m * m;
    float rs = rsqrtf(var + 1e-5f);
#pragma unroll
    for (int j = 0; j < 32; ++j) {
      int c = q + 4 * j;
      float v = xT[c][tok];
      xT[c][tok] = (v - m) * rs * gnS[c] + bnS[c];
    }
  }
  __syncthreads();
  float acc = 0.f;
  int cfix = tid & 127;
  for (int k = tid; k < 8192; k += 256) {
    int tt = k >> 7, c = k & 127;
    float v = xT[c][tt];
    XN[((size_t)(b * L_ + t0 + tt)) * C_ + c] = v;
    acc += v;
  }
  red[tid] = acc;
  __syncthreads();
  if (tid < 128) atomicAdd(&SUMXN[b * C_ + cfix], red[tid] + red[tid + 128]);
}

// ---------------- K2: in-proj + conv + silu + x-proj + dt + z-gate (MFMA) -----
__global__ __launch_bounds__(256) void k2_prep(
    const float* __restrict__ in_W, const float* __restrict__ conv_W,
    const float* __restrict__ conv_b, const float* __restrict__ xproj_W,
    const float* __restrict__ dt_W, const float* __restrict__ dt_b,
    const float* __restrict__ XN, h16* __restrict__ SX2, h16* __restrict__ SDT2,
    h16* __restrict__ SB2, h16* __restrict__ SC2, h16* __restrict__ SZ2) {
  int bid = blockIdx.x;
  int i = bid >> 6, tile = bid & 63;
  int b = i >> 2, ch = i & 3;
  int t0 = tile * 64;
  int tid = threadIdx.x;
  int w = __builtin_amdgcn_readfirstlane(tid >> 6);
  int lane = tid & 63;

  // union: staging (u + x-half of in_W) | x-proj output | z transpose bounce
  __shared__ __attribute__((aligned(16))) union {
    struct {
      _Float16 uH[80][40];   // rows 0..66 = tokens t0-3..t0+63; 67..79 zero
      _Float16 w1H[64][40];  // in_W x-half, row=d, col=c
    } s;
    float xdS[64][36];       // x-proj output, row=token, col=o (34 used)
    _Float16 zL[64][88];     // silu(z) bounce, row=token, col=zd (stride 88: no 4-way)
  } U;
  __shared__ __attribute__((aligned(16))) _Float16 preH[80][66];  // in-proj out
  __shared__ __attribute__((aligned(16))) _Float16 xH[64][72];    // conv+silu out
  __shared__ __attribute__((aligned(16))) _Float16 w2H[48][72];   // xproj_W, pad rows 34..47 = 0
  __shared__ float convWS[64][4];
  __shared__ float dtWS[64][2];
  __shared__ float dtbS[64], cbS[64];

  convWS[tid >> 2][tid & 3] = conv_W[tid];
  if (tid < 128) dtWS[tid >> 1][tid & 1] = dt_W[tid];
  if (tid < 64) { dtbS[tid] = dt_b[tid]; cbS[tid] = conv_b[tid]; }
  const float* xn = XN + (size_t)b * L_ * C_ + ch * DM;
  for (int k = tid; k < 80 * 32; k += 256) {
    int r = k >> 5, c = k & 31;
    int tg = t0 - 3 + r;
    float v = (r < 67 && tg >= 0) ? xn[(size_t)tg * C_ + c] : 0.f;
    U.s.uH[r][c] = (_Float16)v;
  }
  for (int k = tid; k < 2048; k += 256) U.s.w1H[k >> 5][k & 31] = (_Float16)in_W[k];
  for (int k = tid; k < 48 * 64; k += 256) {
    int r = k >> 6, c = k & 63;
    w2H[r][c] = (r < 34) ? (_Float16)xproj_W[r * 64 + c] : (_Float16)0.f;
  }
  __syncthreads();

  int rsel = lane & 15, ksel = (lane >> 4) * 8;
  // in-proj MFMA: wave w owns N-tile nt=w (B-frag loaded once), loops 5 M-tiles
  {
    int nt = w;
    f16x8 bf = *(const f16x8*)&U.s.w1H[nt * 16 + rsel][ksel];
    int row0q = (lane >> 4) << 2;
    int col = nt * 16 + rsel;
#pragma unroll
    for (int mt = 0; mt < 5; ++mt) {
      f16x8 af = *(const f16x8*)&U.s.uH[mt * 16 + rsel][ksel];
      f32x4 acc = {0.f, 0.f, 0.f, 0.f};
      acc = __builtin_amdgcn_mfma_f32_16x16x32_f16(af, bf, acc, 0, 0, 0);
      int row0 = mt * 16 + row0q;
#pragma unroll
      for (int r = 0; r < 4; ++r) preH[row0 + r][col] = (_Float16)acc[r];
    }
  }
  // z-gate MFMA (transposed): D[zd][token]; wave w owns token-tile w.
  f32x4 zacc[4];
  {
    f16x8 bf = *(const f16x8*)&U.s.uH[3 + w * 16 + rsel][ksel];
#pragma unroll
    for (int mt = 0; mt < 4; ++mt) {
      const float* wp = in_W + (64 + mt * 16 + rsel) * 32 + ksel;
      float4 w0 = *(const float4*)wp;
      float4 w1 = *(const float4*)(wp + 4);
      f16x8 af;
      af[0] = (_Float16)w0.x; af[1] = (_Float16)w0.y;
      af[2] = (_Float16)w0.z; af[3] = (_Float16)w0.w;
      af[4] = (_Float16)w1.x; af[5] = (_Float16)w1.y;
      af[6] = (_Float16)w1.z; af[7] = (_Float16)w1.w;
      f32x4 acc = {0.f, 0.f, 0.f, 0.f};
      zacc[mt] = __builtin_amdgcn_mfma_f32_16x16x32_f16(af, bf, acc, 0, 0, 0);
    }
  }
  __syncthreads();

  // causal depthwise conv + silu; write xH (x-proj A operand) + SX2 inline
  h16* SXp = SX2 + ((size_t)i * L_ + t0) * DI;
  for (int k = tid; k < 4096; k += 256) {
    int r = k >> 6, d = k & 63;
    float v = cbS[d];
#pragma unroll
    for (int j = 0; j < 4; ++j) v = fmaf(convWS[d][j], (float)preH[r + j][d], v);
    v = siluf_(v);
    xH[r][d] = (_Float16)v;
    SXp[(size_t)r * DI + d] = (h16)v;
  }
  __syncthreads();

  // x-proj MFMA: wave w owns M-tile mt=w; K=64 as 2 chunks; N padded to 48
  {
    int mt = w;
    f16x8 a0 = *(const f16x8*)&xH[mt * 16 + rsel][ksel];
    f16x8 a1 = *(const f16x8*)&xH[mt * 16 + rsel][32 + ksel];
    int row0 = mt * 16 + ((lane >> 4) << 2);
#pragma unroll
    for (int nt = 0; nt < 3; ++nt) {
      f16x8 b0 = *(const f16x8*)&w2H[nt * 16 + rsel][ksel];
      f16x8 b1 = *(const f16x8*)&w2H[nt * 16 + rsel][32 + ksel];
      f32x4 acc = {0.f, 0.f, 0.f, 0.f};
      acc = __builtin_amdgcn_mfma_f32_16x16x32_f16(a0, b0, acc, 0, 0, 0);
      acc = __builtin_amdgcn_mfma_f32_16x16x32_f16(a1, b1, acc, 0, 0, 0);
      int col = nt * 16 + rsel;
      if (col < 34) {
#pragma unroll
        for (int r = 0; r < 4; ++r) U.xdS[row0 + r][col] = acc[r];
      }
    }
  }
  __syncthreads();

  h16* SDTp = SDT2 + ((size_t)i * L_ + t0) * DI;
  for (int k = tid; k < 4096; k += 256) {
    int d = k & 63, r = k >> 6;
    float raw = fmaf(U.xdS[r][0], dtWS[d][0], fmaf(U.xdS[r][1], dtWS[d][1], dtbS[d]));
    SDTp[(size_t)r * DI + d] = (h16)softplusf_(raw);
  }
  h16* SBp = SB2 + ((size_t)i * L_ + t0) * DS;
  h16* SCp = SC2 + ((size_t)i * L_ + t0) * DS;
  for (int k = tid; k < 1024; k += 256) {
    int s = k & 15, r = k >> 4;
    SBp[(size_t)r * DS + s] = (h16)U.xdS[r][2 + s];
    SCp[(size_t)r * DS + s] = (h16)U.xdS[r][18 + s];
  }
  __syncthreads();   // xdS fully consumed; reuse union as zL

  // z writeout: pack 4 consecutive zd per lane into LDS, then coalesced global
  {
    int tok = w * 16 + rsel;
    int zq = (lane >> 4) << 2;
#pragma unroll
    for (int mt = 0; mt < 4; ++mt) {
      f16x4 pk;
#pragma unroll
      for (int r = 0; r < 4; ++r) pk[r] = (_Float16)siluf_(zacc[mt][r]);
      *(f16x4*)&U.zL[tok][mt * 16 + zq] = pk;
    }
  }
  __syncthreads();
  h16* SZp = SZ2 + ((size_t)i * L_ + t0) * DI;
  for (int k = tid; k < 512; k += 256) {
    int r = k >> 3, dblk = (k & 7) * 8;
    f16x8 v = *(const f16x8*)&U.zL[r][dblk];
    *(f16x8*)&SZp[(size_t)r * DI + dblk] = v;
  }
}

// ---------------- K3a: per-segment local scan (d-per-thread) -> (P, Q) ----------------
__global__ __launch_bounds__(256) void k3a_seg(
    const float* __restrict__ A_log, const h16* __restrict__ SDT2,
    const h16* __restrict__ SX2, const h16* __restrict__ SB2,
    float* __restrict__ Pp, float* __restrict__ Qp) {
  int bid = blockIdx.x;             // i*32 + sg
  int i = bid >> 5, sg = bid & 31;
  int tid = threadIdx.x;
  int w = tid >> 6, lane = tid & 63;
  int seg = sg * 4 + w;
  int t0 = seg * SL;
  __shared__ float bS[4][SL][20];
  {
    int tk = lane & 31, hf = lane >> 5;
    const h16* pb = SB2 + ((size_t)i * L_ + t0 + tk) * DS + hf * 8;
    float4 r0 = *(const float4*)pb;
    const h16* h0p = (const h16*)&r0;
#pragma unroll
    for (int s = 0; s < 8; ++s) bS[w][tk][hf * 8 + s] = (float)h0p[s];
  }
  __syncthreads();
  float Av[16];
#pragma unroll
  for (int s = 0; s < 16; ++s) Av[s] = -__expf(A_log[lane * 16 + s]);
  float A0 = Av[0];
  bool okf = true;
#pragma unroll
  for (int s = 0; s < 16; ++s) okf &= fabsf(Av[s] - (float)(s + 1) * A0) <= 1e-4f * fabsf(Av[s]);
  int fastp = __all(okf ? 1 : 0);
  float h[16];
#pragma unroll
  for (int s = 0; s < 16; ++s) h[s] = 0.f;
  float sdt = 0.f;
  const h16* pdt = SDT2 + ((size_t)i * L_ + t0) * DI + lane;
  const h16* pxx = SX2 + ((size_t)i * L_ + t0) * DI + lane;
  float dtc = (float)pdt[0], xvc = (float)pxx[0];
  for (int t = 0; t < SL; ++t) {
    float dt = dtc, xv = xvc;
    if (t < SL - 1) { dtc = (float)pdt[(t + 1) * DI]; xvc = (float)pxx[(t + 1) * DI]; }
    float Bv[16];
    const float* row = &bS[w][t][0];
#pragma unroll
    for (int j = 0; j < 4; ++j) *(float4*)&Bv[4 * j] = *(const float4*)(row + 4 * j);
    float dtx = dt * xv;
    float dA[16];
    if (fastp) {
      powladder_(__expf(A0 * dt), dA);
    } else {
#pragma unroll
      for (int s = 0; s < 16; ++s) dA[s] = __expf(Av[s] * dt);
    }
#pragma unroll
    for (int s = 0; s < 16; ++s) h[s] = fmaf(dA[s], h[s], dtx * Bv[s]);
    sdt += dt;
  }
  float P[16];
  if (fastp) {
    powladder_(__expf(A0 * sdt), P);
  } else {
#pragma unroll
    for (int s = 0; s < 16; ++s) P[s] = __expf(Av[s] * sdt);
  }
  size_t base = (((size_t)i * DI + lane) * NSEG + seg) * DS;
#pragma unroll
  for (int j = 0; j < 4; ++j) {
    *(float4*)(Pp + base + 4 * j) = *(float4*)&P[4 * j];
    *(float4*)(Qp + base + 4 * j) = *(float4*)&h[4 * j];
  }
}

// ---------------- K3b: inter-segment scan -> h0 per segment (overlays P) ----------------
__global__ __launch_bounds__(256) void k3b_comb(float* __restrict__ Pp,
                                                const float* __restrict__ Qp) {
  int g = blockIdx.x * 256 + threadIdx.x;  // 32768 = NI*DI*DS
  int s = g & 15;
  int r = g >> 4;          // over NI*DI
  size_t base = (size_t)r * NSEG * DS + s;
  float H = 0.f;
  for (int seg = 0; seg < NSEG; ++seg) {
    size_t a = base + (size_t)seg * DS;
    float P = Pp[a], Q = Qp[a];
    Pp[a] = H;
    H = fmaf(P, H, Q);
  }
}

// ---------------- K3c: final scan, fused with D-term/z-gate-mult/token-sums ----
__global__ __launch_bounds__(256) void k3c_scan(
    const float* __restrict__ A_log, const h16* __restrict__ SDT2,
    const h16* __restrict__ SX2, const h16* __restrict__ SB2,
    const h16* __restrict__ SC2, const h16* __restrict__ SZ2,
    const float* __restrict__ D_p, const float* __restrict__ H0p,
    h16* __restrict__ YS2, float* __restrict__ SUMYF) {
  int bid = blockIdx.x;             // i*32 + sg
  int i = bid >> 5, sg = bid & 31;
  int tid = threadIdx.x;
  int w = tid >> 6, lane = tid & 63;
  int seg = sg * 4 + w;
  int t0 = seg * SL;
  __shared__ float rowS[4][SL][36];   // [w][t][ B16 | C16 ] + pad
  {
    int tk = lane & 31, hf = lane >> 5;
    const h16* p = (hf ? SC2 : SB2) + ((size_t)i * L_ + t0 + tk) * DS;
    float4 r0 = *(const float4*)p;
    float4 r1 = *(const float4*)(p + 8);
    const h16* hp0 = (const h16*)&r0;
    const h16* hp1 = (const h16*)&r1;
#pragma unroll
    for (int s = 0; s < 8; ++s) {
      rowS[w][tk][hf * 16 + s] = (float)hp0[s];
      rowS[w][tk][hf * 16 + 8 + s] = (float)hp1[s];
    }
  }
  __syncthreads();
  float Av[16];
#pragma unroll
  for (int s = 0; s < 16; ++s) Av[s] = -__expf(A_log[lane * 16 + s]);
  float A0 = Av[0];
  bool okf = true;
#pragma unroll
  for (int s = 0; s < 16; ++s) okf &= fabsf(Av[s] - (float)(s + 1) * A0) <= 1e-4f * fabsf(Av[s]);
  int fastp = __all(okf ? 1 : 0);
  float Dp = D_p[lane];
  float h[16];
  {
    size_t base = (((size_t)i * DI + lane) * NSEG + seg) * DS;
#pragma unroll
    for (int j = 0; j < 4; ++j) *(float4*)&h[4 * j] = *(const float4*)(H0p + base + 4 * j);
  }
  const h16* pdt = SDT2 + ((size_t)i * L_ + t0) * DI + lane;
  const h16* pxx = SX2 + ((size_t)i * L_ + t0) * DI + lane;
  const h16* pzz = SZ2 + ((size_t)i * L_ + t0) * DI + lane;
  h16* pys = YS2 + ((size_t)i * L_ + t0) * DI + lane;
  float dtc = (float)pdt[0], xvc = (float)pxx[0], zvc = (float)pzz[0];
  float sum = 0.f;
  for (int t = 0; t < SL; ++t) {
    float dt = dtc, xv = xvc, zv = zvc;
    if (t < SL - 1) {
      dtc = (float)pdt[(t + 1) * DI];
      xvc = (float)pxx[(t + 1) * DI];
      zvc = (float)pzz[(t + 1) * DI];
    }
    const float* row = &rowS[w][t][0];
    float Bv[16], Cv[16];
#pragma unroll
    for (int j = 0; j < 4; ++j) {
      *(float4*)&Bv[4 * j] = *(const float4*)(row + 4 * j);
      *(float4*)&Cv[4 * j] = *(const float4*)(row + 16 + 4 * j);
    }
    float dtx = dt * xv;
    float dA[16];
    if (fastp) {
      powladder_(__expf(A0 * dt), dA);
    } else {
#pragma unroll
      for (int s = 0; s < 16; ++s) dA[s] = __expf(Av[s] * dt);
    }
    float y0 = 0.f, y1 = 0.f, y2 = 0.f, y3 = 0.f;
#pragma unroll
    for (int s = 0; s < 16; s += 4) {
      h[s] = fmaf(dA[s], h[s], dtx * Bv[s]);       y0 = fmaf(h[s], Cv[s], y0);
      h[s + 1] = fmaf(dA[s + 1], h[s + 1], dtx * Bv[s + 1]); y1 = fmaf(h[s + 1], Cv[s + 1], y1);
      h[s + 2] = fmaf(dA[s + 2], h[s + 2], dtx * Bv[s + 2]); y2 = fmaf(h[s + 2], Cv[s + 2], y2);
      h[s + 3] = fmaf(dA[s + 3], h[s + 3], dtx * Bv[s + 3]); y3 = fmaf(h[s + 3], Cv[s + 3], y3);
    }
    float y = (y0 + y1) + (y2 + y3);
    float yf = fmaf(xv, Dp, y) * zv;
    pys[(size_t)t * DI] = (h16)yf;
    sum += yf;
  }
  atomicAdd(&SUMYF[i * DI + lane], sum);
}

// ---------------- K4: SE gates ----------------
__global__ __launch_bounds__(64) void k4_gates(
    const float* __restrict__ out_W, const float* __restrict__ se_W1,
    const float* __restrict__ se_W2, const float* __restrict__ skip_p,
    const float* __restrict__ SUMYF, const float* __restrict__ SUMXN,
    float* __restrict__ GATES) {
  int i = blockIdx.x;
  int b = i >> 2, ch = i & 3;
  int tid = threadIdx.x;
  __shared__ float syS[64], catS[64], seS[2];
  syS[tid] = SUMYF[i * DI + tid];
  __syncthreads();
  float invL = 1.f / (float)L_;
  if (tid < 32) {
    float acc = 0.f;
#pragma unroll
    for (int dd = 0; dd < 64; ++dd) acc = fmaf(syS[dd], out_W[tid * 64 + dd], acc);
    catS[tid] = acc * invL;
  } else {
    int c = tid - 32;
    catS[tid] = skip_p[0] * SUMXN[b * C_ + ch * DM + c] * invL;
  }
  __syncthreads();
  if (tid < 2) {
    float acc = 0.f;
#pragma unroll
    for (int k = 0; k < 64; ++k) acc = fmaf(catS[k], se_W1[tid * 64 + k], acc);
    seS[tid] = fmaxf(acc, 0.f);
  }
  __syncthreads();
  float gg = fmaf(seS[0], se_W2[tid * 2 + 0], seS[1] * se_W2[tid * 2 + 1]);
  GATES[i * DI + tid] = sigmoidf_(gg);
}

// ---------------- K5b: M1 = yfull @ outW.T via MFMA, gated combine ------------
// A = YS2 tile (h16, t-major = A-frag layout), B = out_W rows (h16).
// 16 MFMA/block replaces 512 scalar FMA/thread.
__global__ __launch_bounds__(256) void k5b_combine(
    const float* __restrict__ out_W, const float* __restrict__ skip_p,
    const float* __restrict__ GATES, const h16* __restrict__ YS2,
    float* __restrict__ XN) {
  int bid = blockIdx.x;
  int i = bid >> 6, tile = bid & 63;
  int b = i >> 2, ch = i & 3;
  int t0 = tile * 64;
  int tid = threadIdx.x;
  int w = __builtin_amdgcn_readfirstlane(tid >> 6);
  int lane = tid & 63;
  __shared__ __attribute__((aligned(16))) _Float16 yH[64][72];
  __shared__ __attribute__((aligned(16))) _Float16 owH[32][72];
  __shared__ float xnS[64][37];
  __shared__ float gS[64];
  if (tid < 64) gS[tid] = GATES[i * DI + tid];
  const h16* py = YS2 + ((size_t)i * L_ + t0) * DI;
  for (int k = tid; k < 512; k += 256) {
    int tt = k >> 3, dblk = (k & 7) * 8;
    *(f16x8*)&yH[tt][dblk] = *(const f16x8*)&py[(size_t)tt * DI + dblk];
  }
  for (int k = tid; k < 2048; k += 256) owH[k >> 6][k & 63] = (_Float16)out_W[k];
  float* xn = XN + (size_t)b * L_ * C_ + ch * DM;
  for (int k = tid; k < 2048; k += 256) {
    int tt = k >> 5, o = k & 31;
    xnS[tt][o] = xn[(size_t)(t0 + tt) * C_ + o];
  }
  __syncthreads();
  int rsel = lane & 15, ksel = (lane >> 4) * 8;
  float skip = skip_p[0];
  int mt = w;
  f16x8 a0 = *(const f16x8*)&yH[mt * 16 + rsel][ksel];
  f16x8 a1 = *(const f16x8*)&yH[mt * 16 + rsel][32 + ksel];
  int row0 = mt * 16 + ((lane >> 4) << 2);
#pragma unroll
  for (int nt = 0; nt < 2; ++nt) {
    f16x8 b0 = *(const f16x8*)&owH[nt * 16 + rsel][ksel];
    f16x8 b1 = *(const f16x8*)&owH[nt * 16 + rsel][32 + ksel];
    f32x4 acc = {0.f, 0.f, 0.f, 0.f};
    acc = __builtin_amdgcn_mfma_f32_16x16x32_f16(a0, b0, acc, 0, 0, 0);
    acc = __builtin_amdgcn_mfma_f32_16x16x32_f16(a1, b1, acc, 0, 0, 0);
    int o = nt * 16 + rsel;
    float g1 = gS[o], g2s = gS[32 + o] * skip;
#pragma unroll
    for (int r = 0; r < 4; ++r) {
      int tok = row0 + r;
      xnS[tok][o] = g1 * acc[r] + g2s * xnS[tok][o];
    }
  }
  __syncthreads();
  for (int k = tid; k < 2048; k += 256) {
    int tt = k >> 5, o = k & 31;
    xn[(size_t)(t0 + tt) * C_ + o] = xnS[tt][o];
  }
}

// ---------------- K6: LN2 + proj (MFMA) + transpose to (B,OUT,H,W) ------------
// M=64 tok, N=128 out, K=128: 128 MFMA/block (32/wave) replaces 4096 FMA/thread.
__global__ __launch_bounds__(256) void k6_ln_proj(
    const float* __restrict__ gn, const float* __restrict__ bn,
    const float* __restrict__ proj_W, const float* __restrict__ proj_b,
    const float* __restrict__ XN, float* __restrict__ out) {
  int bid = blockIdx.x;
  int b = bid >> 6, tile = bid & 63;
  int t0 = tile * 64;
  int tid = threadIdx.x;
  int w = __builtin_amdgcn_readfirstlane(tid >> 6);
  int lane = tid & 63;
  // projH overlays xmS (dead after the h16 convert)
  __shared__ __attribute__((aligned(16))) union {
    float xmS[64][132];
    _Float16 projH[128][136];
  } U;
  __shared__ __attribute__((aligned(16))) _Float16 xmH[64][136];
  __shared__ float gnS[128], bnS[128];
  if (tid < 128) { gnS[tid] = gn[tid]; bnS[tid] = bn[tid]; }
  const float* xm = XN + (size_t)b * L_ * C_;
  for (int k = tid; k < 8192; k += 256) {
    int tt = k >> 7, c = k & 127;
    U.xmS[tt][c] = xm[(size_t)(t0 + tt) * C_ + c];
  }
  __syncthreads();
  {
    int tok = tid >> 2, q = tid & 3;
    float s = 0.f, qq = 0.f;
#pragma unroll
    for (int j = 0; j < 32; ++j) {
      float v = U.xmS[tok][4 * j + q];
      s += v; qq += v * v;
    }
    s = dpp_add_<0xB1>(s); qq = dpp_add_<0xB1>(qq);
    s = dpp_add_<0x4E>(s); qq = dpp_add_<0x4E>(qq);
    float m = s * (1.f / 128.f);
    float var = qq * (1.f / 128.f) - m * m;
    float rs = rsqrtf(var + 1e-5f);
#pragma unroll
    for (int j = 0; j < 32; ++j) {
      int c = 4 * j + q;
      float v = U.xmS[tok][c];
      U.xmS[tok][c] = (v - m) * rs * gnS[c] + bnS[c];
    }
  }
  __syncthreads();
  // convert LN output to h16 (vector reads/writes, 2-way banks)
  for (int k = tid; k < 1024; k += 256) {
    int tt = k >> 4, cblk = (k & 15) * 8;
    float4 v0 = *(const float4*)&U.xmS[tt][cblk];
    float4 v1 = *(const float4*)&U.xmS[tt][cblk + 4];
    f16x8 hv;
    hv[0] = (_Float16)v0.x; hv[1] = (_Float16)v0.y;
    hv[2] = (_Float16)v0.z; hv[3] = (_Float16)v0.w;
    hv[4] = (_Float16)v1.x; hv[5] = (_Float16)v1.y;
    hv[6] = (_Float16)v1.z; hv[7] = (_Float16)v1.w;
    *(f16x8*)&xmH[tt][cblk] = hv;
  }
  __syncthreads();
  // stage proj_W as h16 over the dead xmS
  for (int k = tid; k < 2048; k += 256) {
    int o = k >> 4, cblk = (k & 15) * 8;
    const float* wp = proj_W + o * 128 + cblk;
    float4 v0 = *(const float4*)wp;
    float4 v1 = *(const float4*)(wp + 4);
    f16x8 hv;
    hv[0] = (_Float16)v0.x; hv[1] = (_Float16)v0.y;
    hv[2] = (_Float16)v0.z; hv[3] = (_Float16)v0.w;
    hv[4] = (_Float16)v1.x; hv[5] = (_Float16)v1.y;
    hv[6] = (_Float16)v1.z; hv[7] = (_Float16)v1.w;
    *(f16x8*)&U.projH[o][cblk] = hv;
  }
  __syncthreads();
  int rsel = lane & 15, ksel = (lane >> 4) * 8;
  int mt = w;
  f16x8 af[4];
#pragma unroll
  for (int kc = 0; kc < 4; ++kc)
    af[kc] = *(const f16x8*)&xmH[mt * 16 + rsel][kc * 32 + ksel];
  int row0 = mt * 16 + ((lane >> 4) << 2);
#pragma unroll
  for (int nt = 0; nt < 8; ++nt) {
    int o = nt * 16 + rsel;
    float pb = proj_b[o];
    f32x4 acc = {pb, pb, pb, pb};
#pragma unroll
    for (int kc = 0; kc < 4; ++kc) {
      f16x8 bf = *(const f16x8*)&U.projH[o][kc * 32 + ksel];
      acc = __builtin_amdgcn_mfma_f32_16x16x32_f16(af[kc], bf, acc, 0, 0, 0);
    }
    *(float4*)&out[((size_t)(b * OUT_ + o)) * L_ + t0 + row0] =
        make_float4(acc[0], acc[1], acc[2], acc[3]);
  }
}

extern "C" void kernel_launch(void* const* d_in, const int* in_sizes, int n_in,
                              void* d_out, int out_size, void* d_ws, size_t ws_size,
                              hipStream_t stream) {
  const float* x = (const float*)d_in[0];
  const float* norm_g = (const float*)d_in[1];
  const float* norm_b = (const float*)d_in[2];
  const float* proj_W = (const float*)d_in[3];
  const float* proj_b = (const float*)d_in[4];
  const float* skip = (const float*)d_in[5];
  const float* se_W1 = (const float*)d_in[6];
  const float* se_W2 = (const float*)d_in[7];
  const float* in_W = (const float*)d_in[8];
  const float* conv_W = (const float*)d_in[9];
  const float* conv_b = (const float*)d_in[10];
  const float* xproj_W = (const float*)d_in[11];
  const float* dt_W = (const float*)d_in[12];
  const float* dt_b = (const float*)d_in[13];
  const float* A_log = (const float*)d_in[14];
  const float* D_p = (const float*)d_in[15];
  const float* out_W = (const float*)d_in[16];
  float* out = (float*)d_out;

  // workspace (~126 MiB)
  float* XN = (float*)d_ws;                         // B*L*C f32
  float* SUMYF = XN + (size_t)B_ * L_ * C_;         // NI*DI
  float* SUMXN = SUMYF + NI * DI;                   // B*C
  float* GATES = SUMXN + B_ * C_;                   // NI*DI
  float* Pp = GATES + NI * DI;                      // NI*DI*NSEG*DS f32
  float* Qp = Pp + (size_t)NI * DI * NSEG * DS;
  h16* YS2 = (h16*)(Qp + (size_t)NI * DI * NSEG * DS);  // NI*L*DI h16
  h16* SX2 = YS2 + (size_t)NI * L_ * DI;
  h16* SDT2 = SX2 + (size_t)NI * L_ * DI;
  h16* SB2 = SDT2 + (size_t)NI * L_ * DI;           // NI*L*DS h16
  h16* SC2 = SB2 + (size_t)NI * L_ * DS;
  h16* SZ2 = SC2 + (size_t)NI * L_ * DS;            // NI*L*DI h16 (silu(z))

  hipMemsetAsync(SUMYF, 0, (size_t)(NI * DI + B_ * C_) * sizeof(float), stream);
  k1_ln<<<B_ * 64, 256, 0, stream>>>(x, norm_g, norm_b, XN, SUMXN);
  k2_prep<<<NI * 64, 256, 0, stream>>>(in_W, conv_W, conv_b, xproj_W, dt_W, dt_b,
                                       XN, SX2, SDT2, SB2, SC2, SZ2);
  k3a_seg<<<NI * 32, 256, 0, stream>>>(A_log, SDT2, SX2, SB2, Pp, Qp);
  k3b_comb<<<128, 256, 0, stream>>>(Pp, Qp);
  k3c_scan<<<NI * 32, 256, 0, stream>>>(A_log, SDT2, SX2, SB2, SC2, SZ2, D_p,
                                        Pp, YS2, SUMYF);
  k4_gates<<<NI, 64, 0, stream>>>(out_W, se_W1, se_W2, skip, SUMYF, SUMXN, GATES);
  k5b_combine<<<NI * 64, 256, 0, stream>>>(out_W, skip, GATES, YS2, XN);
  k6_ln_proj<<<B_ * 64, 256, 0, stream>>>(norm_g, norm_b, proj_W, proj_b, XN, out);
}

// Round 4
// 226.347 us; speedup vs baseline: 1.3111x; 1.0699x over previous
//
#include <hip/hip_runtime.h>
#include <math.h>

typedef _Float16 h16;

#define DEV static __device__ __forceinline__

constexpr int B_ = 8, C_ = 128, L_ = 4096, OUT_ = 128;
constexpr int NCH = 4, DM = 32, DS = 16, DI = 64;
constexpr int NI = 32;            // B_*NCH instances
constexpr int NSEG = 128;         // scan segments
constexpr int SL = L_ / NSEG;     // 32 steps per segment

DEV float sigmoidf_(float x) { return 1.f / (1.f + __expf(-x)); }
DEV float siluf_(float x) { return x * sigmoidf_(x); }
DEV float softplusf_(float x) { return (x > 20.f) ? x : __logf(1.f + __expf(x)); }

template <int CTRL>
DEV float dpp_add_(float x) {
  int v = __builtin_amdgcn_update_dpp(0, __float_as_int(x), CTRL, 0xf, 0xf, false);
  return x + __int_as_float(v);
}

typedef __attribute__((ext_vector_type(8))) _Float16 f16x8;
typedef __attribute__((ext_vector_type(4))) _Float16 f16x4;
typedef __attribute__((ext_vector_type(4))) float f32x4;

// log-depth powers: out[s] = E^(s+1), dep depth ~5 instead of 15
DEV void powladder_(float E, float* out) {
  float E2 = E * E;
  float E4 = E2 * E2;
  float E8 = E4 * E4;
  float E3 = E2 * E;
  out[0] = E;       out[1] = E2;      out[2] = E3;      out[3] = E4;
  out[4] = E4 * E;  out[5] = E4 * E2; out[6] = E4 * E3; out[7] = E8;
  out[8] = E8 * E;  out[9] = E8 * E2; out[10] = E8 * E3; out[11] = E8 * E4;
  out[12] = E8 * out[4]; out[13] = E8 * out[5]; out[14] = E8 * out[6];
  out[15] = E8 * E8;
}

// 8-deep ladder: out[j] = E^(j+1)
DEV void powladder8_(float E, float* out) {
  float E2 = E * E, E3 = E2 * E, E4 = E2 * E2;
  out[0] = E; out[1] = E2; out[2] = E3; out[3] = E4;
  out[4] = E4 * E; out[5] = E4 * E2; out[6] = E4 * E3; out[7] = E4 * E4;
}

// ---------------- K0: one-shot weight convert to h16 ----------------
// WH layout: [0,4096) = in_W (both halves); [4096, 4096+48*64) = xproj_W padded
__global__ __launch_bounds__(256) void k0_wcvt(const float* __restrict__ in_W,
                                               const float* __restrict__ xproj_W,
                                               h16* __restrict__ WH) {
  int tid = blockIdx.x * 256 + threadIdx.x;
  if (tid < 4096) {
    WH[tid] = (h16)in_W[tid];
  } else {
    int j = tid - 4096;
    int r = j >> 6;
    WH[tid] = (r < 34) ? (h16)xproj_W[j - (r - (r < 34 ? 0 : 0)) * 0 + (r * 64 + (j & 63)) - j + j] : (h16)0.f;
    // simplified below (kept simple): recompute cleanly
    WH[tid] = (r < 34) ? (h16)xproj_W[r * 64 + (j & 63)] : (h16)0.f;
  }
}

// ---------------- K1: LayerNorm1 (B,C,L)->(B,L,C) f32+h16 + token sums --------
__global__ __launch_bounds__(256) void k1_ln(const float* __restrict__ x,
                                             const float* __restrict__ gn,
                                             const float* __restrict__ bn,
                                             float* __restrict__ XN,
                                             h16* __restrict__ XNH,
                                             float* __restrict__ SUMXN) {
  int bid = blockIdx.x;
  int b = bid >> 6, tile = bid & 63;
  int t0 = tile * 64;
  int tid = threadIdx.x;
  __shared__ float xT[128][65];
  __shared__ float gnS[128], bnS[128];
  __shared__ float red[256];
  if (tid < 128) { gnS[tid] = gn[tid]; bnS[tid] = bn[tid]; }
  for (int k = tid; k < 8192; k += 256) {
    int c = k >> 6, tt = k & 63;
    xT[c][tt] = x[((size_t)(b * C_ + c)) * L_ + t0 + tt];
  }
  __syncthreads();
  {
    int tok = tid >> 2, q = tid & 3;
    float s = 0.f, qq = 0.f;
#pragma unroll
    for (int j = 0; j < 32; ++j) {
      float v = xT[q + 4 * j][tok];
      s += v; qq += v * v;
    }
    s = dpp_add_<0xB1>(s); qq = dpp_add_<0xB1>(qq);
    s = dpp_add_<0x4E>(s); qq = dpp_add_<0x4E>(qq);
    float m = s * (1.f / 128.f);
    float var = qq * (1.f / 128.f) - m * m;
    float rs = rsqrtf(var + 1e-5f);
#pragma unroll
    for (int j = 0; j < 32; ++j) {
      int c = q + 4 * j;
      float v = xT[c][tok];
      xT[c][tok] = (v - m) * rs * gnS[c] + bnS[c];
    }
  }
  __syncthreads();
  float acc = 0.f;
  int cfix = tid & 127;
  for (int k = tid; k < 8192; k += 256) {
    int tt = k >> 7, c = k & 127;
    float v = xT[c][tt];
    XN[((size_t)(b * L_ + t0 + tt)) * C_ + c] = v;
    acc += v;
  }
  // h16 copy (coalesced 16B stores)
  for (int k = tid; k < 1024; k += 256) {
    int tt = k >> 4, c8 = (k & 15) * 8;
    f16x8 hv;
#pragma unroll
    for (int j = 0; j < 8; ++j) hv[j] = (_Float16)xT[c8 + j][tt];
    *(f16x8*)&XNH[((size_t)(b * L_ + t0 + tt)) * C_ + c8] = hv;
  }
  red[tid] = acc;
  __syncthreads();
  if (tid < 128) atomicAdd(&SUMXN[b * C_ + cfix], red[tid] + red[tid + 128]);
}

// ---------------- K2: in-proj + conv + silu + x-proj + dt + z + LOCAL SCAN ----
// All weights pre-h16 (WH); u from XNH. Fuses k3a: 4 waves = 2 seg x 2 s-halves.
__global__ __launch_bounds__(256) void k2_prep(
    const h16* __restrict__ WH, const float* __restrict__ conv_W,
    const float* __restrict__ conv_b, const float* __restrict__ dt_W,
    const float* __restrict__ dt_b, const float* __restrict__ A_log,
    const h16* __restrict__ XNH, h16* __restrict__ SX2, h16* __restrict__ SDT2,
    h16* __restrict__ SB2, h16* __restrict__ SC2, h16* __restrict__ SZ2,
    float* __restrict__ Pp, float* __restrict__ Qp) {
  int bid = blockIdx.x;
  int i = bid >> 6, tile = bid & 63;
  int b = i >> 2, ch = i & 3;
  int t0 = tile * 64;
  int tid = threadIdx.x;
  int w = __builtin_amdgcn_readfirstlane(tid >> 6);
  int lane = tid & 63;

  // union: staging (u + x-half of in_W) | x-proj output | z transpose bounce
  __shared__ __attribute__((aligned(16))) union {
    struct {
      _Float16 uH[80][40];   // rows 0..66 = tokens t0-3..t0+63; 67..79 zero
      _Float16 w1H[64][40];  // in_W x-half, row=d, col=c
    } s;
    float xdS[64][36];       // x-proj output, row=token, col=o (34 used)
    _Float16 zL[64][88];     // silu(z) bounce
  } U;
  __shared__ __attribute__((aligned(16))) _Float16 wzH[64][40];   // in_W z-half
  __shared__ __attribute__((aligned(16))) _Float16 preH[80][66];  // in-proj out; later dtL
  __shared__ __attribute__((aligned(16))) _Float16 xH[64][72];    // conv+silu out
  __shared__ __attribute__((aligned(16))) _Float16 w2H[48][72];   // xproj_W padded
  __shared__ float convWS[64][4];
  __shared__ float dtWS[64][2];
  __shared__ float dtbS[64], cbS[64];

  convWS[tid >> 2][tid & 3] = conv_W[tid];
  if (tid < 128) dtWS[tid >> 1][tid & 1] = dt_W[tid];
  if (tid < 64) { dtbS[tid] = dt_b[tid]; cbS[tid] = conv_b[tid]; }
  // u from XNH (16B vector loads)
  const h16* xnh = XNH + (size_t)b * L_ * C_ + ch * DM;
  for (int k = tid; k < 320; k += 256) {
    int r = k >> 2, c8 = (k & 3) * 8;
    int tg = t0 - 3 + r;
    f16x8 v = {0, 0, 0, 0, 0, 0, 0, 0};
    if (r < 67 && tg >= 0) v = *(const f16x8*)&xnh[(size_t)tg * C_ + c8];
    *(f16x8*)&U.s.uH[r][c8] = v;
  }
  // weights: h16 vector copies
  if (tid < 256) {
    int r = tid >> 2, c8 = (tid & 3) * 8;
    *(f16x8*)&U.s.w1H[r][c8] = *(const f16x8*)&WH[r * 32 + c8];
    *(f16x8*)&wzH[r][c8] = *(const f16x8*)&WH[(64 + r) * 32 + c8];
  }
  for (int k = tid; k < 384; k += 256) {
    int r = k >> 3, c8 = (k & 7) * 8;
    *(f16x8*)&w2H[r][c8] = *(const f16x8*)&WH[4096 + r * 64 + c8];
  }
  __syncthreads();

  int rsel = lane & 15, ksel = (lane >> 4) * 8;
  // in-proj MFMA: wave w owns N-tile nt=w, loops 5 M-tiles
  {
    int nt = w;
    f16x8 bf = *(const f16x8*)&U.s.w1H[nt * 16 + rsel][ksel];
    int row0q = (lane >> 4) << 2;
    int col = nt * 16 + rsel;
#pragma unroll
    for (int mt = 0; mt < 5; ++mt) {
      f16x8 af = *(const f16x8*)&U.s.uH[mt * 16 + rsel][ksel];
      f32x4 acc = {0.f, 0.f, 0.f, 0.f};
      acc = __builtin_amdgcn_mfma_f32_16x16x32_f16(af, bf, acc, 0, 0, 0);
      int row0 = mt * 16 + row0q;
#pragma unroll
      for (int r = 0; r < 4; ++r) preH[row0 + r][col] = (_Float16)acc[r];
    }
  }
  // z-gate MFMA (transposed): D[zd][token]; wave w owns token-tile w.
  f32x4 zacc[4];
  {
    f16x8 bf = *(const f16x8*)&U.s.uH[3 + w * 16 + rsel][ksel];
#pragma unroll
    for (int mt = 0; mt < 4; ++mt) {
      f16x8 af = *(const f16x8*)&wzH[mt * 16 + rsel][ksel];
      f32x4 acc = {0.f, 0.f, 0.f, 0.f};
      zacc[mt] = __builtin_amdgcn_mfma_f32_16x16x32_f16(af, bf, acc, 0, 0, 0);
    }
  }
  __syncthreads();

  // causal depthwise conv + silu; write xH + SX2 inline
  h16* SXp = SX2 + ((size_t)i * L_ + t0) * DI;
  for (int k = tid; k < 4096; k += 256) {
    int r = k >> 6, d = k & 63;
    float v = cbS[d];
#pragma unroll
    for (int j = 0; j < 4; ++j) v = fmaf(convWS[d][j], (float)preH[r + j][d], v);
    v = siluf_(v);
    xH[r][d] = (_Float16)v;
    SXp[(size_t)r * DI + d] = (h16)v;
  }
  __syncthreads();

  // x-proj MFMA: wave w owns M-tile mt=w; K=64 as 2 chunks; N padded to 48
  {
    int mt = w;
    f16x8 a0 = *(const f16x8*)&xH[mt * 16 + rsel][ksel];
    f16x8 a1 = *(const f16x8*)&xH[mt * 16 + rsel][32 + ksel];
    int row0 = mt * 16 + ((lane >> 4) << 2);
#pragma unroll
    for (int nt = 0; nt < 3; ++nt) {
      f16x8 b0 = *(const f16x8*)&w2H[nt * 16 + rsel][ksel];
      f16x8 b1 = *(const f16x8*)&w2H[nt * 16 + rsel][32 + ksel];
      f32x4 acc = {0.f, 0.f, 0.f, 0.f};
      acc = __builtin_amdgcn_mfma_f32_16x16x32_f16(a0, b0, acc, 0, 0, 0);
      acc = __builtin_amdgcn_mfma_f32_16x16x32_f16(a1, b1, acc, 0, 0, 0);
      int col = nt * 16 + rsel;
      if (col < 34) {
#pragma unroll
        for (int r = 0; r < 4; ++r) U.xdS[row0 + r][col] = acc[r];
      }
    }
  }
  __syncthreads();

  // dt -> LDS (reuse dead preH) + SDT2; B/C writeout
  h16* dtL = (h16*)&preH[0][0];   // stride 66
  h16* SDTp = SDT2 + ((size_t)i * L_ + t0) * DI;
  for (int k = tid; k < 4096; k += 256) {
    int d = k & 63, r = k >> 6;
    float raw = fmaf(U.xdS[r][0], dtWS[d][0], fmaf(U.xdS[r][1], dtWS[d][1], dtbS[d]));
    float dtv = softplusf_(raw);
    dtL[r * 66 + d] = (_Float16)dtv;
    SDTp[(size_t)r * DI + d] = (h16)dtv;
  }
  h16* SBp = SB2 + ((size_t)i * L_ + t0) * DS;
  h16* SCp = SC2 + ((size_t)i * L_ + t0) * DS;
  for (int k = tid; k < 1024; k += 256) {
    int s = k & 15, r = k >> 4;
    SBp[(size_t)r * DS + s] = (h16)U.xdS[r][2 + s];
    SCp[(size_t)r * DS + s] = (h16)U.xdS[r][18 + s];
  }
  __syncthreads();

  // ---- fused local scan (replaces k3a): wave w -> seg=w>>1, shalf=w&1, d=lane
  {
    int seg = w >> 1, shalf = w & 1;
    int s0 = shalf * 8;
    float Av[16];
#pragma unroll
    for (int s = 0; s < 16; ++s) Av[s] = -__expf(A_log[lane * 16 + s]);
    float A0 = Av[0];
    bool okf = true;
#pragma unroll
    for (int s = 0; s < 16; ++s)
      okf &= fabsf(Av[s] - (float)(s + 1) * A0) <= 1e-4f * fabsf(Av[s]);
    int fastp = __all(okf ? 1 : 0);
    float h[8];
#pragma unroll
    for (int j = 0; j < 8; ++j) h[j] = 0.f;
    float sdt = 0.f;
    int rowbase = seg * SL;
    for (int t = 0; t < SL; ++t) {
      int row = rowbase + t;
      float dt = (float)dtL[row * 66 + lane];
      float xv = (float)xH[row][lane];
      float dtx = dt * xv;
      float dA[8];
      if (fastp) {
        powladder8_(__expf(A0 * dt), dA);
        if (shalf) {
          float E8 = dA[7];
#pragma unroll
          for (int j = 0; j < 8; ++j) dA[j] *= E8;
        }
      } else {
#pragma unroll
        for (int j = 0; j < 8; ++j) dA[j] = __expf(Av[s0 + j] * dt);
      }
      const float* brow = &U.xdS[row][2 + s0];
#pragma unroll
      for (int j = 0; j < 8; ++j) h[j] = fmaf(dA[j], h[j], dtx * brow[j]);
      sdt += dt;
    }
    float P[8];
    if (fastp) {
      powladder8_(__expf(A0 * sdt), P);
      if (shalf) {
        float E8 = P[7];
#pragma unroll
        for (int j = 0; j < 8; ++j) P[j] *= E8;
      }
    } else {
#pragma unroll
      for (int j = 0; j < 8; ++j) P[j] = __expf(Av[s0 + j] * sdt);
    }
    int segg = tile * 2 + seg;
    size_t base = (((size_t)i * DI + lane) * NSEG + segg) * DS + s0;
    *(float4*)(Pp + base) = *(float4*)&P[0];
    *(float4*)(Pp + base + 4) = *(float4*)&P[4];
    *(float4*)(Qp + base) = *(float4*)&h[0];
    *(float4*)(Qp + base + 4) = *(float4*)&h[4];
  }
  __syncthreads();   // xdS fully consumed; reuse union as zL

  // z writeout: pack 4 consecutive zd per lane into LDS, then coalesced global
  {
    int tok = w * 16 + rsel;
    int zq = (lane >> 4) << 2;
#pragma unroll
    for (int mt = 0; mt < 4; ++mt) {
      f16x4 pk;
#pragma unroll
      for (int r = 0; r < 4; ++r) pk[r] = (_Float16)siluf_(zacc[mt][r]);
      *(f16x4*)&U.zL[tok][mt * 16 + zq] = pk;
    }
  }
  __syncthreads();
  h16* SZp = SZ2 + ((size_t)i * L_ + t0) * DI;
  for (int k = tid; k < 512; k += 256) {
    int r = k >> 3, dblk = (k & 7) * 8;
    f16x8 v = *(const f16x8*)&U.zL[r][dblk];
    *(f16x8*)&SZp[(size_t)r * DI + dblk] = v;
  }
}

// ---------------- K3b: inter-segment scan -> h0 per segment (overlays P) ----------------
__global__ __launch_bounds__(256) void k3b_comb(float* __restrict__ Pp,
                                                const float* __restrict__ Qp) {
  int g = blockIdx.x * 256 + threadIdx.x;  // 32768 = NI*DI*DS
  int s = g & 15;
  int r = g >> 4;          // over NI*DI
  size_t base = (size_t)r * NSEG * DS + s;
  float H = 0.f;
  for (int seg = 0; seg < NSEG; ++seg) {
    size_t a = base + (size_t)seg * DS;
    float P = Pp[a], Q = Qp[a];
    Pp[a] = H;
    H = fmaf(P, H, Q);
  }
}

// ---------------- K3c: final scan, fused with D-term/z-gate-mult/token-sums ----
__global__ __launch_bounds__(256) void k3c_scan(
    const float* __restrict__ A_log, const h16* __restrict__ SDT2,
    const h16* __restrict__ SX2, const h16* __restrict__ SB2,
    const h16* __restrict__ SC2, const h16* __restrict__ SZ2,
    const float* __restrict__ D_p, const float* __restrict__ H0p,
    h16* __restrict__ YS2, float* __restrict__ SUMYF) {
  int bid = blockIdx.x;             // i*32 + sg
  int i = bid >> 5, sg = bid & 31;
  int tid = threadIdx.x;
  int w = tid >> 6, lane = tid & 63;
  int seg = sg * 4 + w;
  int t0 = seg * SL;
  __shared__ float rowS[4][SL][36];   // [w][t][ B16 | C16 ] + pad
  {
    int tk = lane & 31, hf = lane >> 5;
    const h16* p = (hf ? SC2 : SB2) + ((size_t)i * L_ + t0 + tk) * DS;
    float4 r0 = *(const float4*)p;
    float4 r1 = *(const float4*)(p + 8);
    const h16* hp0 = (const h16*)&r0;
    const h16* hp1 = (const h16*)&r1;
#pragma unroll
    for (int s = 0; s < 8; ++s) {
      rowS[w][tk][hf * 16 + s] = (float)hp0[s];
      rowS[w][tk][hf * 16 + 8 + s] = (float)hp1[s];
    }
  }
  __syncthreads();
  float Av[16];
#pragma unroll
  for (int s = 0; s < 16; ++s) Av[s] = -__expf(A_log[lane * 16 + s]);
  float A0 = Av[0];
  bool okf = true;
#pragma unroll
  for (int s = 0; s < 16; ++s) okf &= fabsf(Av[s] - (float)(s + 1) * A0) <= 1e-4f * fabsf(Av[s]);
  int fastp = __all(okf ? 1 : 0);
  float Dp = D_p[lane];
  float h[16];
  {
    size_t base = (((size_t)i * DI + lane) * NSEG + seg) * DS;
#pragma unroll
    for (int j = 0; j < 4; ++j) *(float4*)&h[4 * j] = *(const float4*)(H0p + base + 4 * j);
  }
  const h16* pdt = SDT2 + ((size_t)i * L_ + t0) * DI + lane;
  const h16* pxx = SX2 + ((size_t)i * L_ + t0) * DI + lane;
  const h16* pzz = SZ2 + ((size_t)i * L_ + t0) * DI + lane;
  h16* pys = YS2 + ((size_t)i * L_ + t0) * DI + lane;
  float dtc = (float)pdt[0], xvc = (float)pxx[0], zvc = (float)pzz[0];
  float sum = 0.f;
  for (int t = 0; t < SL; ++t) {
    float dt = dtc, xv = xvc, zv = zvc;
    if (t < SL - 1) {
      dtc = (float)pdt[(t + 1) * DI];
      xvc = (float)pxx[(t + 1) * DI];
      zvc = (float)pzz[(t + 1) * DI];
    }
    const float* row = &rowS[w][t][0];
    float Bv[16], Cv[16];
#pragma unroll
    for (int j = 0; j < 4; ++j) {
      *(float4*)&Bv[4 * j] = *(const float4*)(row + 4 * j);
      *(float4*)&Cv[4 * j] = *(const float4*)(row + 16 + 4 * j);
    }
    float dtx = dt * xv;
    float dA[16];
    if (fastp) {
      powladder_(__expf(A0 * dt), dA);
    } else {
#pragma unroll
      for (int s = 0; s < 16; ++s) dA[s] = __expf(Av[s] * dt);
    }
    float y0 = 0.f, y1 = 0.f, y2 = 0.f, y3 = 0.f;
#pragma unroll
    for (int s = 0; s < 16; s += 4) {
      h[s] = fmaf(dA[s], h[s], dtx * Bv[s]);       y0 = fmaf(h[s], Cv[s], y0);
      h[s + 1] = fmaf(dA[s + 1], h[s + 1], dtx * Bv[s + 1]); y1 = fmaf(h[s + 1], Cv[s + 1], y1);
      h[s + 2] = fmaf(dA[s + 2], h[s + 2], dtx * Bv[s + 2]); y2 = fmaf(h[s + 2], Cv[s + 2], y2);
      h[s + 3] = fmaf(dA[s + 3], h[s + 3], dtx * Bv[s + 3]); y3 = fmaf(h[s + 3], Cv[s + 3], y3);
    }
    float y = (y0 + y1) + (y2 + y3);
    float yf = fmaf(xv, Dp, y) * zv;
    pys[(size_t)t * DI] = (h16)yf;
    sum += yf;
  }
  atomicAdd(&SUMYF[i * DI + lane], sum);
}

// ---------------- K4: SE gates ----------------
__global__ __launch_bounds__(64) void k4_gates(
    const float* __restrict__ out_W, const float* __restrict__ se_W1,
    const float* __restrict__ se_W2, const float* __restrict__ skip_p,
    const float* __restrict__ SUMYF, const float* __restrict__ SUMXN,
    float* __restrict__ GATES) {
  int i = blockIdx.x;
  int b = i >> 2, ch = i & 3;
  int tid = threadIdx.x;
  __shared__ float syS[64], catS[64], seS[2];
  syS[tid] = SUMYF[i * DI + tid];
  __syncthreads();
  float invL = 1.f / (float)L_;
  if (tid < 32) {
    float acc = 0.f;
#pragma unroll
    for (int dd = 0; dd < 64; ++dd) acc = fmaf(syS[dd], out_W[tid * 64 + dd], acc);
    catS[tid] = acc * invL;
  } else {
    int c = tid - 32;
    catS[tid] = skip_p[0] * SUMXN[b * C_ + ch * DM + c] * invL;
  }
  __syncthreads();
  if (tid < 2) {
    float acc = 0.f;
#pragma unroll
    for (int k = 0; k < 64; ++k) acc = fmaf(catS[k], se_W1[tid * 64 + k], acc);
    seS[tid] = fmaxf(acc, 0.f);
  }
  __syncthreads();
  float gg = fmaf(seS[0], se_W2[tid * 2 + 0], seS[1] * se_W2[tid * 2 + 1]);
  GATES[i * DI + tid] = sigmoidf_(gg);
}

// ---------------- K5b: M1 = yfull @ outW.T via MFMA, gated combine ------------
__global__ __launch_bounds__(256) void k5b_combine(
    const float* __restrict__ out_W, const float* __restrict__ skip_p,
    const float* __restrict__ GATES, const h16* __restrict__ YS2,
    float* __restrict__ XN) {
  int bid = blockIdx.x;
  int i = bid >> 6, tile = bid & 63;
  int b = i >> 2, ch = i & 3;
  int t0 = tile * 64;
  int tid = threadIdx.x;
  int w = __builtin_amdgcn_readfirstlane(tid >> 6);
  int lane = tid & 63;
  __shared__ __attribute__((aligned(16))) _Float16 yH[64][72];
  __shared__ __attribute__((aligned(16))) _Float16 owH[32][72];
  __shared__ float xnS[64][37];
  __shared__ float gS[64];
  if (tid < 64) gS[tid] = GATES[i * DI + tid];
  const h16* py = YS2 + ((size_t)i * L_ + t0) * DI;
  for (int k = tid; k < 512; k += 256) {
    int tt = k >> 3, dblk = (k & 7) * 8;
    *(f16x8*)&yH[tt][dblk] = *(const f16x8*)&py[(size_t)tt * DI + dblk];
  }
  for (int k = tid; k < 2048; k += 256) owH[k >> 6][k & 63] = (_Float16)out_W[k];
  float* xn = XN + (size_t)b * L_ * C_ + ch * DM;
  for (int k = tid; k < 2048; k += 256) {
    int tt = k >> 5, o = k & 31;
    xnS[tt][o] = xn[(size_t)(t0 + tt) * C_ + o];
  }
  __syncthreads();
  int rsel = lane & 15, ksel = (lane >> 4) * 8;
  float skip = skip_p[0];
  int mt = w;
  f16x8 a0 = *(const f16x8*)&yH[mt * 16 + rsel][ksel];
  f16x8 a1 = *(const f16x8*)&yH[mt * 16 + rsel][32 + ksel];
  int row0 = mt * 16 + ((lane >> 4) << 2);
#pragma unroll
  for (int nt = 0; nt < 2; ++nt) {
    f16x8 b0 = *(const f16x8*)&owH[nt * 16 + rsel][ksel];
    f16x8 b1 = *(const f16x8*)&owH[nt * 16 + rsel][32 + ksel];
    f32x4 acc = {0.f, 0.f, 0.f, 0.f};
    acc = __builtin_amdgcn_mfma_f32_16x16x32_f16(a0, b0, acc, 0, 0, 0);
    acc = __builtin_amdgcn_mfma_f32_16x16x32_f16(a1, b1, acc, 0, 0, 0);
    int o = nt * 16 + rsel;
    float g1 = gS[o], g2s = gS[32 + o] * skip;
#pragma unroll
    for (int r = 0; r < 4; ++r) {
      int tok = row0 + r;
      xnS[tok][o] = g1 * acc[r] + g2s * xnS[tok][o];
    }
  }
  __syncthreads();
  for (int k = tid; k < 2048; k += 256) {
    int tt = k >> 5, o = k & 31;
    xn[(size_t)(t0 + tt) * C_ + o] = xnS[tt][o];
  }
}

// ---------------- K6: LN2 + proj (MFMA) + transpose to (B,OUT,H,W) ------------
__global__ __launch_bounds__(256) void k6_ln_proj(
    const float* __restrict__ gn, const float* __restrict__ bn,
    const float* __restrict__ proj_W, const float* __restrict__ proj_b,
    const float* __restrict__ XN, float* __restrict__ out) {
  int bid = blockIdx.x;
  int b = bid >> 6, tile = bid & 63;
  int t0 = tile * 64;
  int tid = threadIdx.x;
  int w = __builtin_amdgcn_readfirstlane(tid >> 6);
  int lane = tid & 63;
  __shared__ __attribute__((aligned(16))) union {
    float xmS[64][132];
    _Float16 projH[128][136];
  } U;
  __shared__ __attribute__((aligned(16))) _Float16 xmH[64][136];
  __shared__ float gnS[128], bnS[128];
  if (tid < 128) { gnS[tid] = gn[tid]; bnS[tid] = bn[tid]; }
  const float* xm = XN + (size_t)b * L_ * C_;
  for (int k = tid; k < 8192; k += 256) {
    int tt = k >> 7, c = k & 127;
    U.xmS[tt][c] = xm[(size_t)(t0 + tt) * C_ + c];
  }
  __syncthreads();
  {
    int tok = tid >> 2, q = tid & 3;
    float s = 0.f, qq = 0.f;
#pragma unroll
    for (int j = 0; j < 32; ++j) {
      float v = U.xmS[tok][4 * j + q];
      s += v; qq += v * v;
    }
    s = dpp_add_<0xB1>(s); qq = dpp_add_<0xB1>(qq);
    s = dpp_add_<0x4E>(s); qq = dpp_add_<0x4E>(qq);
    float m = s * (1.f / 128.f);
    float var = qq * (1.f / 128.f) - m * m;
    float rs = rsqrtf(var + 1e-5f);
#pragma unroll
    for (int j = 0; j < 32; ++j) {
      int c = 4 * j + q;
      float v = U.xmS[tok][c];
      U.xmS[tok][c] = (v - m) * rs * gnS[c] + bnS[c];
    }
  }
  __syncthreads();
  for (int k = tid; k < 1024; k += 256) {
    int tt = k >> 4, cblk = (k & 15) * 8;
    float4 v0 = *(const float4*)&U.xmS[tt][cblk];
    float4 v1 = *(const float4*)&U.xmS[tt][cblk + 4];
    f16x8 hv;
    hv[0] = (_Float16)v0.x; hv[1] = (_Float16)v0.y;
    hv[2] = (_Float16)v0.z; hv[3] = (_Float16)v0.w;
    hv[4] = (_Float16)v1.x; hv[5] = (_Float16)v1.y;
    hv[6] = (_Float16)v1.z; hv[7] = (_Float16)v1.w;
    *(f16x8*)&xmH[tt][cblk] = hv;
  }
  __syncthreads();
  for (int k = tid; k < 2048; k += 256) {
    int o = k >> 4, cblk = (k & 15) * 8;
    const float* wp = proj_W + o * 128 + cblk;
    float4 v0 = *(const float4*)wp;
    float4 v1 = *(const float4*)(wp + 4);
    f16x8 hv;
    hv[0] = (_Float16)v0.x; hv[1] = (_Float16)v0.y;
    hv[2] = (_Float16)v0.z; hv[3] = (_Float16)v0.w;
    hv[4] = (_Float16)v1.x; hv[5] = (_Float16)v1.y;
    hv[6] = (_Float16)v1.z; hv[7] = (_Float16)v1.w;
    *(f16x8*)&U.projH[o][cblk] = hv;
  }
  __syncthreads();
  int rsel = lane & 15, ksel = (lane >> 4) * 8;
  int mt = w;
  f16x8 af[4];
#pragma unroll
  for (int kc = 0; kc < 4; ++kc)
    af[kc] = *(const f16x8*)&xmH[mt * 16 + rsel][kc * 32 + ksel];
  int row0 = mt * 16 + ((lane >> 4) << 2);
#pragma unroll
  for (int nt = 0; nt < 8; ++nt) {
    int o = nt * 16 + rsel;
    float pb = proj_b[o];
    f32x4 acc = {pb, pb, pb, pb};
#pragma unroll
    for (int kc = 0; kc < 4; ++kc) {
      f16x8 bf = *(const f16x8*)&U.projH[o][kc * 32 + ksel];
      acc = __builtin_amdgcn_mfma_f32_16x16x32_f16(af[kc], bf, acc, 0, 0, 0);
    }
    *(float4*)&out[((size_t)(b * OUT_ + o)) * L_ + t0 + row0] =
        make_float4(acc[0], acc[1], acc[2], acc[3]);
  }
}

extern "C" void kernel_launch(void* const* d_in, const int* in_sizes, int n_in,
                              void* d_out, int out_size, void* d_ws, size_t ws_size,
                              hipStream_t stream) {
  const float* x = (const float*)d_in[0];
  const float* norm_g = (const float*)d_in[1];
  const float* norm_b = (const float*)d_in[2];
  const float* proj_W = (const float*)d_in[3];
  const float* proj_b = (const float*)d_in[4];
  const float* skip = (const float*)d_in[5];
  const float* se_W1 = (const float*)d_in[6];
  const float* se_W2 = (const float*)d_in[7];
  const float* in_W = (const float*)d_in[8];
  const float* conv_W = (const float*)d_in[9];
  const float* conv_b = (const float*)d_in[10];
  const float* xproj_W = (const float*)d_in[11];
  const float* dt_W = (const float*)d_in[12];
  const float* dt_b = (const float*)d_in[13];
  const float* A_log = (const float*)d_in[14];
  const float* D_p = (const float*)d_in[15];
  const float* out_W = (const float*)d_in[16];
  float* out = (float*)d_out;

  // workspace (~135 MiB)
  float* XN = (float*)d_ws;                         // B*L*C f32
  float* SUMYF = XN + (size_t)B_ * L_ * C_;         // NI*DI
  float* SUMXN = SUMYF + NI * DI;                   // B*C
  float* GATES = SUMXN + B_ * C_;                   // NI*DI
  float* Pp = GATES + NI * DI;                      // NI*DI*NSEG*DS f32
  float* Qp = Pp + (size_t)NI * DI * NSEG * DS;
  h16* YS2 = (h16*)(Qp + (size_t)NI * DI * NSEG * DS);  // NI*L*DI h16
  h16* SX2 = YS2 + (size_t)NI * L_ * DI;
  h16* SDT2 = SX2 + (size_t)NI * L_ * DI;
  h16* SB2 = SDT2 + (size_t)NI * L_ * DI;           // NI*L*DS h16
  h16* SC2 = SB2 + (size_t)NI * L_ * DS;
  h16* SZ2 = SC2 + (size_t)NI * L_ * DS;            // NI*L*DI h16 (silu(z))
  h16* XNH = SZ2 + (size_t)NI * L_ * DI;            // B*L*C h16
  h16* WH = XNH + (size_t)B_ * L_ * C_;             // 4096 + 48*64 h16

  hipMemsetAsync(SUMYF, 0, (size_t)(NI * DI + B_ * C_) * sizeof(float), stream);
  k0_wcvt<<<28, 256, 0, stream>>>(in_W, xproj_W, WH);
  k1_ln<<<B_ * 64, 256, 0, stream>>>(x, norm_g, norm_b, XN, XNH, SUMXN);
  k2_prep<<<NI * 64, 256, 0, stream>>>(WH, conv_W, conv_b, dt_W, dt_b, A_log,
                                       XNH, SX2, SDT2, SB2, SC2, SZ2, Pp, Qp);
  k3b_comb<<<128, 256, 0, stream>>>(Pp, Qp);
  k3c_scan<<<NI * 32, 256, 0, stream>>>(A_log, SDT2, SX2, SB2, SC2, SZ2, D_p,
                                        Pp, YS2, SUMYF);
  k4_gates<<<NI, 64, 0, stream>>>(out_W, se_W1, se_W2, skip, SUMYF, SUMXN, GATES);
  k5b_combine<<<NI * 64, 256, 0, stream>>>(out_W, skip, GATES, YS2, XN);
  k6_ln_proj<<<B_ * 64, 256, 0, stream>>>(norm_g, norm_b, proj_W, proj_b, XN, out);
}

// Round 5
// 214.125 us; speedup vs baseline: 1.3860x; 1.0571x over previous
//
#include <hip/hip_runtime.h>
#include <math.h>

typedef _Float16 h16;

#define DEV static __device__ __forceinline__

constexpr int B_ = 8, C_ = 128, L_ = 4096, OUT_ = 128;
constexpr int NCH = 4, DM = 32, DS = 16, DI = 64;
constexpr int NI = 32;            // B_*NCH instances
constexpr int NSEG = 128;         // scan segments
constexpr int SL = L_ / NSEG;     // 32 steps per segment

DEV float sigmoidf_(float x) { return 1.f / (1.f + __expf(-x)); }
DEV float siluf_(float x) { return x * sigmoidf_(x); }
DEV float softplusf_(float x) { return (x > 20.f) ? x : __logf(1.f + __expf(x)); }

template <int CTRL>
DEV float dpp_add_(float x) {
  int v = __builtin_amdgcn_update_dpp(0, __float_as_int(x), CTRL, 0xf, 0xf, false);
  return x + __int_as_float(v);
}

typedef __attribute__((ext_vector_type(8))) _Float16 f16x8;
typedef __attribute__((ext_vector_type(4))) _Float16 f16x4;
typedef __attribute__((ext_vector_type(4))) float f32x4;

// log-depth powers: out[s] = E^(s+1)
DEV void powladder_(float E, float* out) {
  float E2 = E * E;
  float E4 = E2 * E2;
  float E8 = E4 * E4;
  float E3 = E2 * E;
  out[0] = E;       out[1] = E2;      out[2] = E3;      out[3] = E4;
  out[4] = E4 * E;  out[5] = E4 * E2; out[6] = E4 * E3; out[7] = E8;
  out[8] = E8 * E;  out[9] = E8 * E2; out[10] = E8 * E3; out[11] = E8 * E4;
  out[12] = E8 * out[4]; out[13] = E8 * out[5]; out[14] = E8 * out[6];
  out[15] = E8 * E8;
}

// 8-deep ladder: out[j] = E^(j+1)
DEV void powladder8_(float E, float* out) {
  float E2 = E * E, E3 = E2 * E, E4 = E2 * E2;
  out[0] = E; out[1] = E2; out[2] = E3; out[3] = E4;
  out[4] = E4 * E; out[5] = E4 * E2; out[6] = E4 * E3; out[7] = E4 * E4;
}

// ---------------- K0: one-shot weight convert to h16 ----------------
// WH layout: [0,4096) = in_W (both halves); [4096, 4096+48*64) = xproj_W padded
__global__ __launch_bounds__(256) void k0_wcvt(const float* __restrict__ in_W,
                                               const float* __restrict__ xproj_W,
                                               h16* __restrict__ WH) {
  int tid = blockIdx.x * 256 + threadIdx.x;
  if (tid < 4096) {
    WH[tid] = (h16)in_W[tid];
  } else if (tid < 4096 + 48 * 64) {
    int j = tid - 4096;
    int r = j >> 6;
    WH[tid] = (r < 34) ? (h16)xproj_W[r * 64 + (j & 63)] : (h16)0.f;
  }
}

// ---------------- K1: LayerNorm1 (B,C,L)->(B,L,C) f32+h16 + token sums --------
__global__ __launch_bounds__(256) void k1_ln(const float* __restrict__ x,
                                             const float* __restrict__ gn,
                                             const float* __restrict__ bn,
                                             float* __restrict__ XN,
                                             h16* __restrict__ XNH,
                                             float* __restrict__ SUMXN) {
  int bid = blockIdx.x;
  int b = bid >> 6, tile = bid & 63;
  int t0 = tile * 64;
  int tid = threadIdx.x;
  __shared__ float xT[128][65];
  __shared__ float gnS[128], bnS[128];
  __shared__ float red[256];
  if (tid < 128) { gnS[tid] = gn[tid]; bnS[tid] = bn[tid]; }
  for (int k = tid; k < 8192; k += 256) {
    int c = k >> 6, tt = k & 63;
    xT[c][tt] = x[((size_t)(b * C_ + c)) * L_ + t0 + tt];
  }
  __syncthreads();
  {
    int tok = tid >> 2, q = tid & 3;
    float s = 0.f, qq = 0.f;
#pragma unroll
    for (int j = 0; j < 32; ++j) {
      float v = xT[q + 4 * j][tok];
      s += v; qq += v * v;
    }
    s = dpp_add_<0xB1>(s); qq = dpp_add_<0xB1>(qq);
    s = dpp_add_<0x4E>(s); qq = dpp_add_<0x4E>(qq);
    float m = s * (1.f / 128.f);
    float var = qq * (1.f / 128.f) - m * m;
    float rs = rsqrtf(var + 1e-5f);
#pragma unroll
    for (int j = 0; j < 32; ++j) {
      int c = q + 4 * j;
      float v = xT[c][tok];
      xT[c][tok] = (v - m) * rs * gnS[c] + bnS[c];
    }
  }
  __syncthreads();
  float acc = 0.f;
  int cfix = tid & 127;
  for (int k = tid; k < 8192; k += 256) {
    int tt = k >> 7, c = k & 127;
    float v = xT[c][tt];
    XN[((size_t)(b * L_ + t0 + tt)) * C_ + c] = v;
    acc += v;
  }
  // h16 copy (coalesced 16B stores)
  for (int k = tid; k < 1024; k += 256) {
    int tt = k >> 4, c8 = (k & 15) * 8;
    f16x8 hv;
#pragma unroll
    for (int j = 0; j < 8; ++j) hv[j] = (_Float16)xT[c8 + j][tt];
    *(f16x8*)&XNH[((size_t)(b * L_ + t0 + tt)) * C_ + c8] = hv;
  }
  red[tid] = acc;
  __syncthreads();
  if (tid < 128) atomicAdd(&SUMXN[b * C_ + cfix], red[tid] + red[tid + 128]);
}

// ---------------- K2: in-proj + conv + silu + x-proj + dt + z + LOCAL SCAN ----
// LDS trimmed to 40448 B (4 blocks/CU): z-gate A-frags read direct from WH (L2).
__global__ __launch_bounds__(256) void k2_prep(
    const h16* __restrict__ WH, const float* __restrict__ conv_W,
    const float* __restrict__ conv_b, const float* __restrict__ dt_W,
    const float* __restrict__ dt_b, const float* __restrict__ A_log,
    const h16* __restrict__ XNH, h16* __restrict__ SX2, h16* __restrict__ SDT2,
    h16* __restrict__ SB2, h16* __restrict__ SC2, h16* __restrict__ SZ2,
    float* __restrict__ Pp, float* __restrict__ Qp) {
  int bid = blockIdx.x;
  int i = bid >> 6, tile = bid & 63;
  int b = i >> 2, ch = i & 3;
  int t0 = tile * 64;
  int tid = threadIdx.x;
  int w = __builtin_amdgcn_readfirstlane(tid >> 6);
  int lane = tid & 63;

  __shared__ __attribute__((aligned(16))) union {
    struct {
      _Float16 uH[80][40];   // rows 0..66 = tokens t0-3..t0+63; 67..79 zero
      _Float16 w1H[64][40];  // in_W x-half, row=d, col=c
    } s;
    float xdS[64][36];       // x-proj output, row=token, col=o (34 used)
    _Float16 zL[64][88];     // silu(z) bounce
  } U;
  __shared__ __attribute__((aligned(16))) _Float16 preH[80][66];  // in-proj out; later dtL
  __shared__ __attribute__((aligned(16))) _Float16 xH[64][72];    // conv+silu out
  __shared__ __attribute__((aligned(16))) _Float16 w2H[48][72];   // xproj_W padded
  __shared__ float convWS[64][4];
  __shared__ float dtWS[64][2];
  __shared__ float dtbS[64], cbS[64];

  convWS[tid >> 2][tid & 3] = conv_W[tid];
  if (tid < 128) dtWS[tid >> 1][tid & 1] = dt_W[tid];
  if (tid < 64) { dtbS[tid] = dt_b[tid]; cbS[tid] = conv_b[tid]; }
  // u from XNH (16B vector loads)
  const h16* xnh = XNH + (size_t)b * L_ * C_ + ch * DM;
  for (int k = tid; k < 320; k += 256) {
    int r = k >> 2, c8 = (k & 3) * 8;
    int tg = t0 - 3 + r;
    f16x8 v = {0, 0, 0, 0, 0, 0, 0, 0};
    if (r < 67 && tg >= 0) v = *(const f16x8*)&xnh[(size_t)tg * C_ + c8];
    *(f16x8*)&U.s.uH[r][c8] = v;
  }
  // x-half weights: h16 vector copies
  {
    int r = tid >> 2, c8 = (tid & 3) * 8;
    *(f16x8*)&U.s.w1H[r][c8] = *(const f16x8*)&WH[r * 32 + c8];
  }
  for (int k = tid; k < 384; k += 256) {
    int r = k >> 3, c8 = (k & 7) * 8;
    *(f16x8*)&w2H[r][c8] = *(const f16x8*)&WH[4096 + r * 64 + c8];
  }
  __syncthreads();

  int rsel = lane & 15, ksel = (lane >> 4) * 8;
  // in-proj MFMA: wave w owns N-tile nt=w, loops 5 M-tiles
  {
    int nt = w;
    f16x8 bf = *(const f16x8*)&U.s.w1H[nt * 16 + rsel][ksel];
    int row0q = (lane >> 4) << 2;
    int col = nt * 16 + rsel;
#pragma unroll
    for (int mt = 0; mt < 5; ++mt) {
      f16x8 af = *(const f16x8*)&U.s.uH[mt * 16 + rsel][ksel];
      f32x4 acc = {0.f, 0.f, 0.f, 0.f};
      acc = __builtin_amdgcn_mfma_f32_16x16x32_f16(af, bf, acc, 0, 0, 0);
      int row0 = mt * 16 + row0q;
#pragma unroll
      for (int r = 0; r < 4; ++r) preH[row0 + r][col] = (_Float16)acc[r];
    }
  }
  // z-gate MFMA (transposed): D[zd][token]; A-frags direct from WH (L2-hot)
  f32x4 zacc[4];
  {
    f16x8 bf = *(const f16x8*)&U.s.uH[3 + w * 16 + rsel][ksel];
#pragma unroll
    for (int mt = 0; mt < 4; ++mt) {
      f16x8 af = *(const f16x8*)&WH[(size_t)(64 + mt * 16 + rsel) * 32 + ksel];
      f32x4 acc = {0.f, 0.f, 0.f, 0.f};
      zacc[mt] = __builtin_amdgcn_mfma_f32_16x16x32_f16(af, bf, acc, 0, 0, 0);
    }
  }
  __syncthreads();

  // causal depthwise conv + silu; write xH + SX2 inline
  h16* SXp = SX2 + ((size_t)i * L_ + t0) * DI;
  for (int k = tid; k < 4096; k += 256) {
    int r = k >> 6, d = k & 63;
    float v = cbS[d];
#pragma unroll
    for (int j = 0; j < 4; ++j) v = fmaf(convWS[d][j], (float)preH[r + j][d], v);
    v = siluf_(v);
    xH[r][d] = (_Float16)v;
    SXp[(size_t)r * DI + d] = (h16)v;
  }
  __syncthreads();

  // x-proj MFMA: wave w owns M-tile mt=w; K=64 as 2 chunks; N padded to 48
  {
    int mt = w;
    f16x8 a0 = *(const f16x8*)&xH[mt * 16 + rsel][ksel];
    f16x8 a1 = *(const f16x8*)&xH[mt * 16 + rsel][32 + ksel];
    int row0 = mt * 16 + ((lane >> 4) << 2);
#pragma unroll
    for (int nt = 0; nt < 3; ++nt) {
      f16x8 b0 = *(const f16x8*)&w2H[nt * 16 + rsel][ksel];
      f16x8 b1 = *(const f16x8*)&w2H[nt * 16 + rsel][32 + ksel];
      f32x4 acc = {0.f, 0.f, 0.f, 0.f};
      acc = __builtin_amdgcn_mfma_f32_16x16x32_f16(a0, b0, acc, 0, 0, 0);
      acc = __builtin_amdgcn_mfma_f32_16x16x32_f16(a1, b1, acc, 0, 0, 0);
      int col = nt * 16 + rsel;
      if (col < 34) {
#pragma unroll
        for (int r = 0; r < 4; ++r) U.xdS[row0 + r][col] = acc[r];
      }
    }
  }
  __syncthreads();

  // dt -> LDS (reuse dead preH) + SDT2; B/C writeout
  h16* dtL = (h16*)&preH[0][0];   // stride 66
  h16* SDTp = SDT2 + ((size_t)i * L_ + t0) * DI;
  for (int k = tid; k < 4096; k += 256) {
    int d = k & 63, r = k >> 6;
    float raw = fmaf(U.xdS[r][0], dtWS[d][0], fmaf(U.xdS[r][1], dtWS[d][1], dtbS[d]));
    float dtv = softplusf_(raw);
    dtL[r * 66 + d] = (_Float16)dtv;
    SDTp[(size_t)r * DI + d] = (h16)dtv;
  }
  h16* SBp = SB2 + ((size_t)i * L_ + t0) * DS;
  h16* SCp = SC2 + ((size_t)i * L_ + t0) * DS;
  for (int k = tid; k < 1024; k += 256) {
    int s = k & 15, r = k >> 4;
    SBp[(size_t)r * DS + s] = (h16)U.xdS[r][2 + s];
    SCp[(size_t)r * DS + s] = (h16)U.xdS[r][18 + s];
  }
  __syncthreads();

  // ---- fused local scan: wave w -> seg=w>>1, shalf=w&1, d=lane
  {
    int seg = w >> 1, shalf = w & 1;
    int s0 = shalf * 8;
    float Av[16];
#pragma unroll
    for (int s = 0; s < 16; ++s) Av[s] = -__expf(A_log[lane * 16 + s]);
    float A0 = Av[0];
    bool okf = true;
#pragma unroll
    for (int s = 0; s < 16; ++s)
      okf &= fabsf(Av[s] - (float)(s + 1) * A0) <= 1e-4f * fabsf(Av[s]);
    int fastp = __all(okf ? 1 : 0);
    float h[8];
#pragma unroll
    for (int j = 0; j < 8; ++j) h[j] = 0.f;
    float sdt = 0.f;
    int rowbase = seg * SL;
    for (int t = 0; t < SL; ++t) {
      int row = rowbase + t;
      float dt = (float)dtL[row * 66 + lane];
      float xv = (float)xH[row][lane];
      float dtx = dt * xv;
      float dA[8];
      if (fastp) {
        powladder8_(__expf(A0 * dt), dA);
        if (shalf) {
          float E8 = dA[7];
#pragma unroll
          for (int j = 0; j < 8; ++j) dA[j] *= E8;
        }
      } else {
#pragma unroll
        for (int j = 0; j < 8; ++j) dA[j] = __expf(Av[s0 + j] * dt);
      }
      const float* brow = &U.xdS[row][2 + s0];
#pragma unroll
      for (int j = 0; j < 8; ++j) h[j] = fmaf(dA[j], h[j], dtx * brow[j]);
      sdt += dt;
    }
    float P[8];
    if (fastp) {
      powladder8_(__expf(A0 * sdt), P);
      if (shalf) {
        float E8 = P[7];
#pragma unroll
        for (int j = 0; j < 8; ++j) P[j] *= E8;
      }
    } else {
#pragma unroll
      for (int j = 0; j < 8; ++j) P[j] = __expf(Av[s0 + j] * sdt);
    }
    int segg = tile * 2 + seg;
    size_t base = (((size_t)i * DI + lane) * NSEG + segg) * DS + s0;
    *(float4*)(Pp + base) = *(float4*)&P[0];
    *(float4*)(Pp + base + 4) = *(float4*)&P[4];
    *(float4*)(Qp + base) = *(float4*)&h[0];
    *(float4*)(Qp + base + 4) = *(float4*)&h[4];
  }
  __syncthreads();   // xdS fully consumed; reuse union as zL

  // z writeout: pack 4 consecutive zd per lane into LDS, then coalesced global
  {
    int tok = w * 16 + rsel;
    int zq = (lane >> 4) << 2;
#pragma unroll
    for (int mt = 0; mt < 4; ++mt) {
      f16x4 pk;
#pragma unroll
      for (int r = 0; r < 4; ++r) pk[r] = (_Float16)siluf_(zacc[mt][r]);
      *(f16x4*)&U.zL[tok][mt * 16 + zq] = pk;
    }
  }
  __syncthreads();
  h16* SZp = SZ2 + ((size_t)i * L_ + t0) * DI;
  for (int k = tid; k < 512; k += 256) {
    int r = k >> 3, dblk = (k & 7) * 8;
    f16x8 v = *(const f16x8*)&U.zL[r][dblk];
    *(f16x8*)&SZp[(size_t)r * DI + dblk] = v;
  }
}

// ---------------- K3b: inter-segment scan -> h0 per segment (overlays P) ------
// Batched 8-wide: loads pipeline, serial chain is just the fma.
__global__ __launch_bounds__(256) void k3b_comb(float* __restrict__ Pp,
                                                const float* __restrict__ Qp) {
  int g = blockIdx.x * 256 + threadIdx.x;  // 32768 = NI*DI*DS
  int s = g & 15;
  int r = g >> 4;          // over NI*DI
  size_t base = (size_t)r * NSEG * DS + s;
  float H = 0.f;
  for (int sb = 0; sb < NSEG; sb += 8) {
    float Pv[8], Qv[8];
#pragma unroll
    for (int j = 0; j < 8; ++j) {
      size_t a = base + (size_t)(sb + j) * DS;
      Pv[j] = Pp[a];
      Qv[j] = Qp[a];
    }
#pragma unroll
    for (int j = 0; j < 8; ++j) {
      size_t a = base + (size_t)(sb + j) * DS;
      Pp[a] = H;
      H = fmaf(Pv[j], H, Qv[j]);
    }
  }
}

// ---------------- K3c: final scan, fused with D-term/z-gate-mult/token-sums ----
__global__ __launch_bounds__(256) void k3c_scan(
    const float* __restrict__ A_log, const h16* __restrict__ SDT2,
    const h16* __restrict__ SX2, const h16* __restrict__ SB2,
    const h16* __restrict__ SC2, const h16* __restrict__ SZ2,
    const float* __restrict__ D_p, const float* __restrict__ H0p,
    h16* __restrict__ YS2, float* __restrict__ SUMYF) {
  int bid = blockIdx.x;             // i*32 + sg
  int i = bid >> 5, sg = bid & 31;
  int tid = threadIdx.x;
  int w = tid >> 6, lane = tid & 63;
  int seg = sg * 4 + w;
  int t0 = seg * SL;
  __shared__ float rowS[4][SL][36];   // [w][t][ B16 | C16 ] + pad
  {
    int tk = lane & 31, hf = lane >> 5;
    const h16* p = (hf ? SC2 : SB2) + ((size_t)i * L_ + t0 + tk) * DS;
    float4 r0 = *(const float4*)p;
    float4 r1 = *(const float4*)(p + 8);
    const h16* hp0 = (const h16*)&r0;
    const h16* hp1 = (const h16*)&r1;
#pragma unroll
    for (int s = 0; s < 8; ++s) {
      rowS[w][tk][hf * 16 + s] = (float)hp0[s];
      rowS[w][tk][hf * 16 + 8 + s] = (float)hp1[s];
    }
  }
  __syncthreads();
  float Av[16];
#pragma unroll
  for (int s = 0; s < 16; ++s) Av[s] = -__expf(A_log[lane * 16 + s]);
  float A0 = Av[0];
  bool okf = true;
#pragma unroll
  for (int s = 0; s < 16; ++s) okf &= fabsf(Av[s] - (float)(s + 1) * A0) <= 1e-4f * fabsf(Av[s]);
  int fastp = __all(okf ? 1 : 0);
  float Dp = D_p[lane];
  float h[16];
  {
    size_t base = (((size_t)i * DI + lane) * NSEG + seg) * DS;
#pragma unroll
    for (int j = 0; j < 4; ++j) *(float4*)&h[4 * j] = *(const float4*)(H0p + base + 4 * j);
  }
  const h16* pdt = SDT2 + ((size_t)i * L_ + t0) * DI + lane;
  const h16* pxx = SX2 + ((size_t)i * L_ + t0) * DI + lane;
  const h16* pzz = SZ2 + ((size_t)i * L_ + t0) * DI + lane;
  h16* pys = YS2 + ((size_t)i * L_ + t0) * DI + lane;
  float dtc = (float)pdt[0], xvc = (float)pxx[0], zvc = (float)pzz[0];
  float sum = 0.f;
  for (int t = 0; t < SL; ++t) {
    float dt = dtc, xv = xvc, zv = zvc;
    if (t < SL - 1) {
      dtc = (float)pdt[(t + 1) * DI];
      xvc = (float)pxx[(t + 1) * DI];
      zvc = (float)pzz[(t + 1) * DI];
    }
    const float* row = &rowS[w][t][0];
    float Bv[16], Cv[16];
#pragma unroll
    for (int j = 0; j < 4; ++j) {
      *(float4*)&Bv[4 * j] = *(const float4*)(row + 4 * j);
      *(float4*)&Cv[4 * j] = *(const float4*)(row + 16 + 4 * j);
    }
    float dtx = dt * xv;
    float dA[16];
    if (fastp) {
      powladder_(__expf(A0 * dt), dA);
    } else {
#pragma unroll
      for (int s = 0; s < 16; ++s) dA[s] = __expf(Av[s] * dt);
    }
    float y0 = 0.f, y1 = 0.f, y2 = 0.f, y3 = 0.f;
#pragma unroll
    for (int s = 0; s < 16; s += 4) {
      h[s] = fmaf(dA[s], h[s], dtx * Bv[s]);       y0 = fmaf(h[s], Cv[s], y0);
      h[s + 1] = fmaf(dA[s + 1], h[s + 1], dtx * Bv[s + 1]); y1 = fmaf(h[s + 1], Cv[s + 1], y1);
      h[s + 2] = fmaf(dA[s + 2], h[s + 2], dtx * Bv[s + 2]); y2 = fmaf(h[s + 2], Cv[s + 2], y2);
      h[s + 3] = fmaf(dA[s + 3], h[s + 3], dtx * Bv[s + 3]); y3 = fmaf(h[s + 3], Cv[s + 3], y3);
    }
    float y = (y0 + y1) + (y2 + y3);
    float yf = fmaf(xv, Dp, y) * zv;
    pys[(size_t)t * DI] = (h16)yf;
    sum += yf;
  }
  atomicAdd(&SUMYF[i * DI + lane], sum);
}

// ---------------- K4: SE gates ----------------
__global__ __launch_bounds__(64) void k4_gates(
    const float* __restrict__ out_W, const float* __restrict__ se_W1,
    const float* __restrict__ se_W2, const float* __restrict__ skip_p,
    const float* __restrict__ SUMYF, const float* __restrict__ SUMXN,
    float* __restrict__ GATES) {
  int i = blockIdx.x;
  int b = i >> 2, ch = i & 3;
  int tid = threadIdx.x;
  __shared__ float syS[64], catS[64], seS[2];
  syS[tid] = SUMYF[i * DI + tid];
  __syncthreads();
  float invL = 1.f / (float)L_;
  if (tid < 32) {
    float acc = 0.f;
#pragma unroll
    for (int dd = 0; dd < 64; ++dd) acc = fmaf(syS[dd], out_W[tid * 64 + dd], acc);
    catS[tid] = acc * invL;
  } else {
    int c = tid - 32;
    catS[tid] = skip_p[0] * SUMXN[b * C_ + ch * DM + c] * invL;
  }
  __syncthreads();
  if (tid < 2) {
    float acc = 0.f;
#pragma unroll
    for (int k = 0; k < 64; ++k) acc = fmaf(catS[k], se_W1[tid * 64 + k], acc);
    seS[tid] = fmaxf(acc, 0.f);
  }
  __syncthreads();
  float gg = fmaf(seS[0], se_W2[tid * 2 + 0], seS[1] * se_W2[tid * 2 + 1]);
  GATES[i * DI + tid] = sigmoidf_(gg);
}

// ---------------- K56: gated combine (MFMA) + LN2 + proj (MFMA) fused ---------
// Per (b,tile): xm never round-trips through global. yH/owH union with xmH
// (pre/post-LN2 phases disjoint). LDS ~54.5 KB -> 3 blocks/CU.
__global__ __launch_bounds__(256) void k56_comb_proj(
    const float* __restrict__ out_W, const float* __restrict__ skip_p,
    const float* __restrict__ GATES, const h16* __restrict__ YS2,
    const float* __restrict__ gn, const float* __restrict__ bn,
    const float* __restrict__ proj_W, const float* __restrict__ proj_b,
    const float* __restrict__ XN, float* __restrict__ out) {
  int bid = blockIdx.x;
  int b = bid >> 6, tile = bid & 63;
  int t0 = tile * 64;
  int tid = threadIdx.x;
  int w = __builtin_amdgcn_readfirstlane(tid >> 6);
  int lane = tid & 63;
  __shared__ __attribute__((aligned(16))) union {
    float xmS[64][132];
    _Float16 projH[128][136];
  } U;
  __shared__ __attribute__((aligned(16))) union {
    struct {
      _Float16 yH[64][72];
      _Float16 owH[32][72];
    } pre;
    _Float16 xmH[64][136];
  } V;
  __shared__ float gAll[4][64];
  __shared__ float gnS[128], bnS[128];

  if (tid < 128) { gnS[tid] = gn[tid]; bnS[tid] = bn[tid]; }
  // stage xn (full C rows, f32)
  const float* xm = XN + (size_t)b * L_ * C_;
  for (int k = tid; k < 8192; k += 256) {
    int tt = k >> 7, c = k & 127;
    U.xmS[tt][c] = xm[(size_t)(t0 + tt) * C_ + c];
  }
  if (tid < 256) gAll[tid >> 6][tid & 63] = GATES[(b * 4 + (tid >> 6)) * DI + (tid & 63)];
  for (int k = tid; k < 2048; k += 256) V.pre.owH[k >> 6][k & 63] = (_Float16)out_W[k];

  int rsel = lane & 15, ksel = (lane >> 4) * 8;
  float skip = skip_p[0];
  // per-channel gated combine: xm[tok][ch*32+o] = g1*M1 + g2*skip*xn
  for (int ch = 0; ch < 4; ++ch) {
    const h16* py = YS2 + ((size_t)(b * 4 + ch) * L_ + t0) * DI;
    for (int k = tid; k < 512; k += 256) {
      int tt = k >> 3, dblk = (k & 7) * 8;
      *(f16x8*)&V.pre.yH[tt][dblk] = *(const f16x8*)&py[(size_t)tt * DI + dblk];
    }
    __syncthreads();
    f16x8 a0 = *(const f16x8*)&V.pre.yH[w * 16 + rsel][ksel];
    f16x8 a1 = *(const f16x8*)&V.pre.yH[w * 16 + rsel][32 + ksel];
    int row0 = w * 16 + ((lane >> 4) << 2);
#pragma unroll
    for (int nt = 0; nt < 2; ++nt) {
      f16x8 b0 = *(const f16x8*)&V.pre.owH[nt * 16 + rsel][ksel];
      f16x8 b1 = *(const f16x8*)&V.pre.owH[nt * 16 + rsel][32 + ksel];
      f32x4 acc = {0.f, 0.f, 0.f, 0.f};
      acc = __builtin_amdgcn_mfma_f32_16x16x32_f16(a0, b0, acc, 0, 0, 0);
      acc = __builtin_amdgcn_mfma_f32_16x16x32_f16(a1, b1, acc, 0, 0, 0);
      int o = nt * 16 + rsel;
      float g1 = gAll[ch][o], g2s = gAll[ch][32 + o] * skip;
      int cc = ch * 32 + o;
#pragma unroll
      for (int r = 0; r < 4; ++r) {
        int tok = row0 + r;
        U.xmS[tok][cc] = g1 * acc[r] + g2s * U.xmS[tok][cc];
      }
    }
    __syncthreads();
  }

  // LN2 over xm rows
  {
    int tok = tid >> 2, q = tid & 3;
    float s = 0.f, qq = 0.f;
#pragma unroll
    for (int j = 0; j < 32; ++j) {
      float v = U.xmS[tok][4 * j + q];
      s += v; qq += v * v;
    }
    s = dpp_add_<0xB1>(s); qq = dpp_add_<0xB1>(qq);
    s = dpp_add_<0x4E>(s); qq = dpp_add_<0x4E>(qq);
    float m = s * (1.f / 128.f);
    float var = qq * (1.f / 128.f) - m * m;
    float rs = rsqrtf(var + 1e-5f);
#pragma unroll
    for (int j = 0; j < 32; ++j) {
      int c = 4 * j + q;
      float v = U.xmS[tok][c];
      U.xmS[tok][c] = (v - m) * rs * gnS[c] + bnS[c];
    }
  }
  __syncthreads();
  // convert LN output to h16 (xmH overlays dead yH/owH)
  for (int k = tid; k < 1024; k += 256) {
    int tt = k >> 4, cblk = (k & 15) * 8;
    float4 v0 = *(const float4*)&U.xmS[tt][cblk];
    float4 v1 = *(const float4*)&U.xmS[tt][cblk + 4];
    f16x8 hv;
    hv[0] = (_Float16)v0.x; hv[1] = (_Float16)v0.y;
    hv[2] = (_Float16)v0.z; hv[3] = (_Float16)v0.w;
    hv[4] = (_Float16)v1.x; hv[5] = (_Float16)v1.y;
    hv[6] = (_Float16)v1.z; hv[7] = (_Float16)v1.w;
    *(f16x8*)&V.xmH[tt][cblk] = hv;
  }
  __syncthreads();
  // stage proj_W as h16 over dead xmS
  for (int k = tid; k < 2048; k += 256) {
    int o = k >> 4, cblk = (k & 15) * 8;
    const float* wp = proj_W + o * 128 + cblk;
    float4 v0 = *(const float4*)wp;
    float4 v1 = *(const float4*)(wp + 4);
    f16x8 hv;
    hv[0] = (_Float16)v0.x; hv[1] = (_Float16)v0.y;
    hv[2] = (_Float16)v0.z; hv[3] = (_Float16)v0.w;
    hv[4] = (_Float16)v1.x; hv[5] = (_Float16)v1.y;
    hv[6] = (_Float16)v1.z; hv[7] = (_Float16)v1.w;
    *(f16x8*)&U.projH[o][cblk] = hv;
  }
  __syncthreads();
  // proj MFMA: M=64 (wave=mt), N=128, K=128
  f16x8 af[4];
#pragma unroll
  for (int kc = 0; kc < 4; ++kc)
    af[kc] = *(const f16x8*)&V.xmH[w * 16 + rsel][kc * 32 + ksel];
  int row0 = w * 16 + ((lane >> 4) << 2);
#pragma unroll
  for (int nt = 0; nt < 8; ++nt) {
    int o = nt * 16 + rsel;
    float pb = proj_b[o];
    f32x4 acc = {pb, pb, pb, pb};
#pragma unroll
    for (int kc = 0; kc < 4; ++kc) {
      f16x8 bf = *(const f16x8*)&U.projH[o][kc * 32 + ksel];
      acc = __builtin_amdgcn_mfma_f32_16x16x32_f16(af[kc], bf, acc, 0, 0, 0);
    }
    *(float4*)&out[((size_t)(b * OUT_ + o)) * L_ + t0 + row0] =
        make_float4(acc[0], acc[1], acc[2], acc[3]);
  }
}

extern "C" void kernel_launch(void* const* d_in, const int* in_sizes, int n_in,
                              void* d_out, int out_size, void* d_ws, size_t ws_size,
                              hipStream_t stream) {
  const float* x = (const float*)d_in[0];
  const float* norm_g = (const float*)d_in[1];
  const float* norm_b = (const float*)d_in[2];
  const float* proj_W = (const float*)d_in[3];
  const float* proj_b = (const float*)d_in[4];
  const float* skip = (const float*)d_in[5];
  const float* se_W1 = (const float*)d_in[6];
  const float* se_W2 = (const float*)d_in[7];
  const float* in_W = (const float*)d_in[8];
  const float* conv_W = (const float*)d_in[9];
  const float* conv_b = (const float*)d_in[10];
  const float* xproj_W = (const float*)d_in[11];
  const float* dt_W = (const float*)d_in[12];
  const float* dt_b = (const float*)d_in[13];
  const float* A_log = (const float*)d_in[14];
  const float* D_p = (const float*)d_in[15];
  const float* out_W = (const float*)d_in[16];
  float* out = (float*)d_out;

  // workspace (~135 MiB)
  float* XN = (float*)d_ws;                         // B*L*C f32
  float* SUMYF = XN + (size_t)B_ * L_ * C_;         // NI*DI
  float* SUMXN = SUMYF + NI * DI;                   // B*C
  float* GATES = SUMXN + B_ * C_;                   // NI*DI
  float* Pp = GATES + NI * DI;                      // NI*DI*NSEG*DS f32
  float* Qp = Pp + (size_t)NI * DI * NSEG * DS;
  h16* YS2 = (h16*)(Qp + (size_t)NI * DI * NSEG * DS);  // NI*L*DI h16
  h16* SX2 = YS2 + (size_t)NI * L_ * DI;
  h16* SDT2 = SX2 + (size_t)NI * L_ * DI;
  h16* SB2 = SDT2 + (size_t)NI * L_ * DI;           // NI*L*DS h16
  h16* SC2 = SB2 + (size_t)NI * L_ * DS;
  h16* SZ2 = SC2 + (size_t)NI * L_ * DS;            // NI*L*DI h16 (silu(z))
  h16* XNH = SZ2 + (size_t)NI * L_ * DI;            // B*L*C h16
  h16* WH = XNH + (size_t)B_ * L_ * C_;             // 4096 + 48*64 h16

  hipMemsetAsync(SUMYF, 0, (size_t)(NI * DI + B_ * C_) * sizeof(float), stream);
  k0_wcvt<<<28, 256, 0, stream>>>(in_W, xproj_W, WH);
  k1_ln<<<B_ * 64, 256, 0, stream>>>(x, norm_g, norm_b, XN, XNH, SUMXN);
  k2_prep<<<NI * 64, 256, 0, stream>>>(WH, conv_W, conv_b, dt_W, dt_b, A_log,
                                       XNH, SX2, SDT2, SB2, SC2, SZ2, Pp, Qp);
  k3b_comb<<<128, 256, 0, stream>>>(Pp, Qp);
  k3c_scan<<<NI * 32, 256, 0, stream>>>(A_log, SDT2, SX2, SB2, SC2, SZ2, D_p,
                                        Pp, YS2, SUMYF);
  k4_gates<<<NI, 64, 0, stream>>>(out_W, se_W1, se_W2, skip, SUMYF, SUMXN, GATES);
  k56_comb_proj<<<B_ * 64, 256, 0, stream>>>(out_W, skip, GATES, YS2, norm_g,
                                             norm_b, proj_W, proj_b, XN, out);
}

// Round 6
// 214.029 us; speedup vs baseline: 1.3866x; 1.0004x over previous
//
#include <hip/hip_runtime.h>
#include <math.h>

typedef _Float16 h16;

#define DEV static __device__ __forceinline__

constexpr int B_ = 8, C_ = 128, L_ = 4096, OUT_ = 128;
constexpr int NCH = 4, DM = 32, DS = 16, DI = 64;
constexpr int NI = 32;            // B_*NCH instances
constexpr int NSEG = 128;         // scan segments
constexpr int SL = L_ / NSEG;     // 32 steps per segment

DEV float sigmoidf_(float x) { return 1.f / (1.f + __expf(-x)); }
DEV float siluf_(float x) { return x * sigmoidf_(x); }
DEV float softplusf_(float x) { return (x > 20.f) ? x : __logf(1.f + __expf(x)); }

template <int CTRL>
DEV float dpp_add_(float x) {
  int v = __builtin_amdgcn_update_dpp(0, __float_as_int(x), CTRL, 0xf, 0xf, false);
  return x + __int_as_float(v);
}

typedef __attribute__((ext_vector_type(8))) _Float16 f16x8;
typedef __attribute__((ext_vector_type(4))) _Float16 f16x4;
typedef __attribute__((ext_vector_type(4))) float f32x4;

// log-depth powers: out[s] = E^(s+1)
DEV void powladder_(float E, float* out) {
  float E2 = E * E;
  float E4 = E2 * E2;
  float E8 = E4 * E4;
  float E3 = E2 * E;
  out[0] = E;       out[1] = E2;      out[2] = E3;      out[3] = E4;
  out[4] = E4 * E;  out[5] = E4 * E2; out[6] = E4 * E3; out[7] = E8;
  out[8] = E8 * E;  out[9] = E8 * E2; out[10] = E8 * E3; out[11] = E8 * E4;
  out[12] = E8 * out[4]; out[13] = E8 * out[5]; out[14] = E8 * out[6];
  out[15] = E8 * E8;
}

// 8-deep ladder: out[j] = E^(j+1)
DEV void powladder8_(float E, float* out) {
  float E2 = E * E, E3 = E2 * E, E4 = E2 * E2;
  out[0] = E; out[1] = E2; out[2] = E3; out[3] = E4;
  out[4] = E4 * E; out[5] = E4 * E2; out[6] = E4 * E3; out[7] = E4 * E4;
}

// ---------------- K0: one-shot weight convert to h16 + workspace zero --------
// WH layout: [0,4096) = in_W; [4096, 7168) = xproj_W padded to 48 rows.
// Also zeros SUMYF (2048) + SUMXN (1024), contiguous at Zp.
__global__ __launch_bounds__(256) void k0_wcvt(const float* __restrict__ in_W,
                                               const float* __restrict__ xproj_W,
                                               h16* __restrict__ WH,
                                               float* __restrict__ Zp) {
  int tid = blockIdx.x * 256 + threadIdx.x;
  if (tid < 3072) Zp[tid] = 0.f;
  if (tid < 4096) {
    WH[tid] = (h16)in_W[tid];
  } else {
    int j = tid - 4096;
    int r = j >> 6;
    WH[tid] = (r < 34) ? (h16)xproj_W[r * 64 + (j & 63)] : (h16)0.f;
  }
}

// ---------------- K1: LayerNorm1 (B,C,L)->(B,L,C) h16 + token sums -----------
__global__ __launch_bounds__(256) void k1_ln(const float* __restrict__ x,
                                             const float* __restrict__ gn,
                                             const float* __restrict__ bn,
                                             h16* __restrict__ XNH,
                                             float* __restrict__ SUMXN) {
  int bid = blockIdx.x;
  int b = bid >> 6, tile = bid & 63;
  int t0 = tile * 64;
  int tid = threadIdx.x;
  __shared__ float xT[128][65];
  __shared__ float gnS[128], bnS[128];
  __shared__ float red[256];
  if (tid < 128) { gnS[tid] = gn[tid]; bnS[tid] = bn[tid]; }
  for (int k = tid; k < 8192; k += 256) {
    int c = k >> 6, tt = k & 63;
    xT[c][tt] = x[((size_t)(b * C_ + c)) * L_ + t0 + tt];
  }
  __syncthreads();
  {
    int tok = tid >> 2, q = tid & 3;
    float s = 0.f, qq = 0.f;
#pragma unroll
    for (int j = 0; j < 32; ++j) {
      float v = xT[q + 4 * j][tok];
      s += v; qq += v * v;
    }
    s = dpp_add_<0xB1>(s); qq = dpp_add_<0xB1>(qq);
    s = dpp_add_<0x4E>(s); qq = dpp_add_<0x4E>(qq);
    float m = s * (1.f / 128.f);
    float var = qq * (1.f / 128.f) - m * m;
    float rs = rsqrtf(var + 1e-5f);
#pragma unroll
    for (int j = 0; j < 32; ++j) {
      int c = q + 4 * j;
      float v = xT[c][tok];
      xT[c][tok] = (v - m) * rs * gnS[c] + bnS[c];
    }
  }
  __syncthreads();
  float acc = 0.f;
  int cfix = tid & 127;
  for (int k = tid; k < 8192; k += 256) {
    int tt = k >> 7, c = k & 127;
    acc += xT[c][tt];
  }
  // h16 write (coalesced 16B stores)
  for (int k = tid; k < 1024; k += 256) {
    int tt = k >> 4, c8 = (k & 15) * 8;
    f16x8 hv;
#pragma unroll
    for (int j = 0; j < 8; ++j) hv[j] = (_Float16)xT[c8 + j][tt];
    *(f16x8*)&XNH[((size_t)(b * L_ + t0 + tt)) * C_ + c8] = hv;
  }
  red[tid] = acc;
  __syncthreads();
  if (tid < 128) atomicAdd(&SUMXN[b * C_ + cfix], red[tid] + red[tid + 128]);
}

// ---------------- K2: in-proj + conv + silu + x-proj + dt + z + LOCAL SCAN ----
// preH stride 68: in-proj store groups land on disjoint bank octets.
__global__ __launch_bounds__(256) void k2_prep(
    const h16* __restrict__ WH, const float* __restrict__ conv_W,
    const float* __restrict__ conv_b, const float* __restrict__ dt_W,
    const float* __restrict__ dt_b, const float* __restrict__ A_log,
    const h16* __restrict__ XNH, h16* __restrict__ SX2, h16* __restrict__ SDT2,
    h16* __restrict__ SB2, h16* __restrict__ SC2, h16* __restrict__ SZ2,
    float* __restrict__ Pp, float* __restrict__ Qp) {
  int bid = blockIdx.x;
  int i = bid >> 6, tile = bid & 63;
  int b = i >> 2, ch = i & 3;
  int t0 = tile * 64;
  int tid = threadIdx.x;
  int w = __builtin_amdgcn_readfirstlane(tid >> 6);
  int lane = tid & 63;

  __shared__ __attribute__((aligned(16))) union {
    struct {
      _Float16 uH[80][40];   // rows 0..66 = tokens t0-3..t0+63; 67..79 zero
      _Float16 w1H[64][40];  // in_W x-half, row=d, col=c
    } s;
    float xdS[64][36];       // x-proj output, row=token, col=o (34 used)
    _Float16 zL[64][88];     // silu(z) bounce
  } U;
  __shared__ __attribute__((aligned(16))) _Float16 preH[80][68];  // in-proj out; later dtL
  __shared__ __attribute__((aligned(16))) _Float16 xH[64][72];    // conv+silu out
  __shared__ __attribute__((aligned(16))) _Float16 w2H[48][72];   // xproj_W padded
  __shared__ float convWS[64][4];
  __shared__ float dtWS[64][2];
  __shared__ float dtbS[64], cbS[64];

  convWS[tid >> 2][tid & 3] = conv_W[tid];
  if (tid < 128) dtWS[tid >> 1][tid & 1] = dt_W[tid];
  if (tid < 64) { dtbS[tid] = dt_b[tid]; cbS[tid] = conv_b[tid]; }
  // u from XNH (16B vector loads)
  const h16* xnh = XNH + (size_t)b * L_ * C_ + ch * DM;
  for (int k = tid; k < 320; k += 256) {
    int r = k >> 2, c8 = (k & 3) * 8;
    int tg = t0 - 3 + r;
    f16x8 v = {0, 0, 0, 0, 0, 0, 0, 0};
    if (r < 67 && tg >= 0) v = *(const f16x8*)&xnh[(size_t)tg * C_ + c8];
    *(f16x8*)&U.s.uH[r][c8] = v;
  }
  // x-half weights: h16 vector copies
  {
    int r = tid >> 2, c8 = (tid & 3) * 8;
    *(f16x8*)&U.s.w1H[r][c8] = *(const f16x8*)&WH[r * 32 + c8];
  }
  for (int k = tid; k < 384; k += 256) {
    int r = k >> 3, c8 = (k & 7) * 8;
    *(f16x8*)&w2H[r][c8] = *(const f16x8*)&WH[4096 + r * 64 + c8];
  }
  __syncthreads();

  int rsel = lane & 15, ksel = (lane >> 4) * 8;
  // in-proj MFMA: wave w owns N-tile nt=w, loops 5 M-tiles
  {
    int nt = w;
    f16x8 bf = *(const f16x8*)&U.s.w1H[nt * 16 + rsel][ksel];
    int row0q = (lane >> 4) << 2;
    int col = nt * 16 + rsel;
#pragma unroll
    for (int mt = 0; mt < 5; ++mt) {
      f16x8 af = *(const f16x8*)&U.s.uH[mt * 16 + rsel][ksel];
      f32x4 acc = {0.f, 0.f, 0.f, 0.f};
      acc = __builtin_amdgcn_mfma_f32_16x16x32_f16(af, bf, acc, 0, 0, 0);
      int row0 = mt * 16 + row0q;
#pragma unroll
      for (int r = 0; r < 4; ++r) preH[row0 + r][col] = (_Float16)acc[r];
    }
  }
  // z-gate MFMA (transposed): D[zd][token]; A-frags direct from WH (L2-hot)
  f32x4 zacc[4];
  {
    f16x8 bf = *(const f16x8*)&U.s.uH[3 + w * 16 + rsel][ksel];
#pragma unroll
    for (int mt = 0; mt < 4; ++mt) {
      f16x8 af = *(const f16x8*)&WH[(size_t)(64 + mt * 16 + rsel) * 32 + ksel];
      f32x4 acc = {0.f, 0.f, 0.f, 0.f};
      zacc[mt] = __builtin_amdgcn_mfma_f32_16x16x32_f16(af, bf, acc, 0, 0, 0);
    }
  }
  __syncthreads();

  // causal depthwise conv + silu; write xH + SX2 inline
  h16* SXp = SX2 + ((size_t)i * L_ + t0) * DI;
  for (int k = tid; k < 4096; k += 256) {
    int r = k >> 6, d = k & 63;
    float v = cbS[d];
#pragma unroll
    for (int j = 0; j < 4; ++j) v = fmaf(convWS[d][j], (float)preH[r + j][d], v);
    v = siluf_(v);
    xH[r][d] = (_Float16)v;
    SXp[(size_t)r * DI + d] = (h16)v;
  }
  __syncthreads();

  // x-proj MFMA: wave w owns M-tile mt=w; K=64 as 2 chunks; N padded to 48
  {
    int mt = w;
    f16x8 a0 = *(const f16x8*)&xH[mt * 16 + rsel][ksel];
    f16x8 a1 = *(const f16x8*)&xH[mt * 16 + rsel][32 + ksel];
    int row0 = mt * 16 + ((lane >> 4) << 2);
#pragma unroll
    for (int nt = 0; nt < 3; ++nt) {
      f16x8 b0 = *(const f16x8*)&w2H[nt * 16 + rsel][ksel];
      f16x8 b1 = *(const f16x8*)&w2H[nt * 16 + rsel][32 + ksel];
      f32x4 acc = {0.f, 0.f, 0.f, 0.f};
      acc = __builtin_amdgcn_mfma_f32_16x16x32_f16(a0, b0, acc, 0, 0, 0);
      acc = __builtin_amdgcn_mfma_f32_16x16x32_f16(a1, b1, acc, 0, 0, 0);
      int col = nt * 16 + rsel;
      if (col < 34) {
#pragma unroll
        for (int r = 0; r < 4; ++r) U.xdS[row0 + r][col] = acc[r];
      }
    }
  }
  __syncthreads();

  // dt -> LDS (reuse dead preH, stride 68) + SDT2; B/C writeout
  h16* dtL = (h16*)&preH[0][0];
  h16* SDTp = SDT2 + ((size_t)i * L_ + t0) * DI;
  for (int k = tid; k < 4096; k += 256) {
    int d = k & 63, r = k >> 6;
    float raw = fmaf(U.xdS[r][0], dtWS[d][0], fmaf(U.xdS[r][1], dtWS[d][1], dtbS[d]));
    float dtv = softplusf_(raw);
    dtL[r * 68 + d] = (_Float16)dtv;
    SDTp[(size_t)r * DI + d] = (h16)dtv;
  }
  h16* SBp = SB2 + ((size_t)i * L_ + t0) * DS;
  h16* SCp = SC2 + ((size_t)i * L_ + t0) * DS;
  for (int k = tid; k < 1024; k += 256) {
    int s = k & 15, r = k >> 4;
    SBp[(size_t)r * DS + s] = (h16)U.xdS[r][2 + s];
    SCp[(size_t)r * DS + s] = (h16)U.xdS[r][18 + s];
  }
  __syncthreads();

  // ---- fused local scan: wave w -> seg=w>>1, shalf=w&1, d=lane
  {
    int seg = w >> 1, shalf = w & 1;
    int s0 = shalf * 8;
    float Av[16];
#pragma unroll
    for (int s = 0; s < 16; ++s) Av[s] = -__expf(A_log[lane * 16 + s]);
    float A0 = Av[0];
    bool okf = true;
#pragma unroll
    for (int s = 0; s < 16; ++s)
      okf &= fabsf(Av[s] - (float)(s + 1) * A0) <= 1e-4f * fabsf(Av[s]);
    int fastp = __all(okf ? 1 : 0);
    float h[8];
#pragma unroll
    for (int j = 0; j < 8; ++j) h[j] = 0.f;
    float sdt = 0.f;
    int rowbase = seg * SL;
    for (int t = 0; t < SL; ++t) {
      int row = rowbase + t;
      float dt = (float)dtL[row * 68 + lane];
      float xv = (float)xH[row][lane];
      float dtx = dt * xv;
      float dA[8];
      if (fastp) {
        powladder8_(__expf(A0 * dt), dA);
        if (shalf) {
          float E8 = dA[7];
#pragma unroll
          for (int j = 0; j < 8; ++j) dA[j] *= E8;
        }
      } else {
#pragma unroll
        for (int j = 0; j < 8; ++j) dA[j] = __expf(Av[s0 + j] * dt);
      }
      const float* brow = &U.xdS[row][2 + s0];
#pragma unroll
      for (int j = 0; j < 8; ++j) h[j] = fmaf(dA[j], h[j], dtx * brow[j]);
      sdt += dt;
    }
    float P[8];
    if (fastp) {
      powladder8_(__expf(A0 * sdt), P);
      if (shalf) {
        float E8 = P[7];
#pragma unroll
        for (int j = 0; j < 8; ++j) P[j] *= E8;
      }
    } else {
#pragma unroll
      for (int j = 0; j < 8; ++j) P[j] = __expf(Av[s0 + j] * sdt);
    }
    int segg = tile * 2 + seg;
    size_t base = (((size_t)i * DI + lane) * NSEG + segg) * DS + s0;
    *(float4*)(Pp + base) = *(float4*)&P[0];
    *(float4*)(Pp + base + 4) = *(float4*)&P[4];
    *(float4*)(Qp + base) = *(float4*)&h[0];
    *(float4*)(Qp + base + 4) = *(float4*)&h[4];
  }
  __syncthreads();   // xdS fully consumed; reuse union as zL

  // z writeout: pack 4 consecutive zd per lane into LDS, then coalesced global
  {
    int tok = w * 16 + rsel;
    int zq = (lane >> 4) << 2;
#pragma unroll
    for (int mt = 0; mt < 4; ++mt) {
      f16x4 pk;
#pragma unroll
      for (int r = 0; r < 4; ++r) pk[r] = (_Float16)siluf_(zacc[mt][r]);
      *(f16x4*)&U.zL[tok][mt * 16 + zq] = pk;
    }
  }
  __syncthreads();
  h16* SZp = SZ2 + ((size_t)i * L_ + t0) * DI;
  for (int k = tid; k < 512; k += 256) {
    int r = k >> 3, dblk = (k & 7) * 8;
    f16x8 v = *(const f16x8*)&U.zL[r][dblk];
    *(f16x8*)&SZp[(size_t)r * DI + dblk] = v;
  }
}

// ---------------- K3b: inter-segment scan -> h0 per segment (overlays P) ------
__global__ __launch_bounds__(256) void k3b_comb(float* __restrict__ Pp,
                                                const float* __restrict__ Qp) {
  int g = blockIdx.x * 256 + threadIdx.x;  // 32768 = NI*DI*DS
  int s = g & 15;
  int r = g >> 4;          // over NI*DI
  size_t base = (size_t)r * NSEG * DS + s;
  float H = 0.f;
  for (int sb = 0; sb < NSEG; sb += 8) {
    float Pv[8], Qv[8];
#pragma unroll
    for (int j = 0; j < 8; ++j) {
      size_t a = base + (size_t)(sb + j) * DS;
      Pv[j] = Pp[a];
      Qv[j] = Qp[a];
    }
#pragma unroll
    for (int j = 0; j < 8; ++j) {
      size_t a = base + (size_t)(sb + j) * DS;
      Pp[a] = H;
      H = fmaf(Pv[j], H, Qv[j]);
    }
  }
}

// ---------------- K3c: final scan, fused with D-term/z-gate-mult/token-sums ----
__global__ __launch_bounds__(256) void k3c_scan(
    const float* __restrict__ A_log, const h16* __restrict__ SDT2,
    const h16* __restrict__ SX2, const h16* __restrict__ SB2,
    const h16* __restrict__ SC2, const h16* __restrict__ SZ2,
    const float* __restrict__ D_p, const float* __restrict__ H0p,
    h16* __restrict__ YS2, float* __restrict__ SUMYF) {
  int bid = blockIdx.x;             // i*32 + sg
  int i = bid >> 5, sg = bid & 31;
  int tid = threadIdx.x;
  int w = tid >> 6, lane = tid & 63;
  int seg = sg * 4 + w;
  int t0 = seg * SL;
  __shared__ float rowS[4][SL][36];   // [w][t][ B16 | C16 ] + pad
  {
    int tk = lane & 31, hf = lane >> 5;
    const h16* p = (hf ? SC2 : SB2) + ((size_t)i * L_ + t0 + tk) * DS;
    float4 r0 = *(const float4*)p;
    float4 r1 = *(const float4*)(p + 8);
    const h16* hp0 = (const h16*)&r0;
    const h16* hp1 = (const h16*)&r1;
#pragma unroll
    for (int s = 0; s < 8; ++s) {
      rowS[w][tk][hf * 16 + s] = (float)hp0[s];
      rowS[w][tk][hf * 16 + 8 + s] = (float)hp1[s];
    }
  }
  __syncthreads();
  float Av[16];
#pragma unroll
  for (int s = 0; s < 16; ++s) Av[s] = -__expf(A_log[lane * 16 + s]);
  float A0 = Av[0];
  bool okf = true;
#pragma unroll
  for (int s = 0; s < 16; ++s) okf &= fabsf(Av[s] - (float)(s + 1) * A0) <= 1e-4f * fabsf(Av[s]);
  int fastp = __all(okf ? 1 : 0);
  float Dp = D_p[lane];
  float h[16];
  {
    size_t base = (((size_t)i * DI + lane) * NSEG + seg) * DS;
#pragma unroll
    for (int j = 0; j < 4; ++j) *(float4*)&h[4 * j] = *(const float4*)(H0p + base + 4 * j);
  }
  const h16* pdt = SDT2 + ((size_t)i * L_ + t0) * DI + lane;
  const h16* pxx = SX2 + ((size_t)i * L_ + t0) * DI + lane;
  const h16* pzz = SZ2 + ((size_t)i * L_ + t0) * DI + lane;
  h16* pys = YS2 + ((size_t)i * L_ + t0) * DI + lane;
  float dtc = (float)pdt[0], xvc = (float)pxx[0], zvc = (float)pzz[0];
  float sum = 0.f;
  for (int t = 0; t < SL; ++t) {
    float dt = dtc, xv = xvc, zv = zvc;
    if (t < SL - 1) {
      dtc = (float)pdt[(t + 1) * DI];
      xvc = (float)pxx[(t + 1) * DI];
      zvc = (float)pzz[(t + 1) * DI];
    }
    const float* row = &rowS[w][t][0];
    float Bv[16], Cv[16];
#pragma unroll
    for (int j = 0; j < 4; ++j) {
      *(float4*)&Bv[4 * j] = *(const float4*)(row + 4 * j);
      *(float4*)&Cv[4 * j] = *(const float4*)(row + 16 + 4 * j);
    }
    float dtx = dt * xv;
    float dA[16];
    if (fastp) {
      powladder_(__expf(A0 * dt), dA);
    } else {
#pragma unroll
      for (int s = 0; s < 16; ++s) dA[s] = __expf(Av[s] * dt);
    }
    float y0 = 0.f, y1 = 0.f, y2 = 0.f, y3 = 0.f;
#pragma unroll
    for (int s = 0; s < 16; s += 4) {
      h[s] = fmaf(dA[s], h[s], dtx * Bv[s]);       y0 = fmaf(h[s], Cv[s], y0);
      h[s + 1] = fmaf(dA[s + 1], h[s + 1], dtx * Bv[s + 1]); y1 = fmaf(h[s + 1], Cv[s + 1], y1);
      h[s + 2] = fmaf(dA[s + 2], h[s + 2], dtx * Bv[s + 2]); y2 = fmaf(h[s + 2], Cv[s + 2], y2);
      h[s + 3] = fmaf(dA[s + 3], h[s + 3], dtx * Bv[s + 3]); y3 = fmaf(h[s + 3], Cv[s + 3], y3);
    }
    float y = (y0 + y1) + (y2 + y3);
    float yf = fmaf(xv, Dp, y) * zv;
    pys[(size_t)t * DI] = (h16)yf;
    sum += yf;
  }
  atomicAdd(&SUMYF[i * DI + lane], sum);
}

// ---------------- K56: SE gates + gated combine (MFMA) + LN2 + proj (MFMA) ----
// k4 folded in as a cheap per-block prologue (catS/seL overlay unused yH).
__global__ __launch_bounds__(256) void k56_comb_proj(
    const float* __restrict__ out_W, const float* __restrict__ skip_p,
    const float* __restrict__ se_W1, const float* __restrict__ se_W2,
    const float* __restrict__ SUMYF, const float* __restrict__ SUMXN,
    const h16* __restrict__ YS2, const float* __restrict__ gn,
    const float* __restrict__ bn, const float* __restrict__ proj_W,
    const float* __restrict__ proj_b, const h16* __restrict__ XNH,
    float* __restrict__ out) {
  int bid = blockIdx.x;
  int b = bid >> 6, tile = bid & 63;
  int t0 = tile * 64;
  int tid = threadIdx.x;
  int w = __builtin_amdgcn_readfirstlane(tid >> 6);
  int lane = tid & 63;
  __shared__ __attribute__((aligned(16))) union {
    float xmS[64][132];
    _Float16 projH[128][136];
  } U;
  __shared__ __attribute__((aligned(16))) union {
    struct {
      _Float16 yH[64][72];
      _Float16 owH[32][72];
    } pre;
    _Float16 xmH[64][136];
  } V;
  __shared__ float gAll[4][64];
  __shared__ float gnS[128], bnS[128];
  // catS/seL overlay the yH region (dead until the ch loop)
  float* catS = (float*)&V.pre.yH[0][0];   // 4*64 floats
  float* seL = catS + 256;                 // 8 floats

  if (tid < 128) { gnS[tid] = gn[tid]; bnS[tid] = bn[tid]; }
  for (int k = tid; k < 2048; k += 256) V.pre.owH[k >> 6][k & 63] = (_Float16)out_W[k];
  // stage xm from XNH (h16 -> f32)
  const h16* xmh = XNH + (size_t)b * L_ * C_;
  for (int k = tid; k < 1024; k += 256) {
    int tt = k >> 4, c8 = (k & 15) * 8;
    f16x8 hv = *(const f16x8*)&xmh[(size_t)(t0 + tt) * C_ + c8];
#pragma unroll
    for (int j = 0; j < 8; ++j) U.xmS[tt][c8 + j] = (float)hv[j];
  }
  // ---- gates (folded k4): phase A -> catS
  {
    int ch = tid >> 6, j = tid & 63;
    float invL = 1.f / (float)L_;
    if (j < 32) {
      const float* sy = SUMYF + (b * 4 + ch) * DI;
      const float* ow = out_W + j * 64;
      float acc = 0.f;
#pragma unroll
      for (int dd = 0; dd < 64; ++dd) acc = fmaf(sy[dd], ow[dd], acc);
      catS[ch * 64 + j] = acc * invL;
    } else {
      catS[ch * 64 + j] = skip_p[0] * SUMXN[b * C_ + ch * DM + (j - 32)] * invL;
    }
  }
  __syncthreads();
  if (tid < 8) {
    int ch = tid >> 1, r = tid & 1;
    float acc = 0.f;
#pragma unroll
    for (int k = 0; k < 64; ++k) acc = fmaf(catS[ch * 64 + k], se_W1[r * 64 + k], acc);
    seL[tid] = fmaxf(acc, 0.f);
  }
  __syncthreads();
  {
    int ch = tid >> 6, j = tid & 63;
    gAll[ch][j] = sigmoidf_(fmaf(seL[ch * 2], se_W2[j * 2], seL[ch * 2 + 1] * se_W2[j * 2 + 1]));
  }
  __syncthreads();   // gates done; yH region reusable

  int rsel = lane & 15, ksel = (lane >> 4) * 8;
  float skip = skip_p[0];
  // per-channel gated combine: xm[tok][ch*32+o] = g1*M1 + g2*skip*xn
  for (int ch = 0; ch < 4; ++ch) {
    const h16* py = YS2 + ((size_t)(b * 4 + ch) * L_ + t0) * DI;
    for (int k = tid; k < 512; k += 256) {
      int tt = k >> 3, dblk = (k & 7) * 8;
      *(f16x8*)&V.pre.yH[tt][dblk] = *(const f16x8*)&py[(size_t)tt * DI + dblk];
    }
    __syncthreads();
    f16x8 a0 = *(const f16x8*)&V.pre.yH[w * 16 + rsel][ksel];
    f16x8 a1 = *(const f16x8*)&V.pre.yH[w * 16 + rsel][32 + ksel];
    int row0 = w * 16 + ((lane >> 4) << 2);
#pragma unroll
    for (int nt = 0; nt < 2; ++nt) {
      f16x8 b0 = *(const f16x8*)&V.pre.owH[nt * 16 + rsel][ksel];
      f16x8 b1 = *(const f16x8*)&V.pre.owH[nt * 16 + rsel][32 + ksel];
      f32x4 acc = {0.f, 0.f, 0.f, 0.f};
      acc = __builtin_amdgcn_mfma_f32_16x16x32_f16(a0, b0, acc, 0, 0, 0);
      acc = __builtin_amdgcn_mfma_f32_16x16x32_f16(a1, b1, acc, 0, 0, 0);
      int o = nt * 16 + rsel;
      float g1 = gAll[ch][o], g2s = gAll[ch][32 + o] * skip;
      int cc = ch * 32 + o;
#pragma unroll
      for (int r = 0; r < 4; ++r) {
        int tok = row0 + r;
        U.xmS[tok][cc] = g1 * acc[r] + g2s * U.xmS[tok][cc];
      }
    }
    __syncthreads();
  }

  // LN2 over xm rows
  {
    int tok = tid >> 2, q = tid & 3;
    float s = 0.f, qq = 0.f;
#pragma unroll
    for (int j = 0; j < 32; ++j) {
      float v = U.xmS[tok][4 * j + q];
      s += v; qq += v * v;
    }
    s = dpp_add_<0xB1>(s); qq = dpp_add_<0xB1>(qq);
    s = dpp_add_<0x4E>(s); qq = dpp_add_<0x4E>(qq);
    float m = s * (1.f / 128.f);
    float var = qq * (1.f / 128.f) - m * m;
    float rs = rsqrtf(var + 1e-5f);
#pragma unroll
    for (int j = 0; j < 32; ++j) {
      int c = 4 * j + q;
      float v = U.xmS[tok][c];
      U.xmS[tok][c] = (v - m) * rs * gnS[c] + bnS[c];
    }
  }
  __syncthreads();
  // convert LN output to h16 (xmH overlays dead yH/owH)
  for (int k = tid; k < 1024; k += 256) {
    int tt = k >> 4, cblk = (k & 15) * 8;
    float4 v0 = *(const float4*)&U.xmS[tt][cblk];
    float4 v1 = *(const float4*)&U.xmS[tt][cblk + 4];
    f16x8 hv;
    hv[0] = (_Float16)v0.x; hv[1] = (_Float16)v0.y;
    hv[2] = (_Float16)v0.z; hv[3] = (_Float16)v0.w;
    hv[4] = (_Float16)v1.x; hv[5] = (_Float16)v1.y;
    hv[6] = (_Float16)v1.z; hv[7] = (_Float16)v1.w;
    *(f16x8*)&V.xmH[tt][cblk] = hv;
  }
  __syncthreads();
  // stage proj_W as h16 over dead xmS
  for (int k = tid; k < 2048; k += 256) {
    int o = k >> 4, cblk = (k & 15) * 8;
    const float* wp = proj_W + o * 128 + cblk;
    float4 v0 = *(const float4*)wp;
    float4 v1 = *(const float4*)(wp + 4);
    f16x8 hv;
    hv[0] = (_Float16)v0.x; hv[1] = (_Float16)v0.y;
    hv[2] = (_Float16)v0.z; hv[3] = (_Float16)v0.w;
    hv[4] = (_Float16)v1.x; hv[5] = (_Float16)v1.y;
    hv[6] = (_Float16)v1.z; hv[7] = (_Float16)v1.w;
    *(f16x8*)&U.projH[o][cblk] = hv;
  }
  __syncthreads();
  // proj MFMA: M=64 (wave=mt), N=128, K=128
  f16x8 af[4];
#pragma unroll
  for (int kc = 0; kc < 4; ++kc)
    af[kc] = *(const f16x8*)&V.xmH[w * 16 + rsel][kc * 32 + ksel];
  int row0 = w * 16 + ((lane >> 4) << 2);
#pragma unroll
  for (int nt = 0; nt < 8; ++nt) {
    int o = nt * 16 + rsel;
    float pb = proj_b[o];
    f32x4 acc = {pb, pb, pb, pb};
#pragma unroll
    for (int kc = 0; kc < 4; ++kc) {
      f16x8 bf = *(const f16x8*)&U.projH[o][kc * 32 + ksel];
      acc = __builtin_amdgcn_mfma_f32_16x16x32_f16(af[kc], bf, acc, 0, 0, 0);
    }
    *(float4*)&out[((size_t)(b * OUT_ + o)) * L_ + t0 + row0] =
        make_float4(acc[0], acc[1], acc[2], acc[3]);
  }
}

extern "C" void kernel_launch(void* const* d_in, const int* in_sizes, int n_in,
                              void* d_out, int out_size, void* d_ws, size_t ws_size,
                              hipStream_t stream) {
  const float* x = (const float*)d_in[0];
  const float* norm_g = (const float*)d_in[1];
  const float* norm_b = (const float*)d_in[2];
  const float* proj_W = (const float*)d_in[3];
  const float* proj_b = (const float*)d_in[4];
  const float* skip = (const float*)d_in[5];
  const float* se_W1 = (const float*)d_in[6];
  const float* se_W2 = (const float*)d_in[7];
  const float* in_W = (const float*)d_in[8];
  const float* conv_W = (const float*)d_in[9];
  const float* conv_b = (const float*)d_in[10];
  const float* xproj_W = (const float*)d_in[11];
  const float* dt_W = (const float*)d_in[12];
  const float* dt_b = (const float*)d_in[13];
  const float* A_log = (const float*)d_in[14];
  const float* D_p = (const float*)d_in[15];
  const float* out_W = (const float*)d_in[16];
  float* out = (float*)d_out;

  // workspace (~120 MiB)
  float* SUMYF = (float*)d_ws;                      // NI*DI
  float* SUMXN = SUMYF + NI * DI;                   // B*C
  float* Pp = SUMXN + B_ * C_;                      // NI*DI*NSEG*DS f32
  float* Qp = Pp + (size_t)NI * DI * NSEG * DS;
  h16* YS2 = (h16*)(Qp + (size_t)NI * DI * NSEG * DS);  // NI*L*DI h16
  h16* SX2 = YS2 + (size_t)NI * L_ * DI;
  h16* SDT2 = SX2 + (size_t)NI * L_ * DI;
  h16* SB2 = SDT2 + (size_t)NI * L_ * DI;           // NI*L*DS h16
  h16* SC2 = SB2 + (size_t)NI * L_ * DS;
  h16* SZ2 = SC2 + (size_t)NI * L_ * DS;            // NI*L*DI h16 (silu(z))
  h16* XNH = SZ2 + (size_t)NI * L_ * DI;            // B*L*C h16
  h16* WH = XNH + (size_t)B_ * L_ * C_;             // 7168 h16

  k0_wcvt<<<28, 256, 0, stream>>>(in_W, xproj_W, WH, SUMYF);
  k1_ln<<<B_ * 64, 256, 0, stream>>>(x, norm_g, norm_b, XNH, SUMXN);
  k2_prep<<<NI * 64, 256, 0, stream>>>(WH, conv_W, conv_b, dt_W, dt_b, A_log,
                                       XNH, SX2, SDT2, SB2, SC2, SZ2, Pp, Qp);
  k3b_comb<<<128, 256, 0, stream>>>(Pp, Qp);
  k3c_scan<<<NI * 32, 256, 0, stream>>>(A_log, SDT2, SX2, SB2, SC2, SZ2, D_p,
                                        Pp, YS2, SUMYF);
  k56_comb_proj<<<B_ * 64, 256, 0, stream>>>(out_W, skip, se_W1, se_W2, SUMYF,
                                             SUMXN, YS2, norm_g, norm_b, proj_W,
                                             proj_b, XNH, out);
}

// Round 7
// 212.009 us; speedup vs baseline: 1.3998x; 1.0095x over previous
//
#include <hip/hip_runtime.h>
#include <math.h>

typedef _Float16 h16;

#define DEV static __device__ __forceinline__

constexpr int B_ = 8, C_ = 128, L_ = 4096, OUT_ = 128;
constexpr int NCH = 4, DM = 32, DS = 16, DI = 64;
constexpr int NI = 32;            // B_*NCH instances
constexpr int NSEG = 128;         // scan segments
constexpr int SL = L_ / NSEG;     // 32 steps per segment

DEV float sigmoidf_(float x) { return 1.f / (1.f + __expf(-x)); }
DEV float siluf_(float x) { return x * sigmoidf_(x); }
DEV float softplusf_(float x) { return (x > 20.f) ? x : __logf(1.f + __expf(x)); }

template <int CTRL>
DEV float dpp_add_(float x) {
  int v = __builtin_amdgcn_update_dpp(0, __float_as_int(x), CTRL, 0xf, 0xf, false);
  return x + __int_as_float(v);
}

typedef __attribute__((ext_vector_type(8))) _Float16 f16x8;
typedef __attribute__((ext_vector_type(4))) _Float16 f16x4;
typedef __attribute__((ext_vector_type(4))) float f32x4;

// log-depth powers: out[s] = E^(s+1)
DEV void powladder_(float E, float* out) {
  float E2 = E * E;
  float E4 = E2 * E2;
  float E8 = E4 * E4;
  float E3 = E2 * E;
  out[0] = E;       out[1] = E2;      out[2] = E3;      out[3] = E4;
  out[4] = E4 * E;  out[5] = E4 * E2; out[6] = E4 * E3; out[7] = E8;
  out[8] = E8 * E;  out[9] = E8 * E2; out[10] = E8 * E3; out[11] = E8 * E4;
  out[12] = E8 * out[4]; out[13] = E8 * out[5]; out[14] = E8 * out[6];
  out[15] = E8 * E8;
}

// 8-deep ladder: out[j] = E^(j+1)
DEV void powladder8_(float E, float* out) {
  float E2 = E * E, E3 = E2 * E, E4 = E2 * E2;
  out[0] = E; out[1] = E2; out[2] = E3; out[3] = E4;
  out[4] = E4 * E; out[5] = E4 * E2; out[6] = E4 * E3; out[7] = E4 * E4;
}

// ---------------- K0: one-shot weight convert to h16 + workspace zero --------
__global__ __launch_bounds__(256) void k0_wcvt(const float* __restrict__ in_W,
                                               const float* __restrict__ xproj_W,
                                               h16* __restrict__ WH,
                                               float* __restrict__ Zp) {
  int tid = blockIdx.x * 256 + threadIdx.x;
  if (tid < 3072) Zp[tid] = 0.f;
  if (tid < 4096) {
    WH[tid] = (h16)in_W[tid];
  } else {
    int j = tid - 4096;
    int r = j >> 6;
    WH[tid] = (r < 34) ? (h16)xproj_W[r * 64 + (j & 63)] : (h16)0.f;
  }
}

// ---------------- K1: LayerNorm1 (B,C,L)->(B,L,C) h16 + token sums -----------
__global__ __launch_bounds__(256) void k1_ln(const float* __restrict__ x,
                                             const float* __restrict__ gn,
                                             const float* __restrict__ bn,
                                             h16* __restrict__ XNH,
                                             float* __restrict__ SUMXN) {
  int bid = blockIdx.x;
  int b = bid >> 6, tile = bid & 63;
  int t0 = tile * 64;
  int tid = threadIdx.x;
  __shared__ float xT[128][65];
  __shared__ float gnS[128], bnS[128];
  __shared__ float red[256];
  if (tid < 128) { gnS[tid] = gn[tid]; bnS[tid] = bn[tid]; }
  for (int k = tid; k < 8192; k += 256) {
    int c = k >> 6, tt = k & 63;
    xT[c][tt] = x[((size_t)(b * C_ + c)) * L_ + t0 + tt];
  }
  __syncthreads();
  {
    int tok = tid >> 2, q = tid & 3;
    float s = 0.f, qq = 0.f;
#pragma unroll
    for (int j = 0; j < 32; ++j) {
      float v = xT[q + 4 * j][tok];
      s += v; qq += v * v;
    }
    s = dpp_add_<0xB1>(s); qq = dpp_add_<0xB1>(qq);
    s = dpp_add_<0x4E>(s); qq = dpp_add_<0x4E>(qq);
    float m = s * (1.f / 128.f);
    float var = qq * (1.f / 128.f) - m * m;
    float rs = rsqrtf(var + 1e-5f);
#pragma unroll
    for (int j = 0; j < 32; ++j) {
      int c = q + 4 * j;
      float v = xT[c][tok];
      xT[c][tok] = (v - m) * rs * gnS[c] + bnS[c];
    }
  }
  __syncthreads();
  float acc = 0.f;
  int cfix = tid & 127;
  for (int k = tid; k < 8192; k += 256) {
    int tt = k >> 7, c = k & 127;
    acc += xT[c][tt];
  }
  // h16 write (coalesced 16B stores)
  for (int k = tid; k < 1024; k += 256) {
    int tt = k >> 4, c8 = (k & 15) * 8;
    f16x8 hv;
#pragma unroll
    for (int j = 0; j < 8; ++j) hv[j] = (_Float16)xT[c8 + j][tt];
    *(f16x8*)&XNH[((size_t)(b * L_ + t0 + tt)) * C_ + c8] = hv;
  }
  red[tid] = acc;
  __syncthreads();
  if (tid < 128) atomicAdd(&SUMXN[b * C_ + cfix], red[tid] + red[tid + 128]);
}

// ---------------- K2: in-proj + conv + silu + x-proj + dt + z + LOCAL SCAN ----
__global__ __launch_bounds__(256) void k2_prep(
    const h16* __restrict__ WH, const float* __restrict__ conv_W,
    const float* __restrict__ conv_b, const float* __restrict__ dt_W,
    const float* __restrict__ dt_b, const float* __restrict__ A_log,
    const h16* __restrict__ XNH, h16* __restrict__ SX2, h16* __restrict__ SDT2,
    h16* __restrict__ SB2, h16* __restrict__ SC2, h16* __restrict__ SZ2,
    float* __restrict__ Pp, float* __restrict__ Qp) {
  int bid = blockIdx.x;
  int i = bid >> 6, tile = bid & 63;
  int b = i >> 2, ch = i & 3;
  int t0 = tile * 64;
  int tid = threadIdx.x;
  int w = __builtin_amdgcn_readfirstlane(tid >> 6);
  int lane = tid & 63;

  __shared__ __attribute__((aligned(16))) union {
    struct {
      _Float16 uH[80][40];   // rows 0..66 = tokens t0-3..t0+63; 67..79 zero
      _Float16 w1H[64][40];  // in_W x-half, row=d, col=c
    } s;
    float xdS[64][36];       // x-proj output, row=token, col=o (34 used)
    _Float16 zL[64][88];     // silu(z) bounce
  } U;
  __shared__ __attribute__((aligned(16))) _Float16 preH[80][68];  // in-proj out; later dtL
  __shared__ __attribute__((aligned(16))) _Float16 xH[64][72];    // conv+silu out
  __shared__ __attribute__((aligned(16))) _Float16 w2H[48][72];   // xproj_W padded
  __shared__ float convWS[64][4];
  __shared__ float dtWS[64][2];
  __shared__ float dtbS[64], cbS[64];

  convWS[tid >> 2][tid & 3] = conv_W[tid];
  if (tid < 128) dtWS[tid >> 1][tid & 1] = dt_W[tid];
  if (tid < 64) { dtbS[tid] = dt_b[tid]; cbS[tid] = conv_b[tid]; }
  // u from XNH (16B vector loads)
  const h16* xnh = XNH + (size_t)b * L_ * C_ + ch * DM;
  for (int k = tid; k < 320; k += 256) {
    int r = k >> 2, c8 = (k & 3) * 8;
    int tg = t0 - 3 + r;
    f16x8 v = {0, 0, 0, 0, 0, 0, 0, 0};
    if (r < 67 && tg >= 0) v = *(const f16x8*)&xnh[(size_t)tg * C_ + c8];
    *(f16x8*)&U.s.uH[r][c8] = v;
  }
  // x-half weights: h16 vector copies
  {
    int r = tid >> 2, c8 = (tid & 3) * 8;
    *(f16x8*)&U.s.w1H[r][c8] = *(const f16x8*)&WH[r * 32 + c8];
  }
  for (int k = tid; k < 384; k += 256) {
    int r = k >> 3, c8 = (k & 7) * 8;
    *(f16x8*)&w2H[r][c8] = *(const f16x8*)&WH[4096 + r * 64 + c8];
  }
  __syncthreads();

  int rsel = lane & 15, ksel = (lane >> 4) * 8;
  // in-proj MFMA: wave w owns N-tile nt=w, loops 5 M-tiles
  {
    int nt = w;
    f16x8 bf = *(const f16x8*)&U.s.w1H[nt * 16 + rsel][ksel];
    int row0q = (lane >> 4) << 2;
    int col = nt * 16 + rsel;
#pragma unroll
    for (int mt = 0; mt < 5; ++mt) {
      f16x8 af = *(const f16x8*)&U.s.uH[mt * 16 + rsel][ksel];
      f32x4 acc = {0.f, 0.f, 0.f, 0.f};
      acc = __builtin_amdgcn_mfma_f32_16x16x32_f16(af, bf, acc, 0, 0, 0);
      int row0 = mt * 16 + row0q;
#pragma unroll
      for (int r = 0; r < 4; ++r) preH[row0 + r][col] = (_Float16)acc[r];
    }
  }
  // z-gate MFMA (transposed): D[zd][token]; A-frags direct from WH (L2-hot)
  f32x4 zacc[4];
  {
    f16x8 bf = *(const f16x8*)&U.s.uH[3 + w * 16 + rsel][ksel];
#pragma unroll
    for (int mt = 0; mt < 4; ++mt) {
      f16x8 af = *(const f16x8*)&WH[(size_t)(64 + mt * 16 + rsel) * 32 + ksel];
      f32x4 acc = {0.f, 0.f, 0.f, 0.f};
      zacc[mt] = __builtin_amdgcn_mfma_f32_16x16x32_f16(af, bf, acc, 0, 0, 0);
    }
  }
  __syncthreads();

  // causal depthwise conv + silu; write xH + SX2 inline
  h16* SXp = SX2 + ((size_t)i * L_ + t0) * DI;
  for (int k = tid; k < 4096; k += 256) {
    int r = k >> 6, d = k & 63;
    float v = cbS[d];
#pragma unroll
    for (int j = 0; j < 4; ++j) v = fmaf(convWS[d][j], (float)preH[r + j][d], v);
    v = siluf_(v);
    xH[r][d] = (_Float16)v;
    SXp[(size_t)r * DI + d] = (h16)v;
  }
  __syncthreads();

  // x-proj MFMA: wave w owns M-tile mt=w; K=64 as 2 chunks; N padded to 48
  {
    int mt = w;
    f16x8 a0 = *(const f16x8*)&xH[mt * 16 + rsel][ksel];
    f16x8 a1 = *(const f16x8*)&xH[mt * 16 + rsel][32 + ksel];
    int row0 = mt * 16 + ((lane >> 4) << 2);
#pragma unroll
    for (int nt = 0; nt < 3; ++nt) {
      f16x8 b0 = *(const f16x8*)&w2H[nt * 16 + rsel][ksel];
      f16x8 b1 = *(const f16x8*)&w2H[nt * 16 + rsel][32 + ksel];
      f32x4 acc = {0.f, 0.f, 0.f, 0.f};
      acc = __builtin_amdgcn_mfma_f32_16x16x32_f16(a0, b0, acc, 0, 0, 0);
      acc = __builtin_amdgcn_mfma_f32_16x16x32_f16(a1, b1, acc, 0, 0, 0);
      int col = nt * 16 + rsel;
      if (col < 34) {
#pragma unroll
        for (int r = 0; r < 4; ++r) U.xdS[row0 + r][col] = acc[r];
      }
    }
  }
  __syncthreads();

  // dt -> LDS (reuse dead preH, stride 68) + SDT2; B/C writeout
  h16* dtL = (h16*)&preH[0][0];
  h16* SDTp = SDT2 + ((size_t)i * L_ + t0) * DI;
  for (int k = tid; k < 4096; k += 256) {
    int d = k & 63, r = k >> 6;
    float raw = fmaf(U.xdS[r][0], dtWS[d][0], fmaf(U.xdS[r][1], dtWS[d][1], dtbS[d]));
    float dtv = softplusf_(raw);
    dtL[r * 68 + d] = (_Float16)dtv;
    SDTp[(size_t)r * DI + d] = (h16)dtv;
  }
  h16* SBp = SB2 + ((size_t)i * L_ + t0) * DS;
  h16* SCp = SC2 + ((size_t)i * L_ + t0) * DS;
  for (int k = tid; k < 1024; k += 256) {
    int s = k & 15, r = k >> 4;
    SBp[(size_t)r * DS + s] = (h16)U.xdS[r][2 + s];
    SCp[(size_t)r * DS + s] = (h16)U.xdS[r][18 + s];
  }
  __syncthreads();

  // ---- fused local scan: wave w -> seg=w>>1, shalf=w&1, d=lane
  {
    int seg = w >> 1, shalf = w & 1;
    int s0 = shalf * 8;
    float Av[16];
#pragma unroll
    for (int s = 0; s < 16; ++s) Av[s] = -__expf(A_log[lane * 16 + s]);
    float A0 = Av[0];
    bool okf = true;
#pragma unroll
    for (int s = 0; s < 16; ++s)
      okf &= fabsf(Av[s] - (float)(s + 1) * A0) <= 1e-4f * fabsf(Av[s]);
    int fastp = __all(okf ? 1 : 0);
    float h[8];
#pragma unroll
    for (int j = 0; j < 8; ++j) h[j] = 0.f;
    float sdt = 0.f;
    int rowbase = seg * SL;
    for (int t = 0; t < SL; ++t) {
      int row = rowbase + t;
      float dt = (float)dtL[row * 68 + lane];
      float xv = (float)xH[row][lane];
      float dtx = dt * xv;
      float dA[8];
      if (fastp) {
        powladder8_(__expf(A0 * dt), dA);
        if (shalf) {
          float E8 = dA[7];
#pragma unroll
          for (int j = 0; j < 8; ++j) dA[j] *= E8;
        }
      } else {
#pragma unroll
        for (int j = 0; j < 8; ++j) dA[j] = __expf(Av[s0 + j] * dt);
      }
      const float* brow = &U.xdS[row][2 + s0];
#pragma unroll
      for (int j = 0; j < 8; ++j) h[j] = fmaf(dA[j], h[j], dtx * brow[j]);
      sdt += dt;
    }
    float P[8];
    if (fastp) {
      powladder8_(__expf(A0 * sdt), P);
      if (shalf) {
        float E8 = P[7];
#pragma unroll
        for (int j = 0; j < 8; ++j) P[j] *= E8;
      }
    } else {
#pragma unroll
      for (int j = 0; j < 8; ++j) P[j] = __expf(Av[s0 + j] * sdt);
    }
    int segg = tile * 2 + seg;
    // seg-major layout: [i][seg][d][s] -> wave writes contiguous 4KB runs
    size_t base = (((size_t)i * NSEG + segg) * DI + lane) * DS + s0;
    *(float4*)(Pp + base) = *(float4*)&P[0];
    *(float4*)(Pp + base + 4) = *(float4*)&P[4];
    *(float4*)(Qp + base) = *(float4*)&h[0];
    *(float4*)(Qp + base + 4) = *(float4*)&h[4];
  }
  __syncthreads();   // xdS fully consumed; reuse union as zL

  // z writeout: pack 4 consecutive zd per lane into LDS, then coalesced global
  {
    int tok = w * 16 + rsel;
    int zq = (lane >> 4) << 2;
#pragma unroll
    for (int mt = 0; mt < 4; ++mt) {
      f16x4 pk;
#pragma unroll
      for (int r = 0; r < 4; ++r) pk[r] = (_Float16)siluf_(zacc[mt][r]);
      *(f16x4*)&U.zL[tok][mt * 16 + zq] = pk;
    }
  }
  __syncthreads();
  h16* SZp = SZ2 + ((size_t)i * L_ + t0) * DI;
  for (int k = tid; k < 512; k += 256) {
    int r = k >> 3, dblk = (k & 7) * 8;
    f16x8 v = *(const f16x8*)&U.zL[r][dblk];
    *(f16x8*)&SZp[(size_t)r * DI + dblk] = v;
  }
}

// ---------------- K3b: inter-segment scan -> h0 per segment (overlays P) ------
// seg-major layout: wave loads are 256B-contiguous, 4KB seg stride.
// Batch 16 -> 32 outstanding loads/thread hides L3 latency at 2 waves/CU.
__global__ __launch_bounds__(256) void k3b_comb(float* __restrict__ Pp,
                                                const float* __restrict__ Qp) {
  int g = blockIdx.x * 256 + threadIdx.x;  // 32768 = NI*DI*DS
  int ds = g & 1023;       // d*16+s within instance
  int i = g >> 10;
  size_t base = (size_t)i * NSEG * DI * DS + ds;
  constexpr int SST = DI * DS;   // 1024 floats per seg
  float H = 0.f;
  for (int sb = 0; sb < NSEG; sb += 16) {
    float Pv[16], Qv[16];
#pragma unroll
    for (int j = 0; j < 16; ++j) {
      size_t a = base + (size_t)(sb + j) * SST;
      Pv[j] = Pp[a];
      Qv[j] = Qp[a];
    }
#pragma unroll
    for (int j = 0; j < 16; ++j) {
      size_t a = base + (size_t)(sb + j) * SST;
      Pp[a] = H;
      H = fmaf(Pv[j], H, Qv[j]);
    }
  }
}

// ---------------- K3c: final scan, fused with D-term/z-gate-mult/token-sums ----
__global__ __launch_bounds__(256) void k3c_scan(
    const float* __restrict__ A_log, const h16* __restrict__ SDT2,
    const h16* __restrict__ SX2, const h16* __restrict__ SB2,
    const h16* __restrict__ SC2, const h16* __restrict__ SZ2,
    const float* __restrict__ D_p, const float* __restrict__ H0p,
    h16* __restrict__ YS2, float* __restrict__ SUMYF) {
  int bid = blockIdx.x;             // i*32 + sg
  int i = bid >> 5, sg = bid & 31;
  int tid = threadIdx.x;
  int w = tid >> 6, lane = tid & 63;
  int seg = sg * 4 + w;
  int t0 = seg * SL;
  __shared__ float rowS[4][SL][36];   // [w][t][ B16 | C16 ] + pad
  {
    int tk = lane & 31, hf = lane >> 5;
    const h16* p = (hf ? SC2 : SB2) + ((size_t)i * L_ + t0 + tk) * DS;
    float4 r0 = *(const float4*)p;
    float4 r1 = *(const float4*)(p + 8);
    const h16* hp0 = (const h16*)&r0;
    const h16* hp1 = (const h16*)&r1;
#pragma unroll
    for (int s = 0; s < 8; ++s) {
      rowS[w][tk][hf * 16 + s] = (float)hp0[s];
      rowS[w][tk][hf * 16 + 8 + s] = (float)hp1[s];
    }
  }
  __syncthreads();
  float Av[16];
#pragma unroll
  for (int s = 0; s < 16; ++s) Av[s] = -__expf(A_log[lane * 16 + s]);
  float A0 = Av[0];
  bool okf = true;
#pragma unroll
  for (int s = 0; s < 16; ++s) okf &= fabsf(Av[s] - (float)(s + 1) * A0) <= 1e-4f * fabsf(Av[s]);
  int fastp = __all(okf ? 1 : 0);
  float Dp = D_p[lane];
  float h[16];
  {
    // seg-major layout: per-wave contiguous 4KB read
    size_t base = (((size_t)i * NSEG + seg) * DI + lane) * DS;
#pragma unroll
    for (int j = 0; j < 4; ++j) *(float4*)&h[4 * j] = *(const float4*)(H0p + base + 4 * j);
  }
  const h16* pdt = SDT2 + ((size_t)i * L_ + t0) * DI + lane;
  const h16* pxx = SX2 + ((size_t)i * L_ + t0) * DI + lane;
  const h16* pzz = SZ2 + ((size_t)i * L_ + t0) * DI + lane;
  h16* pys = YS2 + ((size_t)i * L_ + t0) * DI + lane;
  float dtc = (float)pdt[0], xvc = (float)pxx[0], zvc = (float)pzz[0];
  float sum = 0.f;
  for (int t = 0; t < SL; ++t) {
    float dt = dtc, xv = xvc, zv = zvc;
    if (t < SL - 1) {
      dtc = (float)pdt[(t + 1) * DI];
      xvc = (float)pxx[(t + 1) * DI];
      zvc = (float)pzz[(t + 1) * DI];
    }
    const float* row = &rowS[w][t][0];
    float Bv[16], Cv[16];
#pragma unroll
    for (int j = 0; j < 4; ++j) {
      *(float4*)&Bv[4 * j] = *(const float4*)(row + 4 * j);
      *(float4*)&Cv[4 * j] = *(const float4*)(row + 16 + 4 * j);
    }
    float dtx = dt * xv;
    float dA[16];
    if (fastp) {
      powladder_(__expf(A0 * dt), dA);
    } else {
#pragma unroll
      for (int s = 0; s < 16; ++s) dA[s] = __expf(Av[s] * dt);
    }
    float y0 = 0.f, y1 = 0.f, y2 = 0.f, y3 = 0.f;
#pragma unroll
    for (int s = 0; s < 16; s += 4) {
      h[s] = fmaf(dA[s], h[s], dtx * Bv[s]);       y0 = fmaf(h[s], Cv[s], y0);
      h[s + 1] = fmaf(dA[s + 1], h[s + 1], dtx * Bv[s + 1]); y1 = fmaf(h[s + 1], Cv[s + 1], y1);
      h[s + 2] = fmaf(dA[s + 2], h[s + 2], dtx * Bv[s + 2]); y2 = fmaf(h[s + 2], Cv[s + 2], y2);
      h[s + 3] = fmaf(dA[s + 3], h[s + 3], dtx * Bv[s + 3]); y3 = fmaf(h[s + 3], Cv[s + 3], y3);
    }
    float y = (y0 + y1) + (y2 + y3);
    float yf = fmaf(xv, Dp, y) * zv;
    pys[(size_t)t * DI] = (h16)yf;
    sum += yf;
  }
  atomicAdd(&SUMYF[i * DI + lane], sum);
}

// ---------------- K56: SE gates + gated combine (MFMA) + LN2 + proj (MFMA) ----
__global__ __launch_bounds__(256) void k56_comb_proj(
    const float* __restrict__ out_W, const float* __restrict__ skip_p,
    const float* __restrict__ se_W1, const float* __restrict__ se_W2,
    const float* __restrict__ SUMYF, const float* __restrict__ SUMXN,
    const h16* __restrict__ YS2, const float* __restrict__ gn,
    const float* __restrict__ bn, const float* __restrict__ proj_W,
    const float* __restrict__ proj_b, const h16* __restrict__ XNH,
    float* __restrict__ out) {
  int bid = blockIdx.x;
  int b = bid >> 6, tile = bid & 63;
  int t0 = tile * 64;
  int tid = threadIdx.x;
  int w = __builtin_amdgcn_readfirstlane(tid >> 6);
  int lane = tid & 63;
  __shared__ __attribute__((aligned(16))) union {
    float xmS[64][132];
    _Float16 projH[128][136];
  } U;
  __shared__ __attribute__((aligned(16))) union {
    struct {
      _Float16 yH[64][72];
      _Float16 owH[32][72];
    } pre;
    _Float16 xmH[64][136];
  } V;
  __shared__ float gAll[4][64];
  __shared__ float gnS[128], bnS[128];
  float* catS = (float*)&V.pre.yH[0][0];   // 4*64 floats
  float* seL = catS + 256;                 // 8 floats

  if (tid < 128) { gnS[tid] = gn[tid]; bnS[tid] = bn[tid]; }
  for (int k = tid; k < 2048; k += 256) V.pre.owH[k >> 6][k & 63] = (_Float16)out_W[k];
  // stage xm from XNH (h16 -> f32)
  const h16* xmh = XNH + (size_t)b * L_ * C_;
  for (int k = tid; k < 1024; k += 256) {
    int tt = k >> 4, c8 = (k & 15) * 8;
    f16x8 hv = *(const f16x8*)&xmh[(size_t)(t0 + tt) * C_ + c8];
#pragma unroll
    for (int j = 0; j < 8; ++j) U.xmS[tt][c8 + j] = (float)hv[j];
  }
  // ---- gates (folded k4): phase A -> catS
  {
    int ch = tid >> 6, j = tid & 63;
    float invL = 1.f / (float)L_;
    if (j < 32) {
      const float* sy = SUMYF + (b * 4 + ch) * DI;
      const float* ow = out_W + j * 64;
      float acc = 0.f;
#pragma unroll
      for (int dd = 0; dd < 64; ++dd) acc = fmaf(sy[dd], ow[dd], acc);
      catS[ch * 64 + j] = acc * invL;
    } else {
      catS[ch * 64 + j] = skip_p[0] * SUMXN[b * C_ + ch * DM + (j - 32)] * invL;
    }
  }
  __syncthreads();
  if (tid < 8) {
    int ch = tid >> 1, r = tid & 1;
    float acc = 0.f;
#pragma unroll
    for (int k = 0; k < 64; ++k) acc = fmaf(catS[ch * 64 + k], se_W1[r * 64 + k], acc);
    seL[tid] = fmaxf(acc, 0.f);
  }
  __syncthreads();
  {
    int ch = tid >> 6, j = tid & 63;
    gAll[ch][j] = sigmoidf_(fmaf(seL[ch * 2], se_W2[j * 2], seL[ch * 2 + 1] * se_W2[j * 2 + 1]));
  }
  __syncthreads();   // gates done; yH region reusable

  int rsel = lane & 15, ksel = (lane >> 4) * 8;
  float skip = skip_p[0];
  // per-channel gated combine: xm[tok][ch*32+o] = g1*M1 + g2*skip*xn
  for (int ch = 0; ch < 4; ++ch) {
    const h16* py = YS2 + ((size_t)(b * 4 + ch) * L_ + t0) * DI;
    for (int k = tid; k < 512; k += 256) {
      int tt = k >> 3, dblk = (k & 7) * 8;
      *(f16x8*)&V.pre.yH[tt][dblk] = *(const f16x8*)&py[(size_t)tt * DI + dblk];
    }
    __syncthreads();
    f16x8 a0 = *(const f16x8*)&V.pre.yH[w * 16 + rsel][ksel];
    f16x8 a1 = *(const f16x8*)&V.pre.yH[w * 16 + rsel][32 + ksel];
    int row0 = w * 16 + ((lane >> 4) << 2);
#pragma unroll
    for (int nt = 0; nt < 2; ++nt) {
      f16x8 b0 = *(const f16x8*)&V.pre.owH[nt * 16 + rsel][ksel];
      f16x8 b1 = *(const f16x8*)&V.pre.owH[nt * 16 + rsel][32 + ksel];
      f32x4 acc = {0.f, 0.f, 0.f, 0.f};
      acc = __builtin_amdgcn_mfma_f32_16x16x32_f16(a0, b0, acc, 0, 0, 0);
      acc = __builtin_amdgcn_mfma_f32_16x16x32_f16(a1, b1, acc, 0, 0, 0);
      int o = nt * 16 + rsel;
      float g1 = gAll[ch][o], g2s = gAll[ch][32 + o] * skip;
      int cc = ch * 32 + o;
#pragma unroll
      for (int r = 0; r < 4; ++r) {
        int tok = row0 + r;
        U.xmS[tok][cc] = g1 * acc[r] + g2s * U.xmS[tok][cc];
      }
    }
    __syncthreads();
  }

  // LN2 over xm rows
  {
    int tok = tid >> 2, q = tid & 3;
    float s = 0.f, qq = 0.f;
#pragma unroll
    for (int j = 0; j < 32; ++j) {
      float v = U.xmS[tok][4 * j + q];
      s += v; qq += v * v;
    }
    s = dpp_add_<0xB1>(s); qq = dpp_add_<0xB1>(qq);
    s = dpp_add_<0x4E>(s); qq = dpp_add_<0x4E>(qq);
    float m = s * (1.f / 128.f);
    float var = qq * (1.f / 128.f) - m * m;
    float rs = rsqrtf(var + 1e-5f);
#pragma unroll
    for (int j = 0; j < 32; ++j) {
      int c = 4 * j + q;
      float v = U.xmS[tok][c];
      U.xmS[tok][c] = (v - m) * rs * gnS[c] + bnS[c];
    }
  }
  __syncthreads();
  // convert LN output to h16 (xmH overlays dead yH/owH)
  for (int k = tid; k < 1024; k += 256) {
    int tt = k >> 4, cblk = (k & 15) * 8;
    float4 v0 = *(const float4*)&U.xmS[tt][cblk];
    float4 v1 = *(const float4*)&U.xmS[tt][cblk + 4];
    f16x8 hv;
    hv[0] = (_Float16)v0.x; hv[1] = (_Float16)v0.y;
    hv[2] = (_Float16)v0.z; hv[3] = (_Float16)v0.w;
    hv[4] = (_Float16)v1.x; hv[5] = (_Float16)v1.y;
    hv[6] = (_Float16)v1.z; hv[7] = (_Float16)v1.w;
    *(f16x8*)&V.xmH[tt][cblk] = hv;
  }
  __syncthreads();
  // stage proj_W as h16 over dead xmS
  for (int k = tid; k < 2048; k += 256) {
    int o = k >> 4, cblk = (k & 15) * 8;
    const float* wp = proj_W + o * 128 + cblk;
    float4 v0 = *(const float4*)wp;
    float4 v1 = *(const float4*)(wp + 4);
    f16x8 hv;
    hv[0] = (_Float16)v0.x; hv[1] = (_Float16)v0.y;
    hv[2] = (_Float16)v0.z; hv[3] = (_Float16)v0.w;
    hv[4] = (_Float16)v1.x; hv[5] = (_Float16)v1.y;
    hv[6] = (_Float16)v1.z; hv[7] = (_Float16)v1.w;
    *(f16x8*)&U.projH[o][cblk] = hv;
  }
  __syncthreads();
  // proj MFMA: M=64 (wave=mt), N=128, K=128
  f16x8 af[4];
#pragma unroll
  for (int kc = 0; kc < 4; ++kc)
    af[kc] = *(const f16x8*)&V.xmH[w * 16 + rsel][kc * 32 + ksel];
  int row0 = w * 16 + ((lane >> 4) << 2);
#pragma unroll
  for (int nt = 0; nt < 8; ++nt) {
    int o = nt * 16 + rsel;
    float pb = proj_b[o];
    f32x4 acc = {pb, pb, pb, pb};
#pragma unroll
    for (int kc = 0; kc < 4; ++kc) {
      f16x8 bf = *(const f16x8*)&U.projH[o][kc * 32 + ksel];
      acc = __builtin_amdgcn_mfma_f32_16x16x32_f16(af[kc], bf, acc, 0, 0, 0);
    }
    *(float4*)&out[((size_t)(b * OUT_ + o)) * L_ + t0 + row0] =
        make_float4(acc[0], acc[1], acc[2], acc[3]);
  }
}

extern "C" void kernel_launch(void* const* d_in, const int* in_sizes, int n_in,
                              void* d_out, int out_size, void* d_ws, size_t ws_size,
                              hipStream_t stream) {
  const float* x = (const float*)d_in[0];
  const float* norm_g = (const float*)d_in[1];
  const float* norm_b = (const float*)d_in[2];
  const float* proj_W = (const float*)d_in[3];
  const float* proj_b = (const float*)d_in[4];
  const float* skip = (const float*)d_in[5];
  const float* se_W1 = (const float*)d_in[6];
  const float* se_W2 = (const float*)d_in[7];
  const float* in_W = (const float*)d_in[8];
  const float* conv_W = (const float*)d_in[9];
  const float* conv_b = (const float*)d_in[10];
  const float* xproj_W = (const float*)d_in[11];
  const float* dt_W = (const float*)d_in[12];
  const float* dt_b = (const float*)d_in[13];
  const float* A_log = (const float*)d_in[14];
  const float* D_p = (const float*)d_in[15];
  const float* out_W = (const float*)d_in[16];
  float* out = (float*)d_out;

  // workspace (~120 MiB)
  float* SUMYF = (float*)d_ws;                      // NI*DI
  float* SUMXN = SUMYF + NI * DI;                   // B*C
  float* Pp = SUMXN + B_ * C_;                      // NI*NSEG*DI*DS f32 (seg-major)
  float* Qp = Pp + (size_t)NI * DI * NSEG * DS;
  h16* YS2 = (h16*)(Qp + (size_t)NI * DI * NSEG * DS);  // NI*L*DI h16
  h16* SX2 = YS2 + (size_t)NI * L_ * DI;
  h16* SDT2 = SX2 + (size_t)NI * L_ * DI;
  h16* SB2 = SDT2 + (size_t)NI * L_ * DI;           // NI*L*DS h16
  h16* SC2 = SB2 + (size_t)NI * L_ * DS;
  h16* SZ2 = SC2 + (size_t)NI * L_ * DS;            // NI*L*DI h16 (silu(z))
  h16* XNH = SZ2 + (size_t)NI * L_ * DI;            // B*L*C h16
  h16* WH = XNH + (size_t)B_ * L_ * C_;             // 7168 h16

  k0_wcvt<<<28, 256, 0, stream>>>(in_W, xproj_W, WH, SUMYF);
  k1_ln<<<B_ * 64, 256, 0, stream>>>(x, norm_g, norm_b, XNH, SUMXN);
  k2_prep<<<NI * 64, 256, 0, stream>>>(WH, conv_W, conv_b, dt_W, dt_b, A_log,
                                       XNH, SX2, SDT2, SB2, SC2, SZ2, Pp, Qp);
  k3b_comb<<<128, 256, 0, stream>>>(Pp, Qp);
  k3c_scan<<<NI * 32, 256, 0, stream>>>(A_log, SDT2, SX2, SB2, SC2, SZ2, D_p,
                                        Pp, YS2, SUMYF);
  k56_comb_proj<<<B_ * 64, 256, 0, stream>>>(out_W, skip, se_W1, se_W2, SUMYF,
                                             SUMXN, YS2, norm_g, norm_b, proj_W,
                                             proj_b, XNH, out);
}